// Round 1
// baseline (8434.809 us; speedup 1.0000x reference)
//
#include <hip/hip_runtime.h>
#include <math.h>

// ---------------------------------------------------------------------------
// FeatureProcessor forward, fp32 faithful baseline.
// Shapes fixed by setup_inputs(): B=8, C=64, H=W=64, RED=16, EXP=512.
// Dominant cost: e2 conv 5x5 512->512 (~429 GFLOP of ~470 total).
//
// Workspace layout (bytes):
//   [0,   64M) regA : y4 (fe out, 8x512x64x64 f32). After e2 consumed, reused:
//                     +0   ll_a (c1/c5 out)      +8M  ll_b (c3 out)
//                     +16M ll_l2                 +24M hl_l1
//                     +32M lh_l1                 +40M hl_l2
//                     +48M lh_l2                 +56M hh_a
//   [64M, 128M) regB : y5 (e2 out). After cr consumed, reused: +0 hh_l2
//   [128M,144M) y7   : cr out (8x128x64x64)
//   [144M,146M) y1   : cc out (8x16x64x64)
//   [146M,148M) y2   : e1 out
//   [148M, ..)  hh_m (8x64x64 f32 = 128KB), then stats1/2/3
// ---------------------------------------------------------------------------

#define HWP 4096  // 64*64

// ---------------- median of 64 channels of 5x5 box-sum (reflect pad) -------
__global__ void __launch_bounds__(256) median_k(
    const float* __restrict__ hh, const float* __restrict__ w_hh,
    float* __restrict__ hh_m) {
  int tid = threadIdx.x;
  int wave = blockIdx.x * 4 + (tid >> 6);     // one wave per (b,h,w)
  int lane = tid & 63;                        // lane == channel
  int b = wave >> 12;
  int hw = wave & 4095;
  int h = hw >> 6, w = hw & 63;
  const float* base = hh + (((size_t)(b * 64 + lane)) << 12);
  float s = 0.f;
#pragma unroll
  for (int kh = 0; kh < 5; ++kh) {
    int ih = h - 2 + kh;
    ih = ih < 0 ? -ih : (ih > 63 ? 126 - ih : ih);
#pragma unroll
    for (int kw = 0; kw < 5; ++kw) {
      int iw = w - 2 + kw;
      iw = iw < 0 ? -iw : (iw > 63 ? 126 - iw : iw);
      s += base[(ih << 6) + iw];
    }
  }
  s *= w_hh[0];
  // bitonic sort across the 64 lanes (ascending)
  for (int k = 2; k <= 64; k <<= 1) {
    for (int j = k >> 1; j > 0; j >>= 1) {
      float o = __shfl_xor(s, j, 64);
      bool up = (lane & k) == 0;
      bool low = (lane & j) == 0;
      s = (low == up) ? fminf(s, o) : fmaxf(s, o);
    }
  }
  float v31 = __shfl(s, 31, 64);
  float v32 = __shfl(s, 32, 64);
  if (lane == 0) hh_m[wave] = 0.5f * (v31 + v32);
}

// ---------------- per-channel mean/invstd over (B,H,W) ---------------------
__global__ void __launch_bounds__(256) stats_k(
    const float* __restrict__ x, float* __restrict__ stats, int C, int B) {
  int c = blockIdx.x;
  int tid = threadIdx.x;
  int N = B * HWP;
  float s = 0.f, q = 0.f;
  for (int i = tid; i < N; i += 256) {
    int b = i >> 12, p = i & 4095;
    float v = x[(((size_t)(b * C + c)) << 12) + p];
    s += v;
    q += v * v;
  }
  __shared__ float rs[256], rq[256];
  rs[tid] = s; rq[tid] = q;
  __syncthreads();
  for (int st = 128; st > 0; st >>= 1) {
    if (tid < st) { rs[tid] += rs[tid + st]; rq[tid] += rq[tid + st]; }
    __syncthreads();
  }
  if (tid == 0) {
    float mean = rs[0] / (float)N;
    float var = rq[0] / (float)N - mean * mean;
    stats[c] = mean;
    stats[C + c] = rsqrtf(fmaxf(var, 0.f) + 1e-5f);
  }
}

// ---------------- 1x1 conv (pointwise GEMM) with fused input modes ---------
// mode 0: v = inA[b,c,p]
// mode 1: v = c<C1 ? sA*inA[b,c,p] : sB*inB[b,c-C1,p]   (sA/sB null -> 1.0)
// mode 2: v = relu((inA - mean[c])*invstd[c]*g[c] + bb[c])
// mode 3: v = inA[b,c,p] + extra[b,p]                   (hh_l1 = hh_freq+hh_m)
// out_mode 1: leaky_relu(0.1)
__global__ void __launch_bounds__(256) conv1x1_k(
    const float* __restrict__ inA, const float* __restrict__ inB, int C1,
    const float* __restrict__ sA, const float* __restrict__ sB,
    const float* __restrict__ bn_stats, const float* __restrict__ bn_g,
    const float* __restrict__ bn_b, const float* __restrict__ extra, int mode,
    const float* __restrict__ wgt, const float* __restrict__ bias,
    float* __restrict__ out, int CIN, int COUT, int out_mode) {
  __shared__ __align__(16) float s_in[16][128];
  __shared__ __align__(16) float s_w[16][32];
  int tid = threadIdx.x;
  int p0 = blockIdx.x * 128;
  int co0 = blockIdx.y * 32;
  int b = blockIdx.z;
  float fA = sA ? sA[0] : 1.f;
  float fB = sB ? sB[0] : 1.f;
  int pi = tid & 63;   // position pair index
  int cog = tid >> 6;  // 0..3 -> 8 co each
  float acc0[8] = {0.f, 0.f, 0.f, 0.f, 0.f, 0.f, 0.f, 0.f};
  float acc1[8] = {0.f, 0.f, 0.f, 0.f, 0.f, 0.f, 0.f, 0.f};
  for (int ci0 = 0; ci0 < CIN; ci0 += 16) {
#pragma unroll
    for (int t = 0; t < 8; ++t) {
      int idx = tid + t * 256;
      int ci = idx >> 7, pp = idx & 127;
      int c = ci0 + ci;
      int p = p0 + pp;
      float v;
      if (mode == 1) {
        v = (c < C1) ? fA * inA[(((size_t)(b * C1 + c)) << 12) + p]
                     : fB * inB[(((size_t)(b * (CIN - C1) + (c - C1))) << 12) + p];
      } else {
        v = inA[(((size_t)(b * CIN + c)) << 12) + p];
        if (mode == 2) {
          v = (v - bn_stats[c]) * bn_stats[CIN + c] * bn_g[c] + bn_b[c];
          v = fmaxf(v, 0.f);
        } else if (mode == 3) {
          v += extra[(b << 12) + p];
        }
      }
      s_in[ci][pp] = v;
    }
#pragma unroll
    for (int t = 0; t < 2; ++t) {
      int idx = tid + t * 256;
      int ci = idx >> 5, co = idx & 31;
      float wv = 0.f;
      if (co0 + co < COUT) wv = wgt[(size_t)(co0 + co) * CIN + ci0 + ci];
      s_w[ci][co] = wv;
    }
    __syncthreads();
#pragma unroll
    for (int ci = 0; ci < 16; ++ci) {
      float v0 = s_in[ci][pi * 2];
      float v1 = s_in[ci][pi * 2 + 1];
      const float4* wp = (const float4*)&s_w[ci][cog * 8];
#pragma unroll
      for (int q = 0; q < 2; ++q) {
        float4 wv = wp[q];
        float wj[4] = {wv.x, wv.y, wv.z, wv.w};
#pragma unroll
        for (int r = 0; r < 4; ++r) {
          acc0[q * 4 + r] += v0 * wj[r];
          acc1[q * 4 + r] += v1 * wj[r];
        }
      }
    }
    __syncthreads();
  }
#pragma unroll
  for (int j = 0; j < 8; ++j) {
    int co = co0 + cog * 8 + j;
    if (co < COUT) {
      float bs = bias[co];
      float r0 = acc0[j] + bs;
      float r1 = acc1[j] + bs;
      if (out_mode == 1) {
        r0 = r0 < 0.f ? 0.1f * r0 : r0;
        r1 = r1 < 0.f ? 0.1f * r1 : r1;
      }
      float2 rr = make_float2(r0, r1);
      *(float2*)&out[(((size_t)(b * COUT + co)) << 12) + p0 + pi * 2] = rr;
    }
  }
}

// ---------------- generic KxK direct conv, 32x32 tile, 2x2 microtile -------
// OUTMODE 1: tanh. scale_ptr (optional): multiply input values.
template <int K, int DIL, int CI_T, int OUTMODE>
__global__ void __launch_bounds__(256) convK_k(
    const float* __restrict__ in, const float* __restrict__ wgt,
    const float* __restrict__ bias, float* __restrict__ out, int CIN, int COUT,
    const float* __restrict__ scale_ptr) {
  constexpr int IH = 32 + (K - 1) * DIL;
  constexpr int IW = 32 + (K - 1) * DIL;
  constexpr int PAD = (K - 1) / 2 * DIL;
  constexpr int KK = K * K;
  __shared__ __align__(16) float s_in[CI_T][IH][IW];
  __shared__ __align__(16) float s_w[CI_T * KK * 16];
  int tid = threadIdx.x;
  int tx = tid & 15, ty = tid >> 4;
  int w0 = blockIdx.x * 32, h0 = blockIdx.y * 32;
  int ncog = COUT >> 4;
  int cog = blockIdx.z % ncog;
  int b = blockIdx.z / ncog;
  int co0 = cog << 4;
  float scale = scale_ptr ? scale_ptr[0] : 1.f;
  float a00[16] = {}, a01[16] = {}, a10[16] = {}, a11[16] = {};
  for (int ci0 = 0; ci0 < CIN; ci0 += CI_T) {
    for (int idx = tid; idx < CI_T * IH * IW; idx += 256) {
      int ci = idx / (IH * IW);
      int r = idx - ci * (IH * IW);
      int iy = r / IW;
      int ix = r - iy * IW;
      int gh = h0 - PAD + iy, gw = w0 - PAD + ix;
      float v = 0.f;
      if ((unsigned)gh < 64u && (unsigned)gw < 64u)
        v = in[((((size_t)(b * CIN + ci0 + ci)) << 6) + (size_t)gh << 6) + gw] * scale;
      s_in[ci][iy][ix] = v;
    }
    for (int idx = tid; idx < CI_T * KK * 16; idx += 256) {
      int co = idx & 15;
      int t = (idx >> 4) % KK;
      int ci = (idx >> 4) / KK;
      s_w[(ci * KK + t) * 16 + co] =
          wgt[((size_t)(co0 + co) * CIN + ci0 + ci) * KK + t];
    }
    __syncthreads();
    for (int ci = 0; ci < CI_T; ++ci) {
#pragma unroll
      for (int t = 0; t < KK; ++t) {
        int kh = t / K, kw = t - (t / K) * K;
        int iy = ty * 2 + kh * DIL, ix = tx * 2 + kw * DIL;
        float v00 = s_in[ci][iy][ix];
        float v01 = s_in[ci][iy][ix + 1];
        float v10 = s_in[ci][iy + 1][ix];
        float v11 = s_in[ci][iy + 1][ix + 1];
        const float4* wp = (const float4*)&s_w[(ci * KK + t) * 16];
#pragma unroll
        for (int q = 0; q < 4; ++q) {
          float4 wv = wp[q];
          float wj[4] = {wv.x, wv.y, wv.z, wv.w};
#pragma unroll
          for (int r = 0; r < 4; ++r) {
            a00[q * 4 + r] += v00 * wj[r];
            a01[q * 4 + r] += v01 * wj[r];
            a10[q * 4 + r] += v10 * wj[r];
            a11[q * 4 + r] += v11 * wj[r];
          }
        }
      }
    }
    __syncthreads();
  }
  int oh = h0 + ty * 2, ow = w0 + tx * 2;
#pragma unroll
  for (int j = 0; j < 16; ++j) {
    int co = co0 + j;
    float bs = bias[co];
    float r00 = a00[j] + bs, r01 = a01[j] + bs;
    float r10 = a10[j] + bs, r11 = a11[j] + bs;
    if (OUTMODE == 1) {
      r00 = tanhf(r00); r01 = tanhf(r01);
      r10 = tanhf(r10); r11 = tanhf(r11);
    }
    size_t ob = ((((size_t)(b * COUT + co)) << 6) + (size_t)oh) << 6;
    *(float2*)&out[ob + ow] = make_float2(r00, r01);
    *(float2*)&out[ob + 64 + ow] = make_float2(r10, r11);
  }
}

// ---------------- sigmoid gate: hl_l1 / lh_l1 ------------------------------
__global__ void __launch_bounds__(256) gate_k(
    const float* __restrict__ y7, const float* __restrict__ st,
    const float* __restrict__ g, const float* __restrict__ bb,
    const float* __restrict__ hl_freq, const float* __restrict__ lh_freq,
    const float* __restrict__ w_hl, const float* __restrict__ w_lh,
    float* __restrict__ hl_l1, float* __restrict__ lh_l1) {
  int i = blockIdx.x * 256 + threadIdx.x;  // [0, 8*128*4096)
  int p = i & 4095;
  int c = (i >> 12) & 127;
  int b = i >> 19;
  float nv = (y7[i] - st[c]) * st[128 + c] * g[c] + bb[c];
  float sig = 1.f / (1.f + expf(-nv));
  if (c < 64) {
    size_t k = (((size_t)(b * 64 + c)) << 12) + p;
    hl_l1[k] = w_hl[0] * hl_freq[k] * sig;
  } else {
    size_t k = (((size_t)(b * 64 + (c - 64))) << 12) + p;
    lh_l1[k] = w_lh[0] * lh_freq[k] * sig;
  }
}

// ---------------- Haar IDWT ------------------------------------------------
__global__ void __launch_bounds__(256) idwt_k(
    const float* __restrict__ ca, const float* __restrict__ ch,
    const float* __restrict__ cv, const float* __restrict__ cd,
    float* __restrict__ out) {
  int i = blockIdx.x * 256 + threadIdx.x;  // [0, 8*64*4096)
  float A = ca[i], Hd = ch[i], V = cv[i], D = cd[i];
  float y00 = (A + Hd + V + D) * 0.5f;
  float y01 = (A + Hd - V - D) * 0.5f;
  float y10 = (A - Hd + V - D) * 0.5f;
  float y11 = (A - Hd - V + D) * 0.5f;
  int w = i & 63;
  int h = (i >> 6) & 63;
  int bc = i >> 12;
  size_t ob = (((size_t)bc * 128) + 2 * h) * 128 + 2 * w;
  *(float2*)&out[ob] = make_float2(y00, y01);
  *(float2*)&out[ob + 128] = make_float2(y10, y11);
}

// ---------------------------------------------------------------------------
extern "C" void kernel_launch(void* const* d_in, const int* in_sizes, int n_in,
                              void* d_out, int out_size, void* d_ws,
                              size_t ws_size, hipStream_t stream) {
  const float* ll_freq = (const float*)d_in[0];
  const float* hl_freq = (const float*)d_in[1];
  const float* lh_freq = (const float*)d_in[2];
  const float* hh_freq = (const float*)d_in[3];
  const float* w_ll = (const float*)d_in[4];
  const float* w_hl = (const float*)d_in[5];
  const float* w_lh = (const float*)d_in[6];
  const float* w_hh = (const float*)d_in[7];
  const float* cc_w = (const float*)d_in[8];
  const float* cc_b = (const float*)d_in[9];
  const float* bnc_g = (const float*)d_in[10];
  const float* bnc_b = (const float*)d_in[11];
  const float* e1_w = (const float*)d_in[12];
  const float* e1_b = (const float*)d_in[13];
  const float* fe_w = (const float*)d_in[14];
  const float* fe_b = (const float*)d_in[15];
  const float* e2_w = (const float*)d_in[16];
  const float* e2_b = (const float*)d_in[17];
  const float* bne_g = (const float*)d_in[18];
  const float* bne_b = (const float*)d_in[19];
  const float* cr_w = (const float*)d_in[20];
  const float* cr_b = (const float*)d_in[21];
  const float* bnr_g = (const float*)d_in[22];
  const float* bnr_b = (const float*)d_in[23];
  const float* adj_w = (const float*)d_in[24];
  const float* adj_b = (const float*)d_in[25];
  const float* cll_w = (const float*)d_in[26];
  const float* cll_b = (const float*)d_in[27];
  const float* chh_w = (const float*)d_in[28];
  const float* chh_b = (const float*)d_in[29];
  const float* c1_w = (const float*)d_in[30];
  const float* c1_b = (const float*)d_in[31];
  const float* c3_w = (const float*)d_in[32];
  const float* c3_b = (const float*)d_in[33];
  const float* c5_w = (const float*)d_in[34];
  const float* c5_b = (const float*)d_in[35];

  const size_t MB = 1ull << 20;
  char* ws = (char*)d_ws;
  float* regA = (float*)(ws);              // 64MB: y4, later sub-buffers
  float* regB = (float*)(ws + 64 * MB);    // 64MB: y5, later hh_l2
  float* y7   = (float*)(ws + 128 * MB);   // 16MB
  float* y1   = (float*)(ws + 144 * MB);   // 2MB
  float* y2   = (float*)(ws + 146 * MB);   // 2MB
  float* hh_m = (float*)(ws + 148 * MB);   // 128KB
  float* st1  = (float*)(ws + 149 * MB);   // 32 f
  float* st2  = st1 + 1024;                // 1024 f
  float* st3  = st2 + 2048;                // 256 f

  const size_t F2M = 2097152;  // floats per 8MB
  float* ll_a  = regA + 0 * F2M;
  float* ll_b  = regA + 1 * F2M;
  float* ll_l2 = regA + 2 * F2M;
  float* hl_l1 = regA + 3 * F2M;
  float* lh_l1 = regA + 4 * F2M;
  float* hl_l2 = regA + 5 * F2M;
  float* lh_l2 = regA + 6 * F2M;
  float* hh_a  = regA + 7 * F2M;
  float* hh_l2 = regB;

  dim3 blk(256);

  // 1. hh_m = median over channels of 5x5 box-sum of (w_hh*hh_freq)
  median_k<<<dim3(8192), blk, 0, stream>>>(hh_freq, w_hh, hh_m);

  // 2. cc 1x1 on concat(w_hl*hl, w_lh*lh): 128->16
  conv1x1_k<<<dim3(32, 1, 8), blk, 0, stream>>>(
      hl_freq, lh_freq, 64, w_hl, w_lh, nullptr, nullptr, nullptr, nullptr, 1,
      cc_w, cc_b, y1, 128, 16, 0);

  // 3. e1 3x3 16->16
  convK_k<3, 1, 8, 0><<<dim3(2, 2, 8), blk, 0, stream>>>(y1, e1_w, e1_b, y2, 16,
                                                         16, nullptr);
  // 4. bnc stats
  stats_k<<<dim3(16), blk, 0, stream>>>(y2, st1, 16, 8);

  // 5. fe 1x1 16->512, input relu(bn(y2))
  conv1x1_k<<<dim3(32, 16, 8), blk, 0, stream>>>(
      y2, nullptr, 0, nullptr, nullptr, st1, bnc_g, bnc_b, nullptr, 2, fe_w,
      fe_b, regA, 16, 512, 0);

  // 6. e2 5x5 512->512  (the 429-GFLOP kernel)
  convK_k<5, 1, 8, 0><<<dim3(2, 2, 256), blk, 0, stream>>>(
      regA, e2_w, e2_b, regB, 512, 512, nullptr);

  // 7. bne stats
  stats_k<<<dim3(512), blk, 0, stream>>>(regB, st2, 512, 8);

  // 8. cr 1x1 512->128, input relu(bn(y5))
  conv1x1_k<<<dim3(32, 4, 8), blk, 0, stream>>>(
      regB, nullptr, 0, nullptr, nullptr, st2, bne_g, bne_b, nullptr, 2, cr_w,
      cr_b, y7, 512, 128, 0);

  // 9. bnr stats
  stats_k<<<dim3(128), blk, 0, stream>>>(y7, st3, 128, 8);

  // 10. gate: hl_l1 / lh_l1 = orig * sigmoid(bn(y7))
  gate_k<<<dim3(16384), blk, 0, stream>>>(y7, st3, bnr_g, bnr_b, hl_freq,
                                          lh_freq, w_hl, w_lh, hl_l1, lh_l1);

  // 11-13. LL branch: c1(3x3) -> c3(5x5) -> c5(7x7), input ll = w_ll*ll_freq
  convK_k<3, 1, 8, 0><<<dim3(2, 2, 32), blk, 0, stream>>>(
      ll_freq, c1_w, c1_b, ll_a, 64, 64, w_ll);
  convK_k<5, 1, 8, 0><<<dim3(2, 2, 32), blk, 0, stream>>>(ll_a, c3_w, c3_b,
                                                          ll_b, 64, 64, nullptr);
  convK_k<7, 1, 8, 0><<<dim3(2, 2, 32), blk, 0, stream>>>(ll_b, c5_w, c5_b,
                                                          ll_a, 64, 64, nullptr);

  // 14. ll_l2 = adj(concat(ll_l1, w_ll*ll_freq))
  conv1x1_k<<<dim3(32, 2, 8), blk, 0, stream>>>(
      ll_a, ll_freq, 64, nullptr, w_ll, nullptr, nullptr, nullptr, nullptr, 1,
      adj_w, adj_b, ll_l2, 128, 64, 0);
  // 15. hl_l2 = adj(concat(hl_l1, hl_freq))
  conv1x1_k<<<dim3(32, 2, 8), blk, 0, stream>>>(
      hl_l1, hl_freq, 64, nullptr, nullptr, nullptr, nullptr, nullptr, nullptr,
      1, adj_w, adj_b, hl_l2, 128, 64, 0);
  // 16. lh_l2 = adj(concat(lh_l1, lh_freq))
  conv1x1_k<<<dim3(32, 2, 8), blk, 0, stream>>>(
      lh_l1, lh_freq, 64, nullptr, nullptr, nullptr, nullptr, nullptr, nullptr,
      1, adj_w, adj_b, lh_l2, 128, 64, 0);

  // 17. hh_a = leaky_relu(chh(hh_l1)), hh_l1 = hh_freq + hh_m (broadcast)
  conv1x1_k<<<dim3(32, 2, 8), blk, 0, stream>>>(
      hh_freq, nullptr, 0, nullptr, nullptr, nullptr, nullptr, nullptr, hh_m, 3,
      chh_w, chh_b, hh_a, 64, 64, 1);

  // 18. hh_l2 = tanh(cll 5x5 dil2 of hh_a)
  convK_k<5, 2, 8, 1><<<dim3(2, 2, 32), blk, 0, stream>>>(
      hh_a, cll_w, cll_b, hh_l2, 64, 64, nullptr);

  // 19. IDWT -> out (8,64,128,128)
  idwt_k<<<dim3(8192), blk, 0, stream>>>(ll_l2, hl_l2, lh_l2, hh_l2,
                                         (float*)d_out);
}

// Round 3
// 2758.879 us; speedup vs baseline: 3.0573x; 3.0573x over previous
//
#include <hip/hip_runtime.h>
#include <math.h>

// ---------------------------------------------------------------------------
// FeatureProcessor forward. B=8, C=64, H=W=64, RED=16, EXP=512.
// e2 (5x5 512->512, 429 GFLOP) runs on bf16 MFMA via implicit GEMM with
// split-A 2-product (A exact to 2^-16, weights bf16-rounded).
// R2 fix: bterm was missing the wave-N offset (wn*64) -> wn=1 waves used
// co 0..63 weights while writing co 64..127.
//
// Workspace layout:
//   [0,  32M) y4h : fe out hi, bf16 channels-last ci-blocked pre-swizzled
//   [32M,64M) y4l : fe out lo
//     (region reused after e2: ll_a/ll_b/ll_l2/hl_l1/lh_l1/hl_l2/lh_l2/hh_a)
//   [64M,128M) regB : e2 out fp32 NCHW; later hh_l2
//   [128M,144M) y7 ; [144M,146M) y1 ; [146M,148M) y2
//   [148M,162M) Wt  : e2 weights bf16 [cbco4][cbci16][tap25][co128][ci32]
//   [162M, ..) hh_m, stats
// ---------------------------------------------------------------------------

#define HWP 4096

typedef __attribute__((ext_vector_type(8))) short bf16x8;
typedef __attribute__((ext_vector_type(4))) float f32x4;

__device__ __forceinline__ unsigned short f2bf(float x) {
  unsigned int u = __float_as_uint(x);
  unsigned int r = (u + 0x7fffu + ((u >> 16) & 1u)) >> 16;
  return (unsigned short)r;
}
__device__ __forceinline__ float bf2f(unsigned short h) {
  return __uint_as_float(((unsigned int)h) << 16);
}

__device__ __forceinline__ void gload16(const void* g, void* l) {
  __builtin_amdgcn_global_load_lds(
      (const __attribute__((address_space(1))) unsigned int*)g,
      (__attribute__((address_space(3))) unsigned int*)l, 16, 0, 0);
}

// ---------------- median of 64 channels of 5x5 box-sum (reflect pad) -------
__global__ void __launch_bounds__(256) median_k(
    const float* __restrict__ hh, const float* __restrict__ w_hh,
    float* __restrict__ hh_m) {
  int tid = threadIdx.x;
  int wave = blockIdx.x * 4 + (tid >> 6);
  int lane = tid & 63;
  int b = wave >> 12;
  int hw = wave & 4095;
  int h = hw >> 6, w = hw & 63;
  const float* base = hh + (((size_t)(b * 64 + lane)) << 12);
  float s = 0.f;
#pragma unroll
  for (int kh = 0; kh < 5; ++kh) {
    int ih = h - 2 + kh;
    ih = ih < 0 ? -ih : (ih > 63 ? 126 - ih : ih);
#pragma unroll
    for (int kw = 0; kw < 5; ++kw) {
      int iw = w - 2 + kw;
      iw = iw < 0 ? -iw : (iw > 63 ? 126 - iw : iw);
      s += base[(ih << 6) + iw];
    }
  }
  s *= w_hh[0];
  for (int k = 2; k <= 64; k <<= 1) {
    for (int j = k >> 1; j > 0; j >>= 1) {
      float o = __shfl_xor(s, j, 64);
      bool up = (lane & k) == 0;
      bool low = (lane & j) == 0;
      s = (low == up) ? fminf(s, o) : fmaxf(s, o);
    }
  }
  float v31 = __shfl(s, 31, 64);
  float v32 = __shfl(s, 32, 64);
  if (lane == 0) hh_m[wave] = 0.5f * (v31 + v32);
}

// ---------------- per-channel mean/invstd over (B,H,W) ---------------------
__global__ void __launch_bounds__(256) stats_k(
    const float* __restrict__ x, float* __restrict__ stats, int C, int B) {
  int c = blockIdx.x;
  int tid = threadIdx.x;
  int N = B * HWP;
  float s = 0.f, q = 0.f;
  for (int i = tid; i < N; i += 256) {
    int b = i >> 12, p = i & 4095;
    float v = x[(((size_t)(b * C + c)) << 12) + p];
    s += v;
    q += v * v;
  }
  __shared__ float rs[256], rq[256];
  rs[tid] = s; rq[tid] = q;
  __syncthreads();
  for (int st = 128; st > 0; st >>= 1) {
    if (tid < st) { rs[tid] += rs[tid + st]; rq[tid] += rq[tid + st]; }
    __syncthreads();
  }
  if (tid == 0) {
    float mean = rs[0] / (float)N;
    float var = rq[0] / (float)N - mean * mean;
    stats[c] = mean;
    stats[C + c] = rsqrtf(fmaxf(var, 0.f) + 1e-5f);
  }
}

// ---------------- 1x1 conv (pointwise GEMM) with fused input modes ---------
// input modes as before. out_mode: 0 plain, 1 leaky_relu(0.1),
// 2: write bf16 hi/lo channels-last ci-blocked(32) granule-pre-swizzled.
__global__ void __launch_bounds__(256) conv1x1_k(
    const float* __restrict__ inA, const float* __restrict__ inB, int C1,
    const float* __restrict__ sA, const float* __restrict__ sB,
    const float* __restrict__ bn_stats, const float* __restrict__ bn_g,
    const float* __restrict__ bn_b, const float* __restrict__ extra, int mode,
    const float* __restrict__ wgt, const float* __restrict__ bias,
    float* __restrict__ out, int CIN, int COUT, int out_mode,
    unsigned short* __restrict__ o_hi, unsigned short* __restrict__ o_lo) {
  __shared__ __align__(16) float s_in[16][128];
  __shared__ __align__(16) float s_w[16][32];
  int tid = threadIdx.x;
  int p0 = blockIdx.x * 128;
  int co0 = blockIdx.y * 32;
  int b = blockIdx.z;
  float fA = sA ? sA[0] : 1.f;
  float fB = sB ? sB[0] : 1.f;
  int pi = tid & 63;
  int cog = tid >> 6;
  float acc0[8] = {0.f, 0.f, 0.f, 0.f, 0.f, 0.f, 0.f, 0.f};
  float acc1[8] = {0.f, 0.f, 0.f, 0.f, 0.f, 0.f, 0.f, 0.f};
  for (int ci0 = 0; ci0 < CIN; ci0 += 16) {
#pragma unroll
    for (int t = 0; t < 8; ++t) {
      int idx = tid + t * 256;
      int ci = idx >> 7, pp = idx & 127;
      int c = ci0 + ci;
      int p = p0 + pp;
      float v;
      if (mode == 1) {
        v = (c < C1) ? fA * inA[(((size_t)(b * C1 + c)) << 12) + p]
                     : fB * inB[(((size_t)(b * (CIN - C1) + (c - C1))) << 12) + p];
      } else {
        v = inA[(((size_t)(b * CIN + c)) << 12) + p];
        if (mode == 2) {
          v = (v - bn_stats[c]) * bn_stats[CIN + c] * bn_g[c] + bn_b[c];
          v = fmaxf(v, 0.f);
        } else if (mode == 3) {
          v += extra[(b << 12) + p];
        }
      }
      s_in[ci][pp] = v;
    }
#pragma unroll
    for (int t = 0; t < 2; ++t) {
      int idx = tid + t * 256;
      int ci = idx >> 5, co = idx & 31;
      float wv = 0.f;
      if (co0 + co < COUT) wv = wgt[(size_t)(co0 + co) * CIN + ci0 + ci];
      s_w[ci][co] = wv;
    }
    __syncthreads();
#pragma unroll
    for (int ci = 0; ci < 16; ++ci) {
      float v0 = s_in[ci][pi * 2];
      float v1 = s_in[ci][pi * 2 + 1];
      const float4* wp = (const float4*)&s_w[ci][cog * 8];
#pragma unroll
      for (int q = 0; q < 2; ++q) {
        float4 wv = wp[q];
        float wj[4] = {wv.x, wv.y, wv.z, wv.w};
#pragma unroll
        for (int r = 0; r < 4; ++r) {
          acc0[q * 4 + r] += v0 * wj[r];
          acc1[q * 4 + r] += v1 * wj[r];
        }
      }
    }
    __syncthreads();
  }
  if (out_mode == 2) {
#pragma unroll
    for (int j = 0; j < 8; ++j) {
      int co = co0 + cog * 8 + j;
      float bs = bias[co];
      float r[2] = {acc0[j] + bs, acc1[j] + bs};
      int cb = co >> 5, cil = co & 31, g = cil >> 3, jj = cil & 7;
#pragma unroll
      for (int e = 0; e < 2; ++e) {
        int p = p0 + pi * 2 + e;
        int w = p & 63;
        int gs = g ^ (((w + 2) >> 1) & 3);
        size_t idx = (((size_t)(b * 16 + cb) << 12) + p) * 32 + gs * 8 + jj;
        unsigned short h = f2bf(r[e]);
        o_hi[idx] = h;
        o_lo[idx] = f2bf(r[e] - bf2f(h));
      }
    }
  } else {
#pragma unroll
    for (int j = 0; j < 8; ++j) {
      int co = co0 + cog * 8 + j;
      if (co < COUT) {
        float bs = bias[co];
        float r0 = acc0[j] + bs;
        float r1 = acc1[j] + bs;
        if (out_mode == 1) {
          r0 = r0 < 0.f ? 0.1f * r0 : r0;
          r1 = r1 < 0.f ? 0.1f * r1 : r1;
        }
        float2 rr = make_float2(r0, r1);
        *(float2*)&out[(((size_t)(b * COUT + co)) << 12) + p0 + pi * 2] = rr;
      }
    }
  }
}

// ---------------- e2 weight prep: -> [cbco][cbci][tap][co][ci] bf16 --------
__global__ void __launch_bounds__(256) prep_w_k(const float* __restrict__ w,
                                                unsigned short* __restrict__ Wt) {
  int co = blockIdx.x;  // 0..511
  int cbco = co >> 7, co_l = co & 127;
  const float* src = w + (size_t)co * 12800;
  int gs_x = (co_l >> 1) & 3;
  for (int idx = threadIdx.x; idx < 12800; idx += 256) {
    int ci = idx / 25;
    int tap = idx - ci * 25;
    float v = src[idx];
    int cbci = ci >> 5, cil = ci & 31, g = cil >> 3, j = cil & 7;
    int gsw = g ^ gs_x;
    size_t dst = ((size_t)((cbco * 16 + cbci) * 25 + tap) << 12) +
                 (size_t)co_l * 32 + gsw * 8 + j;
    Wt[dst] = f2bf(v);
  }
}

// ---------------- e2: implicit-GEMM MFMA, split-A bf16 2-product -----------
// Block: 256 thr (4 waves, 2M x 2N). Tile M=128 px (2 rows x 64 cols),
// N=128 co, K = 16 ci-blocks x 25 taps x 32 ci.
// LDS: A[hi 26112][lo 26112] rows 6 x 68 entries x 64B ; B dbuf 2 x 8192.
__global__ void __launch_bounds__(256, 2) e2_mfma_k(
    const unsigned short* __restrict__ y4h, const unsigned short* __restrict__ y4l,
    const unsigned short* __restrict__ Wt, const float* __restrict__ bias,
    float* __restrict__ out) {
  __shared__ __align__(16) char smem[68608];
  const int tid = threadIdx.x;
  const int lane = tid & 63;
  const int wid = tid >> 6;
  int logical = ((blockIdx.x & 7) << 7) + (blockIdx.x >> 3);  // XCD chunking
  int cbco = logical >> 8;
  int rem = logical & 255;
  int rowpair = rem >> 3;
  int b = rem & 7;
  int h0 = rowpair << 1;
  const int wm = wid >> 1, wn = wid & 1;
  const int l15 = lane & 15, lg = lane >> 4;

  int colterm[4][5];
#pragma unroll
  for (int mi = 0; mi < 4; ++mi)
#pragma unroll
    for (int kw = 0; kw < 5; ++kw) {
      int col = mi * 16 + l15 + kw;
      colterm[mi][kw] = col * 64 + ((lg ^ ((col >> 1) & 3)) << 4);
    }
  int bterm[4];
#pragma unroll
  for (int ni = 0; ni < 4; ++ni) {
    int c = wn * 64 + ni * 16 + l15;  // R2 FIX: include wave-N offset
    bterm[ni] = c * 64 + ((lg ^ ((c >> 1) & 3)) << 4);
  }

  // zero halo columns (entries 0,1,66,67) once; never rewritten by staging
  if (tid < 192) {
    int g = tid & 3, e = tid >> 2;
    int part = e / 24, r = e - part * 24;
    int s = r >> 2, cp = r & 3;
    int col = (cp < 2) ? cp : (64 + cp);
    *(float4*)(smem + part * 26112 + s * 4352 + col * 64 + g * 16) =
        make_float4(0.f, 0.f, 0.f, 0.f);
  }

  f32x4 acc[4][4];
#pragma unroll
  for (int i = 0; i < 4; ++i)
#pragma unroll
    for (int j = 0; j < 4; ++j) acc[i][j] = (f32x4)(0.f);

  const int part = wid >> 1;           // staging role: 0 -> hi, 1 -> lo
  const int s0 = (wid & 1) * 3;        // staging rows
  const unsigned short* srcA = part ? y4l : y4h;

#pragma unroll 1
  for (int cb = 0; cb < 16; ++cb) {
    // ---- stage A (6 rows x 64 valid cols x 32ci, hi+lo), linear via gll ----
#pragma unroll
    for (int si = 0; si < 3; ++si) {
      int s = s0 + si;
      int irow = h0 - 2 + s;
      char* ldsrow = smem + part * 26112 + s * 4352 + 128;
      if ((unsigned)irow < 64u) {
        const unsigned short* src =
            srcA + (((size_t)(b * 16 + cb) * 64 + irow) << 11);
#pragma unroll
        for (int c = 0; c < 4; ++c)
          gload16(src + (c << 9) + (lane << 3), ldsrow + (c << 10));
      } else {
#pragma unroll
        for (int c = 0; c < 4; ++c)
          *(float4*)(ldsrow + (c << 10) + (lane << 4)) =
              make_float4(0.f, 0.f, 0.f, 0.f);
      }
    }
    // ---- stage B tap 0 into buf 0 ----
    {
      const unsigned short* src = Wt + ((size_t)((cbco * 16 + cb) * 25) << 12);
#pragma unroll
      for (int k = 0; k < 2; ++k) {
        int c2 = wid * 2 + k;
        gload16(src + (c2 << 9) + (lane << 3), smem + 52224 + (c2 << 10));
      }
    }
    __syncthreads();

#pragma unroll 1
    for (int kh = 0; kh < 5; ++kh) {
      int abase = (wm + kh) * 4352;
#pragma unroll
      for (int kw = 0; kw < 5; ++kw) {
        int tap = kh * 5 + kw;
        if (tap < 24) {  // prefetch next tap's B into other buffer
          const unsigned short* src =
              Wt + ((size_t)((cbco * 16 + cb) * 25 + tap + 1) << 12);
          int buf = (tap + 1) & 1;
#pragma unroll
          for (int k = 0; k < 2; ++k) {
            int c2 = wid * 2 + k;
            gload16(src + (c2 << 9) + (lane << 3),
                    smem + 52224 + (buf << 13) + (c2 << 10));
          }
        }
        char* bbase = smem + 52224 + ((tap & 1) << 13);
        bf16x8 bfr[4];
#pragma unroll
        for (int ni = 0; ni < 4; ++ni)
          bfr[ni] = *(bf16x8*)(bbase + bterm[ni]);
#pragma unroll
        for (int mi = 0; mi < 4; ++mi) {
          bf16x8 ah = *(bf16x8*)(smem + abase + colterm[mi][kw]);
          bf16x8 al = *(bf16x8*)(smem + 26112 + abase + colterm[mi][kw]);
#pragma unroll
          for (int ni = 0; ni < 4; ++ni) {
            acc[mi][ni] = __builtin_amdgcn_mfma_f32_16x16x32_bf16(
                ah, bfr[ni], acc[mi][ni], 0, 0, 0);
            acc[mi][ni] = __builtin_amdgcn_mfma_f32_16x16x32_bf16(
                al, bfr[ni], acc[mi][ni], 0, 0, 0);
          }
        }
        __syncthreads();
      }
    }
  }

  // ---- epilogue: bias + store fp32 NCHW ----
  int row = h0 + wm;
#pragma unroll
  for (int ni = 0; ni < 4; ++ni) {
    int co = cbco * 128 + wn * 64 + ni * 16 + l15;
    float bs = bias[co];
#pragma unroll
    for (int mi = 0; mi < 4; ++mi) {
      int col = mi * 16 + lg * 4;
      f32x4 v = acc[mi][ni];
      v += (f32x4)(bs);
      *(f32x4*)(out + ((size_t)((b * 512 + co) * 64 + row) << 6) + col) = v;
    }
  }
}

// ---------------- generic KxK direct conv, 32x32 tile, 2x2 microtile -------
template <int K, int DIL, int CI_T, int OUTMODE>
__global__ void __launch_bounds__(256) convK_k(
    const float* __restrict__ in, const float* __restrict__ wgt,
    const float* __restrict__ bias, float* __restrict__ out, int CIN, int COUT,
    const float* __restrict__ scale_ptr) {
  constexpr int IH = 32 + (K - 1) * DIL;
  constexpr int IW = 32 + (K - 1) * DIL;
  constexpr int PAD = (K - 1) / 2 * DIL;
  constexpr int KK = K * K;
  __shared__ __align__(16) float s_in[CI_T][IH][IW];
  __shared__ __align__(16) float s_w[CI_T * KK * 16];
  int tid = threadIdx.x;
  int tx = tid & 15, ty = tid >> 4;
  int w0 = blockIdx.x * 32, h0 = blockIdx.y * 32;
  int ncog = COUT >> 4;
  int cog = blockIdx.z % ncog;
  int b = blockIdx.z / ncog;
  int co0 = cog << 4;
  float scale = scale_ptr ? scale_ptr[0] : 1.f;
  float a00[16] = {}, a01[16] = {}, a10[16] = {}, a11[16] = {};
  for (int ci0 = 0; ci0 < CIN; ci0 += CI_T) {
    for (int idx = tid; idx < CI_T * IH * IW; idx += 256) {
      int ci = idx / (IH * IW);
      int r = idx - ci * (IH * IW);
      int iy = r / IW;
      int ix = r - iy * IW;
      int gh = h0 - PAD + iy, gw = w0 - PAD + ix;
      float v = 0.f;
      if ((unsigned)gh < 64u && (unsigned)gw < 64u)
        v = in[((((size_t)(b * CIN + ci0 + ci)) << 6) + (size_t)gh << 6) + gw] * scale;
      s_in[ci][iy][ix] = v;
    }
    for (int idx = tid; idx < CI_T * KK * 16; idx += 256) {
      int co = idx & 15;
      int t = (idx >> 4) % KK;
      int ci = (idx >> 4) / KK;
      s_w[(ci * KK + t) * 16 + co] =
          wgt[((size_t)(co0 + co) * CIN + ci0 + ci) * KK + t];
    }
    __syncthreads();
    for (int ci = 0; ci < CI_T; ++ci) {
#pragma unroll
      for (int t = 0; t < KK; ++t) {
        int kh = t / K, kw = t - (t / K) * K;
        int iy = ty * 2 + kh * DIL, ix = tx * 2 + kw * DIL;
        float v00 = s_in[ci][iy][ix];
        float v01 = s_in[ci][iy][ix + 1];
        float v10 = s_in[ci][iy + 1][ix];
        float v11 = s_in[ci][iy + 1][ix + 1];
        const float4* wp = (const float4*)&s_w[(ci * KK + t) * 16];
#pragma unroll
        for (int q = 0; q < 4; ++q) {
          float4 wv = wp[q];
          float wj[4] = {wv.x, wv.y, wv.z, wv.w};
#pragma unroll
          for (int r = 0; r < 4; ++r) {
            a00[q * 4 + r] += v00 * wj[r];
            a01[q * 4 + r] += v01 * wj[r];
            a10[q * 4 + r] += v10 * wj[r];
            a11[q * 4 + r] += v11 * wj[r];
          }
        }
      }
    }
    __syncthreads();
  }
  int oh = h0 + ty * 2, ow = w0 + tx * 2;
#pragma unroll
  for (int j = 0; j < 16; ++j) {
    int co = co0 + j;
    float bs = bias[co];
    float r00 = a00[j] + bs, r01 = a01[j] + bs;
    float r10 = a10[j] + bs, r11 = a11[j] + bs;
    if (OUTMODE == 1) {
      r00 = tanhf(r00); r01 = tanhf(r01);
      r10 = tanhf(r10); r11 = tanhf(r11);
    }
    size_t ob = ((((size_t)(b * COUT + co)) << 6) + (size_t)oh) << 6;
    *(float2*)&out[ob + ow] = make_float2(r00, r01);
    *(float2*)&out[ob + 64 + ow] = make_float2(r10, r11);
  }
}

// ---------------- sigmoid gate: hl_l1 / lh_l1 ------------------------------
__global__ void __launch_bounds__(256) gate_k(
    const float* __restrict__ y7, const float* __restrict__ st,
    const float* __restrict__ g, const float* __restrict__ bb,
    const float* __restrict__ hl_freq, const float* __restrict__ lh_freq,
    const float* __restrict__ w_hl, const float* __restrict__ w_lh,
    float* __restrict__ hl_l1, float* __restrict__ lh_l1) {
  int i = blockIdx.x * 256 + threadIdx.x;
  int p = i & 4095;
  int c = (i >> 12) & 127;
  int b = i >> 19;
  float nv = (y7[i] - st[c]) * st[128 + c] * g[c] + bb[c];
  float sig = 1.f / (1.f + expf(-nv));
  if (c < 64) {
    size_t k = (((size_t)(b * 64 + c)) << 12) + p;
    hl_l1[k] = w_hl[0] * hl_freq[k] * sig;
  } else {
    size_t k = (((size_t)(b * 64 + (c - 64))) << 12) + p;
    lh_l1[k] = w_lh[0] * lh_freq[k] * sig;
  }
}

// ---------------- Haar IDWT ------------------------------------------------
__global__ void __launch_bounds__(256) idwt_k(
    const float* __restrict__ ca, const float* __restrict__ ch,
    const float* __restrict__ cv, const float* __restrict__ cd,
    float* __restrict__ out) {
  int i = blockIdx.x * 256 + threadIdx.x;
  float A = ca[i], Hd = ch[i], V = cv[i], D = cd[i];
  float y00 = (A + Hd + V + D) * 0.5f;
  float y01 = (A + Hd - V - D) * 0.5f;
  float y10 = (A - Hd + V - D) * 0.5f;
  float y11 = (A - Hd - V + D) * 0.5f;
  int w = i & 63;
  int h = (i >> 6) & 63;
  int bc = i >> 12;
  size_t ob = (((size_t)bc * 128) + 2 * h) * 128 + 2 * w;
  *(float2*)&out[ob] = make_float2(y00, y01);
  *(float2*)&out[ob + 128] = make_float2(y10, y11);
}

// ---------------------------------------------------------------------------
extern "C" void kernel_launch(void* const* d_in, const int* in_sizes, int n_in,
                              void* d_out, int out_size, void* d_ws,
                              size_t ws_size, hipStream_t stream) {
  const float* ll_freq = (const float*)d_in[0];
  const float* hl_freq = (const float*)d_in[1];
  const float* lh_freq = (const float*)d_in[2];
  const float* hh_freq = (const float*)d_in[3];
  const float* w_ll = (const float*)d_in[4];
  const float* w_hl = (const float*)d_in[5];
  const float* w_lh = (const float*)d_in[6];
  const float* w_hh = (const float*)d_in[7];
  const float* cc_w = (const float*)d_in[8];
  const float* cc_b = (const float*)d_in[9];
  const float* bnc_g = (const float*)d_in[10];
  const float* bnc_b = (const float*)d_in[11];
  const float* e1_w = (const float*)d_in[12];
  const float* e1_b = (const float*)d_in[13];
  const float* fe_w = (const float*)d_in[14];
  const float* fe_b = (const float*)d_in[15];
  const float* e2_w = (const float*)d_in[16];
  const float* e2_b = (const float*)d_in[17];
  const float* bne_g = (const float*)d_in[18];
  const float* bne_b = (const float*)d_in[19];
  const float* cr_w = (const float*)d_in[20];
  const float* cr_b = (const float*)d_in[21];
  const float* bnr_g = (const float*)d_in[22];
  const float* bnr_b = (const float*)d_in[23];
  const float* adj_w = (const float*)d_in[24];
  const float* adj_b = (const float*)d_in[25];
  const float* cll_w = (const float*)d_in[26];
  const float* cll_b = (const float*)d_in[27];
  const float* chh_w = (const float*)d_in[28];
  const float* chh_b = (const float*)d_in[29];
  const float* c1_w = (const float*)d_in[30];
  const float* c1_b = (const float*)d_in[31];
  const float* c3_w = (const float*)d_in[32];
  const float* c3_b = (const float*)d_in[33];
  const float* c5_w = (const float*)d_in[34];
  const float* c5_b = (const float*)d_in[35];

  const size_t MB = 1ull << 20;
  char* ws = (char*)d_ws;
  unsigned short* y4h = (unsigned short*)(ws);            // 32MB
  unsigned short* y4l = (unsigned short*)(ws + 32 * MB);  // 32MB
  float* regA = (float*)(ws);                             // reused post-e2
  float* regB = (float*)(ws + 64 * MB);                   // 64MB
  float* y7   = (float*)(ws + 128 * MB);                  // 16MB
  float* y1   = (float*)(ws + 144 * MB);                  // 2MB
  float* y2   = (float*)(ws + 146 * MB);                  // 2MB
  unsigned short* Wt = (unsigned short*)(ws + 148 * MB);  // 13.1MB
  float* hh_m = (float*)(ws + 162 * MB);                  // 128KB
  float* st1  = (float*)(ws + 163 * MB);
  float* st2  = st1 + 1024;
  float* st3  = st2 + 2048;

  const size_t F2M = 2097152;
  float* ll_a  = regA + 0 * F2M;
  float* ll_b  = regA + 1 * F2M;
  float* ll_l2 = regA + 2 * F2M;
  float* hl_l1 = regA + 3 * F2M;
  float* lh_l1 = regA + 4 * F2M;
  float* hl_l2 = regA + 5 * F2M;
  float* lh_l2 = regA + 6 * F2M;
  float* hh_a  = regA + 7 * F2M;
  float* hh_l2 = regB;

  dim3 blk(256);

  // weight prep for e2 (independent)
  prep_w_k<<<dim3(512), blk, 0, stream>>>(e2_w, Wt);

  // 1. hh_m
  median_k<<<dim3(8192), blk, 0, stream>>>(hh_freq, w_hh, hh_m);

  // 2. cc 1x1 on concat(w_hl*hl, w_lh*lh): 128->16
  conv1x1_k<<<dim3(32, 1, 8), blk, 0, stream>>>(
      hl_freq, lh_freq, 64, w_hl, w_lh, nullptr, nullptr, nullptr, nullptr, 1,
      cc_w, cc_b, y1, 128, 16, 0, nullptr, nullptr);

  // 3. e1 3x3 16->16
  convK_k<3, 1, 8, 0><<<dim3(2, 2, 8), blk, 0, stream>>>(y1, e1_w, e1_b, y2, 16,
                                                         16, nullptr);
  // 4. bnc stats
  stats_k<<<dim3(16), blk, 0, stream>>>(y2, st1, 16, 8);

  // 5. fe 1x1 16->512, input relu(bn(y2)); out: bf16 hi/lo channels-last
  conv1x1_k<<<dim3(32, 16, 8), blk, 0, stream>>>(
      y2, nullptr, 0, nullptr, nullptr, st1, bnc_g, bnc_b, nullptr, 2, fe_w,
      fe_b, nullptr, 16, 512, 2, y4h, y4l);

  // 6. e2 5x5 512->512 via MFMA implicit GEMM
  e2_mfma_k<<<dim3(1024), blk, 0, stream>>>(y4h, y4l, Wt, e2_b, regB);

  // 7. bne stats
  stats_k<<<dim3(512), blk, 0, stream>>>(regB, st2, 512, 8);

  // 8. cr 1x1 512->128, input relu(bn(y5))
  conv1x1_k<<<dim3(32, 4, 8), blk, 0, stream>>>(
      regB, nullptr, 0, nullptr, nullptr, st2, bne_g, bne_b, nullptr, 2, cr_w,
      cr_b, y7, 512, 128, 0, nullptr, nullptr);

  // 9. bnr stats
  stats_k<<<dim3(128), blk, 0, stream>>>(y7, st3, 128, 8);

  // 10. gate
  gate_k<<<dim3(16384), blk, 0, stream>>>(y7, st3, bnr_g, bnr_b, hl_freq,
                                          lh_freq, w_hl, w_lh, hl_l1, lh_l1);

  // 11-13. LL branch
  convK_k<3, 1, 8, 0><<<dim3(2, 2, 32), blk, 0, stream>>>(
      ll_freq, c1_w, c1_b, ll_a, 64, 64, w_ll);
  convK_k<5, 1, 8, 0><<<dim3(2, 2, 32), blk, 0, stream>>>(ll_a, c3_w, c3_b,
                                                          ll_b, 64, 64, nullptr);
  convK_k<7, 1, 8, 0><<<dim3(2, 2, 32), blk, 0, stream>>>(ll_b, c5_w, c5_b,
                                                          ll_a, 64, 64, nullptr);

  // 14-16. adj convs
  conv1x1_k<<<dim3(32, 2, 8), blk, 0, stream>>>(
      ll_a, ll_freq, 64, nullptr, w_ll, nullptr, nullptr, nullptr, nullptr, 1,
      adj_w, adj_b, ll_l2, 128, 64, 0, nullptr, nullptr);
  conv1x1_k<<<dim3(32, 2, 8), blk, 0, stream>>>(
      hl_l1, hl_freq, 64, nullptr, nullptr, nullptr, nullptr, nullptr, nullptr,
      1, adj_w, adj_b, hl_l2, 128, 64, 0, nullptr, nullptr);
  conv1x1_k<<<dim3(32, 2, 8), blk, 0, stream>>>(
      lh_l1, lh_freq, 64, nullptr, nullptr, nullptr, nullptr, nullptr, nullptr,
      1, adj_w, adj_b, lh_l2, 128, 64, 0, nullptr, nullptr);

  // 17. hh_a = leaky_relu(chh(hh_freq + hh_m))
  conv1x1_k<<<dim3(32, 2, 8), blk, 0, stream>>>(
      hh_freq, nullptr, 0, nullptr, nullptr, nullptr, nullptr, nullptr, hh_m, 3,
      chh_w, chh_b, hh_a, 64, 64, 1, nullptr, nullptr);

  // 18. hh_l2 = tanh(cll 5x5 dil2 of hh_a)
  convK_k<5, 2, 8, 1><<<dim3(2, 2, 32), blk, 0, stream>>>(
      hh_a, cll_w, cll_b, hh_l2, 64, 64, nullptr);

  // 19. IDWT
  idwt_k<<<dim3(8192), blk, 0, stream>>>(ll_l2, hl_l2, lh_l2, hh_l2,
                                         (float*)d_out);
}

// Round 4
// 1555.278 us; speedup vs baseline: 5.4233x; 1.7739x over previous
//
#include <hip/hip_runtime.h>
#include <math.h>

// ---------------------------------------------------------------------------
// FeatureProcessor forward. B=8, C=64, H=W=64, RED=16, EXP=512.
// e2 + c1/c3/c5/cll run on bf16 MFMA implicit GEMM with split-A 2-product
// (activations exact as hi+lo bf16, weights bf16-rounded).
//
// Workspace layout:
//   [0,64M) regA: pre-e2 = y4h(32M)+y4l(32M) (fe out, e2 in).
//     post-e2 reuse: ll_a[0,8) ll_l2[8,16) hl_l1[16,24) lh_l1[24,32)
//                    hl_l2[32,40) lh_l2[40,48) Ph[48,52) Pl[52,56)
//                    Qh[56,60) Ql[60,64)
//   [64M,128M) regB: pre-e2 = boxsum S[64,72); then e2 out fp32 NCHW;
//                    post-cr reuse: hh_l2[64,72)
//   [128M,144M) y7 ; [144M,146M) y1 ; [146M,148M) y2
//   [148M,~161M) Wt e2 weights bf16 [cbco4][cbci16][tap25][co128][ci32]
//   [162M,163.5M) hh_m, stats, small-conv weights
// ---------------------------------------------------------------------------

#define HWP 4096

typedef __attribute__((ext_vector_type(8))) short bf16x8;
typedef __attribute__((ext_vector_type(4))) float f32x4;

__device__ __forceinline__ unsigned short f2bf(float x) {
  unsigned int u = __float_as_uint(x);
  unsigned int r = (u + 0x7fffu + ((u >> 16) & 1u)) >> 16;
  return (unsigned short)r;
}
__device__ __forceinline__ float bf2f(unsigned short h) {
  return __uint_as_float(((unsigned int)h) << 16);
}

__device__ __forceinline__ void gload16(const void* g, void* l) {
  __builtin_amdgcn_global_load_lds(
      (const __attribute__((address_space(1))) unsigned int*)g,
      (__attribute__((address_space(3))) unsigned int*)l, 16, 0, 0);
}

// ---------------- box-sum 5x5 reflect (per b,c), out NCHW ------------------
__global__ void __launch_bounds__(256) boxsum_k(
    const float* __restrict__ hh, const float* __restrict__ w_hh,
    float* __restrict__ S) {
  __shared__ float img[64][65];
  __shared__ float rs[64][65];
  int bc = blockIdx.x;  // b*64+c
  const float* src = hh + ((size_t)bc << 12);
  float wv = w_hh[0];
  int tid = threadIdx.x;
  for (int i = tid; i < 4096; i += 256) img[i >> 6][i & 63] = src[i] * wv;
  __syncthreads();
  for (int i = tid; i < 4096; i += 256) {
    int h = i >> 6, w = i & 63;
    float s = 0.f;
#pragma unroll
    for (int d = -2; d <= 2; ++d) {
      int ww = w + d;
      ww = ww < 0 ? -ww : (ww > 63 ? 126 - ww : ww);
      s += img[h][ww];
    }
    rs[h][w] = s;
  }
  __syncthreads();
  float* dst = S + ((size_t)bc << 12);
  for (int i = tid; i < 4096; i += 256) {
    int h = i >> 6, w = i & 63;
    float s = 0.f;
#pragma unroll
    for (int d = -2; d <= 2; ++d) {
      int h2 = h + d;
      h2 = h2 < 0 ? -h2 : (h2 > 63 ? 126 - h2 : h2);
      s += rs[h2][w];
    }
    dst[i] = s;
  }
}

// ---------------- median over 64 channels (wave bitonic, LDS transpose) ----
__global__ void __launch_bounds__(256) med_k(const float* __restrict__ S,
                                             float* __restrict__ hh_m) {
  __shared__ float ldsS[64][65];
  int bx = blockIdx.x;  // b*64 + h
  int b = bx >> 6, h = bx & 63;
  int tid = threadIdx.x;
  for (int i = tid; i < 4096; i += 256) {
    int c = i >> 6, w = i & 63;
    ldsS[c][w] = S[((size_t)(b * 64 + c) << 12) + (h << 6) + w];
  }
  __syncthreads();
  int lane = tid & 63, wv = tid >> 6;
  for (int i = 0; i < 16; ++i) {
    int w = wv * 16 + i;
    float s = ldsS[lane][w];
    for (int k = 2; k <= 64; k <<= 1)
      for (int j = k >> 1; j > 0; j >>= 1) {
        float o = __shfl_xor(s, j, 64);
        bool up = (lane & k) == 0;
        bool low = (lane & j) == 0;
        s = (low == up) ? fminf(s, o) : fmaxf(s, o);
      }
    float v31 = __shfl(s, 31, 64);
    float v32 = __shfl(s, 32, 64);
    if (lane == 0) hh_m[(b << 12) + (h << 6) + w] = 0.5f * (v31 + v32);
  }
}

// ---------------- per-channel mean/invstd over (B,H,W) ---------------------
__global__ void __launch_bounds__(256) stats_k(
    const float* __restrict__ x, float* __restrict__ stats, int C, int B) {
  int c = blockIdx.x;
  int tid = threadIdx.x;
  int N = B * HWP;
  float s = 0.f, q = 0.f;
  for (int i = tid; i < N; i += 256) {
    int b = i >> 12, p = i & 4095;
    float v = x[(((size_t)(b * C + c)) << 12) + p];
    s += v;
    q += v * v;
  }
  __shared__ float rs[256], rq[256];
  rs[tid] = s; rq[tid] = q;
  __syncthreads();
  for (int st = 128; st > 0; st >>= 1) {
    if (tid < st) { rs[tid] += rs[tid + st]; rq[tid] += rq[tid + st]; }
    __syncthreads();
  }
  if (tid == 0) {
    float mean = rs[0] / (float)N;
    float var = rq[0] / (float)N - mean * mean;
    stats[c] = mean;
    stats[C + c] = rsqrtf(fmaxf(var, 0.f) + 1e-5f);
  }
}

// ---------------- 1x1 conv (pointwise GEMM) with fused input modes ---------
// input modes: 0 plain; 1 concat(sA*inA, sB*inB); 2 relu(bn(inA));
//              3 inA + extra broadcast.
// out modes:   0 plain fp32 NCHW; 1 leaky_relu(0.1) fp32 NCHW;
//              2 bf16 hi/lo channels-last swizzled; 3 leaky + mode-2.
__global__ void __launch_bounds__(256) conv1x1_k(
    const float* __restrict__ inA, const float* __restrict__ inB, int C1,
    const float* __restrict__ sA, const float* __restrict__ sB,
    const float* __restrict__ bn_stats, const float* __restrict__ bn_g,
    const float* __restrict__ bn_b, const float* __restrict__ extra, int mode,
    const float* __restrict__ wgt, const float* __restrict__ bias,
    float* __restrict__ out, int CIN, int COUT, int out_mode,
    unsigned short* __restrict__ o_hi, unsigned short* __restrict__ o_lo) {
  __shared__ __align__(16) float s_in[16][128];
  __shared__ __align__(16) float s_w[16][32];
  __shared__ __align__(16) short sOH[4096];
  __shared__ __align__(16) short sOL[4096];
  int tid = threadIdx.x;
  int p0 = blockIdx.x * 128;
  int co0 = blockIdx.y * 32;
  int b = blockIdx.z;
  float fA = sA ? sA[0] : 1.f;
  float fB = sB ? sB[0] : 1.f;
  int pi = tid & 63;
  int cog = tid >> 6;
  float acc0[8] = {0.f, 0.f, 0.f, 0.f, 0.f, 0.f, 0.f, 0.f};
  float acc1[8] = {0.f, 0.f, 0.f, 0.f, 0.f, 0.f, 0.f, 0.f};
  for (int ci0 = 0; ci0 < CIN; ci0 += 16) {
#pragma unroll
    for (int t = 0; t < 8; ++t) {
      int idx = tid + t * 256;
      int ci = idx >> 7, pp = idx & 127;
      int c = ci0 + ci;
      int p = p0 + pp;
      float v;
      if (mode == 1) {
        v = (c < C1) ? fA * inA[(((size_t)(b * C1 + c)) << 12) + p]
                     : fB * inB[(((size_t)(b * (CIN - C1) + (c - C1))) << 12) + p];
      } else {
        v = inA[(((size_t)(b * CIN + c)) << 12) + p];
        if (mode == 2) {
          v = (v - bn_stats[c]) * bn_stats[CIN + c] * bn_g[c] + bn_b[c];
          v = fmaxf(v, 0.f);
        } else if (mode == 3) {
          v += extra[(b << 12) + p];
        }
      }
      s_in[ci][pp] = v;
    }
#pragma unroll
    for (int t = 0; t < 2; ++t) {
      int idx = tid + t * 256;
      int ci = idx >> 5, co = idx & 31;
      float wv = 0.f;
      if (co0 + co < COUT) wv = wgt[(size_t)(co0 + co) * CIN + ci0 + ci];
      s_w[ci][co] = wv;
    }
    __syncthreads();
#pragma unroll
    for (int ci = 0; ci < 16; ++ci) {
      float2 v01 = *(const float2*)&s_in[ci][pi * 2];
      const float4* wp = (const float4*)&s_w[ci][cog * 8];
#pragma unroll
      for (int q = 0; q < 2; ++q) {
        float4 wv = wp[q];
        float wj[4] = {wv.x, wv.y, wv.z, wv.w};
#pragma unroll
        for (int r = 0; r < 4; ++r) {
          acc0[q * 4 + r] += v01.x * wj[r];
          acc1[q * 4 + r] += v01.y * wj[r];
        }
      }
    }
    __syncthreads();
  }
  if (out_mode >= 2) {
    // scatter to LDS tile [128 px][32 ch swizzled], then linear copy out
#pragma unroll
    for (int j = 0; j < 8; ++j) {
      int co = co0 + cog * 8 + j;
      float bs = bias[co];
      float r[2] = {acc0[j] + bs, acc1[j] + bs};
#pragma unroll
      for (int e = 0; e < 2; ++e) {
        float v = r[e];
        if (out_mode == 3) v = v < 0.f ? 0.1f * v : v;
        int px = pi * 2 + e;
        int w = px & 63;
        int slot = ((cog ^ ((w >> 1) & 3)) << 3) + j;
        int o = px * 32 + slot;
        unsigned short hsh = f2bf(v);
        sOH[o] = (short)hsh;
        sOL[o] = (short)f2bf(v - bf2f(hsh));
      }
    }
    __syncthreads();
    int cb = co0 >> 5;
    size_t base = (size_t)(b * (COUT >> 5) + cb) * 131072 + (size_t)p0 * 32;
    for (int k = tid; k < 512; k += 256) {
      *(float4*)(o_hi + base + (size_t)k * 8) = *(float4*)&sOH[k * 8];
      *(float4*)(o_lo + base + (size_t)k * 8) = *(float4*)&sOL[k * 8];
    }
  } else {
#pragma unroll
    for (int j = 0; j < 8; ++j) {
      int co = co0 + cog * 8 + j;
      if (co < COUT) {
        float bs = bias[co];
        float r0 = acc0[j] + bs;
        float r1 = acc1[j] + bs;
        if (out_mode == 1) {
          r0 = r0 < 0.f ? 0.1f * r0 : r0;
          r1 = r1 < 0.f ? 0.1f * r1 : r1;
        }
        float2 rr = make_float2(r0, r1);
        *(float2*)&out[(((size_t)(b * COUT + co)) << 12) + p0 + pi * 2] = rr;
      }
    }
  }
}

// ---------------- pack NCHW fp32 -> channels-last hi/lo bf16 (swizzled) ----
__global__ void __launch_bounds__(256) pack_k(
    const float* __restrict__ in, const float* __restrict__ scale_ptr,
    unsigned short* __restrict__ o_hi, unsigned short* __restrict__ o_lo) {
  __shared__ float lds[32][130];
  int bx = blockIdx.x;  // b*64 + cb*32 + pchunk(32)
  int pc = bx & 31, cb = (bx >> 5) & 1, b = bx >> 6;
  int p0 = pc * 128;
  float sc = scale_ptr ? scale_ptr[0] : 1.f;
  int tid = threadIdx.x;
  for (int i = tid; i < 4096; i += 256) {
    int c = i >> 7, px = i & 127;
    lds[c][px] = in[((size_t)(b * 64 + cb * 32 + c) << 12) + p0 + px] * sc;
  }
  __syncthreads();
  size_t base = (size_t)(b * 2 + cb) * 131072 + (size_t)p0 * 32;
  for (int k = tid; k < 512; k += 256) {
    int p = k >> 2, gsw = k & 3;
    int w = p & 63;
    int g = gsw ^ ((w >> 1) & 3);
    bf16x8 hi, lo;
#pragma unroll
    for (int j = 0; j < 8; ++j) {
      float v = lds[g * 8 + j][p];
      unsigned short h = f2bf(v);
      hi[j] = (short)h;
      lo[j] = (short)f2bf(v - bf2f(h));
    }
    *(bf16x8*)(o_hi + base + (size_t)k * 8) = hi;
    *(bf16x8*)(o_lo + base + (size_t)k * 8) = lo;
  }
}

// ---------------- e2 weight prep (dst-linear, coalesced writes) ------------
__global__ void __launch_bounds__(256) prep_w_k(const float* __restrict__ w,
                                                unsigned short* __restrict__ Wt) {
  int bx = blockIdx.x;  // (cbco*16 + cbci)*25 + tap
  int cbco = bx / 400;
  int r = bx - cbco * 400;
  int cbci = r / 25, tap = r - cbci * 25;
  unsigned short* dst = Wt + (size_t)bx * 4096;
  for (int d = threadIdx.x; d < 4096; d += 256) {
    int co_l = d >> 5, s = d & 31;
    int g = (s >> 3) ^ ((co_l >> 1) & 3);
    int cil = (g << 3) + (s & 7);
    dst[d] = f2bf(w[((size_t)(cbco * 128 + co_l) * 512 + cbci * 32 + cil) * 25 + tap]);
  }
}

// ---------------- small-conv weight prep: [cbci][tap][co64][ci32] ----------
__global__ void __launch_bounds__(256) prep_ws_k(const float* __restrict__ w,
                                                 unsigned short* __restrict__ Wt,
                                                 int CIN, int KK) {
  int bx = blockIdx.x;  // cbci*KK + tap
  int cbci = bx / KK, tap = bx - cbci * KK;
  unsigned short* dst = Wt + (size_t)bx * 2048;
  for (int d = threadIdx.x; d < 2048; d += 256) {
    int co = d >> 5, s = d & 31;
    int g = (s >> 3) ^ ((co >> 1) & 3);
    int cil = (g << 3) + (s & 7);
    dst[d] = f2bf(w[(size_t)(co * CIN + cbci * 32 + cil) * KK + tap]);
  }
}

// ---------------- e2: implicit-GEMM MFMA, split-A bf16 2-product -----------
__global__ void __launch_bounds__(256, 2) e2_mfma_k(
    const unsigned short* __restrict__ y4h, const unsigned short* __restrict__ y4l,
    const unsigned short* __restrict__ Wt, const float* __restrict__ bias,
    float* __restrict__ out) {
  __shared__ __align__(16) char smem[68608];
  const int tid = threadIdx.x;
  const int lane = tid & 63;
  const int wid = tid >> 6;
  int logical = ((blockIdx.x & 7) << 7) + (blockIdx.x >> 3);  // XCD chunking
  int cbco = logical >> 8;
  int rem = logical & 255;
  int rowpair = rem >> 3;
  int b = rem & 7;
  int h0 = rowpair << 1;
  const int wm = wid >> 1, wn = wid & 1;
  const int l15 = lane & 15, lg = lane >> 4;

  int colterm[4][5];
#pragma unroll
  for (int mi = 0; mi < 4; ++mi)
#pragma unroll
    for (int kw = 0; kw < 5; ++kw) {
      int col = mi * 16 + l15 + kw;  // entry = w_in + 2
      colterm[mi][kw] = col * 64 + ((lg ^ (((col + 62) >> 1) & 3)) << 4);
    }
  int bterm[4];
#pragma unroll
  for (int ni = 0; ni < 4; ++ni) {
    int c = wn * 64 + ni * 16 + l15;
    bterm[ni] = c * 64 + ((lg ^ ((c >> 1) & 3)) << 4);
  }

  if (tid < 192) {  // zero halo columns 0,1,66,67
    int g = tid & 3, e = tid >> 2;
    int part = e / 24, r = e - part * 24;
    int s = r >> 2, cp = r & 3;
    int col = (cp < 2) ? cp : (64 + cp);
    *(float4*)(smem + part * 26112 + s * 4352 + col * 64 + g * 16) =
        make_float4(0.f, 0.f, 0.f, 0.f);
  }

  f32x4 acc[4][4];
#pragma unroll
  for (int i = 0; i < 4; ++i)
#pragma unroll
    for (int j = 0; j < 4; ++j) acc[i][j] = (f32x4)(0.f);

  const int part = wid >> 1;
  const int s0 = (wid & 1) * 3;
  const unsigned short* srcA = part ? y4l : y4h;

#pragma unroll 1
  for (int cb = 0; cb < 16; ++cb) {
#pragma unroll
    for (int si = 0; si < 3; ++si) {
      int s = s0 + si;
      int irow = h0 - 2 + s;
      char* ldsrow = smem + part * 26112 + s * 4352 + 128;
      if ((unsigned)irow < 64u) {
        const unsigned short* src =
            srcA + (((size_t)(b * 16 + cb) * 64 + irow) << 11);
#pragma unroll
        for (int c = 0; c < 4; ++c)
          gload16(src + (c << 9) + (lane << 3), ldsrow + (c << 10));
      } else {
#pragma unroll
        for (int c = 0; c < 4; ++c)
          *(float4*)(ldsrow + (c << 10) + (lane << 4)) =
              make_float4(0.f, 0.f, 0.f, 0.f);
      }
    }
    {
      const unsigned short* src = Wt + ((size_t)((cbco * 16 + cb) * 25) << 12);
#pragma unroll
      for (int k = 0; k < 2; ++k) {
        int c2 = wid * 2 + k;
        gload16(src + (c2 << 9) + (lane << 3), smem + 52224 + (c2 << 10));
      }
    }
    __syncthreads();

#pragma unroll 1
    for (int kh = 0; kh < 5; ++kh) {
      int abase = (wm + kh) * 4352;
#pragma unroll
      for (int kw = 0; kw < 5; ++kw) {
        int tap = kh * 5 + kw;
        if (tap < 24) {
          const unsigned short* src =
              Wt + ((size_t)((cbco * 16 + cb) * 25 + tap + 1) << 12);
          int buf = (tap + 1) & 1;
#pragma unroll
          for (int k = 0; k < 2; ++k) {
            int c2 = wid * 2 + k;
            gload16(src + (c2 << 9) + (lane << 3),
                    smem + 52224 + (buf << 13) + (c2 << 10));
          }
        }
        char* bbase = smem + 52224 + ((tap & 1) << 13);
        bf16x8 bfr[4];
#pragma unroll
        for (int ni = 0; ni < 4; ++ni)
          bfr[ni] = *(bf16x8*)(bbase + bterm[ni]);
#pragma unroll
        for (int mi = 0; mi < 4; ++mi) {
          bf16x8 ah = *(bf16x8*)(smem + abase + colterm[mi][kw]);
          bf16x8 al = *(bf16x8*)(smem + 26112 + abase + colterm[mi][kw]);
#pragma unroll
          for (int ni = 0; ni < 4; ++ni) {
            acc[mi][ni] = __builtin_amdgcn_mfma_f32_16x16x32_bf16(
                ah, bfr[ni], acc[mi][ni], 0, 0, 0);
            acc[mi][ni] = __builtin_amdgcn_mfma_f32_16x16x32_bf16(
                al, bfr[ni], acc[mi][ni], 0, 0, 0);
          }
        }
        __syncthreads();
      }
    }
  }

  int row = h0 + wm;
#pragma unroll
  for (int ni = 0; ni < 4; ++ni) {
    int co = cbco * 128 + wn * 64 + ni * 16 + l15;
    float bs = bias[co];
#pragma unroll
    for (int mi = 0; mi < 4; ++mi) {
      int col = mi * 16 + lg * 4;
      f32x4 v = acc[mi][ni];
      v += (f32x4)(bs);
      *(f32x4*)(out + (((size_t)(b * 512 + co) * 64 + row) << 6) + col) = v;
    }
  }
}

// ---------------- small KxK conv via MFMA (CIN=COUT=64, split-A) -----------
// OUTMODE 0: bf16 hi/lo channels-last swizzled (for chain)
// OUTMODE 1: fp32 NCHW; OUTMODE 2: tanh + fp32 NCHW
template <int K, int DIL, int OUTMODE>
__global__ void __launch_bounds__(256, 2) convmf_k(
    const unsigned short* __restrict__ inh, const unsigned short* __restrict__ inl,
    const unsigned short* __restrict__ Wsm, const float* __restrict__ bias,
    float* __restrict__ out_f, unsigned short* __restrict__ o_hi,
    unsigned short* __restrict__ o_lo) {
  constexpr int PAD = (K - 1) / 2 * DIL;
  constexpr int ROWS = 2 + 2 * PAD;
  constexpr int CW = 64 + 2 * PAD;
  constexpr int RB = CW * 64;
  constexpr int ABYTES = ROWS * RB;
  constexpr int KK = K * K;
  __shared__ __align__(16) char smem[2 * ABYTES + 8192];
  const int tid = threadIdx.x;
  const int lane = tid & 63;
  const int wid = tid >> 6;
  const int b = blockIdx.x >> 5;
  const int h0 = (blockIdx.x & 31) << 1;
  const int wm = wid >> 1, wn = wid & 1;
  const int l15 = lane & 15, lg = lane >> 4;

  int colterm[4][K];
#pragma unroll
  for (int mi = 0; mi < 4; ++mi)
#pragma unroll
    for (int kw = 0; kw < K; ++kw) {
      int e = mi * 16 + l15 + kw * DIL;  // entry = w_in + PAD
      colterm[mi][kw] = e * 64 + ((lg ^ (((e - PAD + 64) >> 1) & 3)) << 4);
    }
  int bterm[2];
#pragma unroll
  for (int ni = 0; ni < 2; ++ni) {
    int c = wn * 32 + ni * 16 + l15;
    bterm[ni] = c * 64 + ((lg ^ ((c >> 1) & 3)) << 4);
  }

  // zero halo entries (2*PAD per row, both parts)
  for (int i = tid; i < 2 * ROWS * 2 * PAD * 4; i += 256) {
    int c4 = i & 3;
    int r1 = i >> 2;
    int e = r1 % (2 * PAD);
    int r2 = r1 / (2 * PAD);
    int r = r2 % ROWS;
    int part = r2 / ROWS;
    int col = (e < PAD) ? e : (e + 64);
    *(float4*)(smem + part * ABYTES + r * RB + col * 64 + c4 * 16) =
        make_float4(0.f, 0.f, 0.f, 0.f);
  }

  f32x4 acc[4][2];
#pragma unroll
  for (int i = 0; i < 4; ++i)
#pragma unroll
    for (int j = 0; j < 2; ++j) acc[i][j] = (f32x4)(0.f);

  const int part = wid >> 1;
  const int s0 = (wid & 1) * (ROWS / 2);
  const unsigned short* srcA = part ? inl : inh;

#pragma unroll 1
  for (int cb = 0; cb < 2; ++cb) {
#pragma unroll
    for (int si = 0; si < ROWS / 2; ++si) {
      int s = s0 + si;
      int irow = h0 - PAD + s;
      char* ldsrow = smem + part * ABYTES + s * RB + PAD * 64;
      if ((unsigned)irow < 64u) {
        const unsigned short* src =
            srcA + (((size_t)(b * 2 + cb) << 12) + (irow << 6)) * 32;
#pragma unroll
        for (int c = 0; c < 4; ++c)
          gload16(src + (c << 9) + (lane << 3), ldsrow + (c << 10));
      } else {
#pragma unroll
        for (int c = 0; c < 4; ++c)
          *(float4*)(ldsrow + (c << 10) + (lane << 4)) =
              make_float4(0.f, 0.f, 0.f, 0.f);
      }
    }
    {
      const unsigned short* srcB = Wsm + (size_t)(cb * KK) * 2048;
      gload16(srcB + (tid << 3), smem + 2 * ABYTES + (tid << 4));
    }
    __syncthreads();

#pragma unroll 1
    for (int kh = 0; kh < K; ++kh) {
      int abase = (wm + kh * DIL) * RB;
#pragma unroll
      for (int kw = 0; kw < K; ++kw) {
        int tap = kh * K + kw;
        if (tap + 1 < KK) {
          const unsigned short* srcB = Wsm + (size_t)(cb * KK + tap + 1) * 2048;
          gload16(srcB + (tid << 3),
                  smem + 2 * ABYTES + (((tap + 1) & 1) << 12) + (tid << 4));
        }
        char* bbase = smem + 2 * ABYTES + ((tap & 1) << 12);
        bf16x8 bfr[2];
#pragma unroll
        for (int ni = 0; ni < 2; ++ni)
          bfr[ni] = *(bf16x8*)(bbase + bterm[ni]);
#pragma unroll
        for (int mi = 0; mi < 4; ++mi) {
          bf16x8 ah = *(bf16x8*)(smem + abase + colterm[mi][kw]);
          bf16x8 al = *(bf16x8*)(smem + ABYTES + abase + colterm[mi][kw]);
#pragma unroll
          for (int ni = 0; ni < 2; ++ni) {
            acc[mi][ni] = __builtin_amdgcn_mfma_f32_16x16x32_bf16(
                ah, bfr[ni], acc[mi][ni], 0, 0, 0);
            acc[mi][ni] = __builtin_amdgcn_mfma_f32_16x16x32_bf16(
                al, bfr[ni], acc[mi][ni], 0, 0, 0);
          }
        }
        __syncthreads();
      }
    }
  }

  if (OUTMODE == 0) {
    short* soH = (short*)smem;
    short* soL = (short*)(smem + ABYTES);
#pragma unroll
    for (int mi = 0; mi < 4; ++mi)
#pragma unroll
      for (int ni = 0; ni < 2; ++ni) {
        int co = wn * 32 + ni * 16 + l15;
        float bs = bias[co];
        int ch = co & 31;
#pragma unroll
        for (int j = 0; j < 4; ++j) {
          int w = mi * 16 + lg * 4 + j;
          float v = acc[mi][ni][j] + bs;
          int slot = (((ch >> 3) ^ ((w >> 1) & 3)) << 3) + (ch & 7);
          int o = ((wm * 2 + wn) * 64 + w) * 32 + slot;
          unsigned short hsh = f2bf(v);
          soH[o] = (short)hsh;
          soL[o] = (short)f2bf(v - bf2f(hsh));
        }
      }
    __syncthreads();
    for (int k = tid; k < 1024; k += 256) {
      int grp = k >> 8;
      int row = grp >> 1, cbo = grp & 1;
      size_t dstb = (size_t)(b * 2 + cbo) * 131072 +
                    (size_t)((h0 + row) << 6) * 32 + (size_t)(k & 255) * 8;
      *(float4*)(o_hi + dstb) = *(float4*)(soH + k * 8);
      *(float4*)(o_lo + dstb) = *(float4*)(soL + k * 8);
    }
  } else {
    int row = h0 + wm;
#pragma unroll
    for (int ni = 0; ni < 2; ++ni) {
      int co = wn * 32 + ni * 16 + l15;
      float bs = bias[co];
#pragma unroll
      for (int mi = 0; mi < 4; ++mi) {
        int col = mi * 16 + lg * 4;
        f32x4 v = acc[mi][ni];
        v += (f32x4)(bs);
        if (OUTMODE == 2) {
#pragma unroll
          for (int j = 0; j < 4; ++j) v[j] = tanhf(v[j]);
        }
        *(f32x4*)(out_f + ((size_t)(b * 64 + co) * 64 + row) * 64 + col) = v;
      }
    }
  }
}

// ---------------- generic KxK direct conv fp32 (e1 only) -------------------
template <int K, int DIL, int CI_T, int OUTMODE>
__global__ void __launch_bounds__(256) convK_k(
    const float* __restrict__ in, const float* __restrict__ wgt,
    const float* __restrict__ bias, float* __restrict__ out, int CIN, int COUT,
    const float* __restrict__ scale_ptr) {
  constexpr int IH = 32 + (K - 1) * DIL;
  constexpr int IW = 32 + (K - 1) * DIL;
  constexpr int PAD = (K - 1) / 2 * DIL;
  constexpr int KK = K * K;
  __shared__ __align__(16) float s_in[CI_T][IH][IW];
  __shared__ __align__(16) float s_w[CI_T * KK * 16];
  int tid = threadIdx.x;
  int tx = tid & 15, ty = tid >> 4;
  int w0 = blockIdx.x * 32, h0 = blockIdx.y * 32;
  int ncog = COUT >> 4;
  int cog = blockIdx.z % ncog;
  int b = blockIdx.z / ncog;
  int co0 = cog << 4;
  float scale = scale_ptr ? scale_ptr[0] : 1.f;
  float a00[16] = {}, a01[16] = {}, a10[16] = {}, a11[16] = {};
  for (int ci0 = 0; ci0 < CIN; ci0 += CI_T) {
    for (int idx = tid; idx < CI_T * IH * IW; idx += 256) {
      int ci = idx / (IH * IW);
      int r = idx - ci * (IH * IW);
      int iy = r / IW;
      int ix = r - iy * IW;
      int gh = h0 - PAD + iy, gw = w0 - PAD + ix;
      float v = 0.f;
      if ((unsigned)gh < 64u && (unsigned)gw < 64u)
        v = in[((((size_t)(b * CIN + ci0 + ci)) << 6) + (size_t)gh << 6) + gw] * scale;
      s_in[ci][iy][ix] = v;
    }
    for (int idx = tid; idx < CI_T * KK * 16; idx += 256) {
      int co = idx & 15;
      int t = (idx >> 4) % KK;
      int ci = (idx >> 4) / KK;
      s_w[(ci * KK + t) * 16 + co] =
          wgt[((size_t)(co0 + co) * CIN + ci0 + ci) * KK + t];
    }
    __syncthreads();
    for (int ci = 0; ci < CI_T; ++ci) {
#pragma unroll
      for (int t = 0; t < KK; ++t) {
        int kh = t / K, kw = t - (t / K) * K;
        int iy = ty * 2 + kh * DIL, ix = tx * 2 + kw * DIL;
        float v00 = s_in[ci][iy][ix];
        float v01 = s_in[ci][iy][ix + 1];
        float v10 = s_in[ci][iy + 1][ix];
        float v11 = s_in[ci][iy + 1][ix + 1];
        const float4* wp = (const float4*)&s_w[(ci * KK + t) * 16];
#pragma unroll
        for (int q = 0; q < 4; ++q) {
          float4 wv = wp[q];
          float wj[4] = {wv.x, wv.y, wv.z, wv.w};
#pragma unroll
          for (int r = 0; r < 4; ++r) {
            a00[q * 4 + r] += v00 * wj[r];
            a01[q * 4 + r] += v01 * wj[r];
            a10[q * 4 + r] += v10 * wj[r];
            a11[q * 4 + r] += v11 * wj[r];
          }
        }
      }
    }
    __syncthreads();
  }
  int oh = h0 + ty * 2, ow = w0 + tx * 2;
#pragma unroll
  for (int j = 0; j < 16; ++j) {
    int co = co0 + j;
    float bs = bias[co];
    float r00 = a00[j] + bs, r01 = a01[j] + bs;
    float r10 = a10[j] + bs, r11 = a11[j] + bs;
    if (OUTMODE == 1) {
      r00 = tanhf(r00); r01 = tanhf(r01);
      r10 = tanhf(r10); r11 = tanhf(r11);
    }
    size_t ob = ((((size_t)(b * COUT + co)) << 6) + (size_t)oh) << 6;
    *(float2*)&out[ob + ow] = make_float2(r00, r01);
    *(float2*)&out[ob + 64 + ow] = make_float2(r10, r11);
  }
}

// ---------------- sigmoid gate: hl_l1 / lh_l1 ------------------------------
__global__ void __launch_bounds__(256) gate_k(
    const float* __restrict__ y7, const float* __restrict__ st,
    const float* __restrict__ g, const float* __restrict__ bb,
    const float* __restrict__ hl_freq, const float* __restrict__ lh_freq,
    const float* __restrict__ w_hl, const float* __restrict__ w_lh,
    float* __restrict__ hl_l1, float* __restrict__ lh_l1) {
  int i = blockIdx.x * 256 + threadIdx.x;
  int p = i & 4095;
  int c = (i >> 12) & 127;
  int b = i >> 19;
  float nv = (y7[i] - st[c]) * st[128 + c] * g[c] + bb[c];
  float sig = 1.f / (1.f + expf(-nv));
  if (c < 64) {
    size_t k = (((size_t)(b * 64 + c)) << 12) + p;
    hl_l1[k] = w_hl[0] * hl_freq[k] * sig;
  } else {
    size_t k = (((size_t)(b * 64 + (c - 64))) << 12) + p;
    lh_l1[k] = w_lh[0] * lh_freq[k] * sig;
  }
}

// ---------------- Haar IDWT ------------------------------------------------
__global__ void __launch_bounds__(256) idwt_k(
    const float* __restrict__ ca, const float* __restrict__ ch,
    const float* __restrict__ cv, const float* __restrict__ cd,
    float* __restrict__ out) {
  int i = blockIdx.x * 256 + threadIdx.x;
  float A = ca[i], Hd = ch[i], V = cv[i], D = cd[i];
  float y00 = (A + Hd + V + D) * 0.5f;
  float y01 = (A + Hd - V - D) * 0.5f;
  float y10 = (A - Hd + V - D) * 0.5f;
  float y11 = (A - Hd - V + D) * 0.5f;
  int w = i & 63;
  int h = (i >> 6) & 63;
  int bc = i >> 12;
  size_t ob = (((size_t)bc * 128) + 2 * h) * 128 + 2 * w;
  *(float2*)&out[ob] = make_float2(y00, y01);
  *(float2*)&out[ob + 128] = make_float2(y10, y11);
}

// ---------------------------------------------------------------------------
extern "C" void kernel_launch(void* const* d_in, const int* in_sizes, int n_in,
                              void* d_out, int out_size, void* d_ws,
                              size_t ws_size, hipStream_t stream) {
  const float* ll_freq = (const float*)d_in[0];
  const float* hl_freq = (const float*)d_in[1];
  const float* lh_freq = (const float*)d_in[2];
  const float* hh_freq = (const float*)d_in[3];
  const float* w_ll = (const float*)d_in[4];
  const float* w_hl = (const float*)d_in[5];
  const float* w_lh = (const float*)d_in[6];
  const float* w_hh = (const float*)d_in[7];
  const float* cc_w = (const float*)d_in[8];
  const float* cc_b = (const float*)d_in[9];
  const float* bnc_g = (const float*)d_in[10];
  const float* bnc_b = (const float*)d_in[11];
  const float* e1_w = (const float*)d_in[12];
  const float* e1_b = (const float*)d_in[13];
  const float* fe_w = (const float*)d_in[14];
  const float* fe_b = (const float*)d_in[15];
  const float* e2_w = (const float*)d_in[16];
  const float* e2_b = (const float*)d_in[17];
  const float* bne_g = (const float*)d_in[18];
  const float* bne_b = (const float*)d_in[19];
  const float* cr_w = (const float*)d_in[20];
  const float* cr_b = (const float*)d_in[21];
  const float* bnr_g = (const float*)d_in[22];
  const float* bnr_b = (const float*)d_in[23];
  const float* adj_w = (const float*)d_in[24];
  const float* adj_b = (const float*)d_in[25];
  const float* cll_w = (const float*)d_in[26];
  const float* cll_b = (const float*)d_in[27];
  const float* chh_w = (const float*)d_in[28];
  const float* chh_b = (const float*)d_in[29];
  const float* c1_w = (const float*)d_in[30];
  const float* c1_b = (const float*)d_in[31];
  const float* c3_w = (const float*)d_in[32];
  const float* c3_b = (const float*)d_in[33];
  const float* c5_w = (const float*)d_in[34];
  const float* c5_b = (const float*)d_in[35];

  const size_t MB = 1ull << 20;
  char* ws = (char*)d_ws;
  // pre-e2 regA
  unsigned short* y4h = (unsigned short*)(ws);            // 32MB
  unsigned short* y4l = (unsigned short*)(ws + 32 * MB);  // 32MB
  float* regA = (float*)(ws);
  float* regB = (float*)(ws + 64 * MB);                   // 64MB
  float* y7   = (float*)(ws + 128 * MB);                  // 16MB
  float* y1   = (float*)(ws + 144 * MB);                  // 2MB
  float* y2   = (float*)(ws + 146 * MB);                  // 2MB
  unsigned short* Wt = (unsigned short*)(ws + 148 * MB);  // 13.1MB
  char* base162 = ws + 162 * MB;
  float* hh_m = (float*)(base162);                        // 128KB
  float* st1  = (float*)(base162 + 128 * 1024);
  float* st2  = (float*)(base162 + 132 * 1024);
  float* st3  = (float*)(base162 + 140 * 1024);
  unsigned short* Wc1  = (unsigned short*)(base162 + 256 * 1024);   // 72KB
  unsigned short* Wc3  = (unsigned short*)(base162 + 512 * 1024);   // 200KB
  unsigned short* Wc5  = (unsigned short*)(base162 + 768 * 1024);   // 392KB
  unsigned short* Wcll = (unsigned short*)(base162 + 1280 * 1024);  // 200KB

  const size_t F2M = 2097152;  // floats per 8MB
  float* ll_a  = regA + 0 * F2M;
  float* ll_l2 = regA + 1 * F2M;
  float* hl_l1 = regA + 2 * F2M;
  float* lh_l1 = regA + 3 * F2M;
  float* hl_l2 = regA + 4 * F2M;
  float* lh_l2 = regA + 5 * F2M;
  unsigned short* Ph = (unsigned short*)(regA + 6 * F2M);  // 4MB
  unsigned short* Pl = (unsigned short*)(ws + 52 * MB);    // 4MB
  unsigned short* Qh = (unsigned short*)(ws + 56 * MB);    // 4MB
  unsigned short* Ql = (unsigned short*)(ws + 60 * MB);    // 4MB
  float* S = regB;          // boxsum scratch (pre-e2)
  float* hh_l2 = regB;      // post-cr reuse

  dim3 blk(256);

  // weight preps (independent of activations)
  prep_w_k<<<dim3(1600), blk, 0, stream>>>(e2_w, Wt);
  prep_ws_k<<<dim3(18), blk, 0, stream>>>(c1_w, Wc1, 64, 9);
  prep_ws_k<<<dim3(50), blk, 0, stream>>>(c3_w, Wc3, 64, 25);
  prep_ws_k<<<dim3(98), blk, 0, stream>>>(c5_w, Wc5, 64, 49);
  prep_ws_k<<<dim3(50), blk, 0, stream>>>(cll_w, Wcll, 64, 25);

  // 1. median: box-sum (into S=regB) then wave-bitonic median
  boxsum_k<<<dim3(512), blk, 0, stream>>>(hh_freq, w_hh, S);
  med_k<<<dim3(512), blk, 0, stream>>>(S, hh_m);

  // 2. cc 1x1 on concat(w_hl*hl, w_lh*lh): 128->16
  conv1x1_k<<<dim3(32, 1, 8), blk, 0, stream>>>(
      hl_freq, lh_freq, 64, w_hl, w_lh, nullptr, nullptr, nullptr, nullptr, 1,
      cc_w, cc_b, y1, 128, 16, 0, nullptr, nullptr);

  // 3. e1 3x3 16->16 (fp32 direct)
  convK_k<3, 1, 8, 0><<<dim3(2, 2, 8), blk, 0, stream>>>(y1, e1_w, e1_b, y2, 16,
                                                         16, nullptr);
  // 4. bnc stats
  stats_k<<<dim3(16), blk, 0, stream>>>(y2, st1, 16, 8);

  // 5. fe 1x1 16->512, input relu(bn(y2)); out bf16 hi/lo channels-last
  conv1x1_k<<<dim3(32, 16, 8), blk, 0, stream>>>(
      y2, nullptr, 0, nullptr, nullptr, st1, bnc_g, bnc_b, nullptr, 2, fe_w,
      fe_b, nullptr, 16, 512, 2, y4h, y4l);

  // 6. e2 5x5 512->512 via MFMA implicit GEMM
  e2_mfma_k<<<dim3(1024), blk, 0, stream>>>(y4h, y4l, Wt, e2_b, regB);

  // 7. bne stats
  stats_k<<<dim3(512), blk, 0, stream>>>(regB, st2, 512, 8);

  // 8. cr 1x1 512->128, input relu(bn(y5))
  conv1x1_k<<<dim3(32, 4, 8), blk, 0, stream>>>(
      regB, nullptr, 0, nullptr, nullptr, st2, bne_g, bne_b, nullptr, 2, cr_w,
      cr_b, y7, 512, 128, 0, nullptr, nullptr);

  // 9. bnr stats
  stats_k<<<dim3(128), blk, 0, stream>>>(y7, st3, 128, 8);

  // 10. gate
  gate_k<<<dim3(16384), blk, 0, stream>>>(y7, st3, bnr_g, bnr_b, hl_freq,
                                          lh_freq, w_hl, w_lh, hl_l1, lh_l1);

  // 11-13. LL branch via MFMA: pack(ll) -> c1 -> c3 -> c5
  pack_k<<<dim3(512), blk, 0, stream>>>(ll_freq, w_ll, Ph, Pl);
  convmf_k<3, 1, 0><<<dim3(256), blk, 0, stream>>>(Ph, Pl, Wc1, c1_b, nullptr,
                                                   Qh, Ql);
  convmf_k<5, 1, 0><<<dim3(256), blk, 0, stream>>>(Qh, Ql, Wc3, c3_b, nullptr,
                                                   Ph, Pl);
  convmf_k<7, 1, 1><<<dim3(256), blk, 0, stream>>>(Ph, Pl, Wc5, c5_b, ll_a,
                                                   nullptr, nullptr);

  // 14-16. adj convs (fp32 1x1)
  conv1x1_k<<<dim3(32, 2, 8), blk, 0, stream>>>(
      ll_a, ll_freq, 64, nullptr, w_ll, nullptr, nullptr, nullptr, nullptr, 1,
      adj_w, adj_b, ll_l2, 128, 64, 0, nullptr, nullptr);
  conv1x1_k<<<dim3(32, 2, 8), blk, 0, stream>>>(
      hl_l1, hl_freq, 64, nullptr, nullptr, nullptr, nullptr, nullptr, nullptr,
      1, adj_w, adj_b, hl_l2, 128, 64, 0, nullptr, nullptr);
  conv1x1_k<<<dim3(32, 2, 8), blk, 0, stream>>>(
      lh_l1, lh_freq, 64, nullptr, nullptr, nullptr, nullptr, nullptr, nullptr,
      1, adj_w, adj_b, lh_l2, 128, 64, 0, nullptr, nullptr);

  // 17. hh_a = leaky_relu(chh(hh_freq + hh_m)) -> bf16 hi/lo (Q)
  conv1x1_k<<<dim3(32, 2, 8), blk, 0, stream>>>(
      hh_freq, nullptr, 0, nullptr, nullptr, nullptr, nullptr, nullptr, hh_m, 3,
      chh_w, chh_b, nullptr, 64, 64, 3, Qh, Ql);

  // 18. hh_l2 = tanh(cll 5x5 dil2 of hh_a) via MFMA
  convmf_k<5, 2, 2><<<dim3(256), blk, 0, stream>>>(Qh, Ql, Wcll, cll_b, hh_l2,
                                                   nullptr, nullptr);

  // 19. IDWT
  idwt_k<<<dim3(8192), blk, 0, stream>>>(ll_l2, hl_l2, lh_l2, hh_l2,
                                         (float*)d_out);
}

// Round 5
// 1447.462 us; speedup vs baseline: 5.8273x; 1.0745x over previous
//
#include <hip/hip_runtime.h>
#include <math.h>

// ---------------------------------------------------------------------------
// FeatureProcessor forward. B=8, C=64, H=W=64, RED=16, EXP=512.
// e2/cr/c1/c3/c5/cll on bf16 MFMA (split-A 2-product: activations exact as
// hi+lo bf16, weights bf16-rounded). e2 uses counted-vmcnt 3-buffer B
// prefetch (never drains to 0 in the tap loop). BN stats fused into
// producer epilogues via atomics.
//
// Workspace:
//   [0,64M) regA: pre-e2 = y4h(32M)+y4l(32M).
//     post-e2: ll_a[0,8) ll_l2[8,16) hl_l2[16,24) lh_l2[24,32)
//              Ph@48M Pl@52M Qh@56M Ql@60M
//   [64M,128M) regB: E2h[64,96) E2l[96,128) (e2 out, packed);
//              post-cr: hh_l2[64,72)
//   [128M,144M) y7 ; [144M,146M) y1 ; [146M,148M) y2
//   [148M,~161M) Wt e2 weights
//   [162M,164M): hh_m(128K), st1, SM(sums), AB2, AB3, Wc1/3/5, Wcll, Wcr
// ---------------------------------------------------------------------------

#define HWP 4096

typedef __attribute__((ext_vector_type(8))) short bf16x8;
typedef __attribute__((ext_vector_type(4))) float f32x4;

__device__ __forceinline__ unsigned short f2bf(float x) {
  unsigned int u = __float_as_uint(x);
  unsigned int r = (u + 0x7fffu + ((u >> 16) & 1u)) >> 16;
  return (unsigned short)r;
}
__device__ __forceinline__ float bf2f(unsigned short h) {
  return __uint_as_float(((unsigned int)h) << 16);
}

__device__ __forceinline__ void gload16(const void* g, void* l) {
  __builtin_amdgcn_global_load_lds(
      (const __attribute__((address_space(1))) unsigned int*)g,
      (__attribute__((address_space(3))) unsigned int*)l, 16, 0, 0);
}

// ---------------- zero the stats accumulators ------------------------------
__global__ void __launch_bounds__(256) zero_k(float* __restrict__ Z) {
  for (int i = threadIdx.x; i < 1280; i += 256) Z[i] = 0.f;
}

// ---------------- finalize: sums -> BN affine (a = g*inv, b2 = beta-mean*a)
__global__ void finalize_k(const float* __restrict__ s,
                           const float* __restrict__ q,
                           const float* __restrict__ gamma,
                           const float* __restrict__ beta, float invN, int C,
                           float* __restrict__ ab) {
  int c = threadIdx.x;
  if (c < C) {
    float mean = s[c] * invN;
    float var = q[c] * invN - mean * mean;
    float a = gamma[c] * rsqrtf(fmaxf(var, 0.f) + 1e-5f);
    ab[c] = a;
    ab[C + c] = beta[c] - mean * a;
  }
}

// ---------------- box-sum 5x5 reflect (per b,c) ----------------------------
__global__ void __launch_bounds__(256) boxsum_k(
    const float* __restrict__ hh, const float* __restrict__ w_hh,
    float* __restrict__ S) {
  __shared__ float img[64][65];
  __shared__ float rs[64][65];
  int bc = blockIdx.x;
  const float* src = hh + ((size_t)bc << 12);
  float wv = w_hh[0];
  int tid = threadIdx.x;
  for (int i = tid; i < 4096; i += 256) img[i >> 6][i & 63] = src[i] * wv;
  __syncthreads();
  for (int i = tid; i < 4096; i += 256) {
    int h = i >> 6, w = i & 63;
    float s = 0.f;
#pragma unroll
    for (int d = -2; d <= 2; ++d) {
      int ww = w + d;
      ww = ww < 0 ? -ww : (ww > 63 ? 126 - ww : ww);
      s += img[h][ww];
    }
    rs[h][w] = s;
  }
  __syncthreads();
  float* dst = S + ((size_t)bc << 12);
  for (int i = tid; i < 4096; i += 256) {
    int h = i >> 6, w = i & 63;
    float s = 0.f;
#pragma unroll
    for (int d = -2; d <= 2; ++d) {
      int h2 = h + d;
      h2 = h2 < 0 ? -h2 : (h2 > 63 ? 126 - h2 : h2);
      s += rs[h2][w];
    }
    dst[i] = s;
  }
}

// ---------------- median over 64 channels ----------------------------------
__global__ void __launch_bounds__(256) med_k(const float* __restrict__ S,
                                             float* __restrict__ hh_m) {
  __shared__ float ldsS[64][65];
  int bx = blockIdx.x;
  int b = bx >> 6, h = bx & 63;
  int tid = threadIdx.x;
  for (int i = tid; i < 4096; i += 256) {
    int c = i >> 6, w = i & 63;
    ldsS[c][w] = S[((size_t)(b * 64 + c) << 12) + (h << 6) + w];
  }
  __syncthreads();
  int lane = tid & 63, wv = tid >> 6;
  for (int i = 0; i < 16; ++i) {
    int w = wv * 16 + i;
    float s = ldsS[lane][w];
    for (int k = 2; k <= 64; k <<= 1)
      for (int j = k >> 1; j > 0; j >>= 1) {
        float o = __shfl_xor(s, j, 64);
        bool up = (lane & k) == 0;
        bool low = (lane & j) == 0;
        s = (low == up) ? fminf(s, o) : fmaxf(s, o);
      }
    float v31 = __shfl(s, 31, 64);
    float v32 = __shfl(s, 32, 64);
    if (lane == 0) hh_m[(b << 12) + (h << 6) + w] = 0.5f * (v31 + v32);
  }
}

// ---------------- per-channel mean/invstd (bnc only) -----------------------
__global__ void __launch_bounds__(256) stats_k(
    const float* __restrict__ x, float* __restrict__ stats, int C, int B) {
  int c = blockIdx.x;
  int tid = threadIdx.x;
  int N = B * HWP;
  float s = 0.f, q = 0.f;
  for (int i = tid; i < N; i += 256) {
    int b = i >> 12, p = i & 4095;
    float v = x[(((size_t)(b * C + c)) << 12) + p];
    s += v;
    q += v * v;
  }
  __shared__ float rs[256], rq[256];
  rs[tid] = s; rq[tid] = q;
  __syncthreads();
  for (int st = 128; st > 0; st >>= 1) {
    if (tid < st) { rs[tid] += rs[tid + st]; rq[tid] += rq[tid + st]; }
    __syncthreads();
  }
  if (tid == 0) {
    float mean = rs[0] / (float)N;
    float var = rq[0] / (float)N - mean * mean;
    stats[c] = mean;
    stats[C + c] = rsqrtf(fmaxf(var, 0.f) + 1e-5f);
  }
}

// ---------------- 1x1 conv (pointwise GEMM) with fused input modes ---------
// input modes: 0 plain; 1 concat(sA*inA, sB*inB); 2 relu(bn(inA));
//              3 inA + extra broadcast; 4 gated concat (gate fused).
// out modes:   0 plain fp32; 1 leaky fp32; 2 bf16 hi/lo packed; 3 leaky+packed
__global__ void __launch_bounds__(256) conv1x1_k(
    const float* __restrict__ inA, const float* __restrict__ inB, int C1,
    const float* __restrict__ sA, const float* __restrict__ sB,
    const float* __restrict__ bn_stats, const float* __restrict__ bn_g,
    const float* __restrict__ bn_b, const float* __restrict__ extra, int mode,
    const float* __restrict__ wgt, const float* __restrict__ bias,
    float* __restrict__ out, int CIN, int COUT, int out_mode,
    unsigned short* __restrict__ o_hi, unsigned short* __restrict__ o_lo,
    int coff) {
  __shared__ __align__(16) float s_in[16][128];
  __shared__ __align__(16) float s_w[16][32];
  __shared__ __align__(16) short sOH[4096];
  __shared__ __align__(16) short sOL[4096];
  int tid = threadIdx.x;
  int p0 = blockIdx.x * 128;
  int co0 = blockIdx.y * 32;
  int b = blockIdx.z;
  float fA = sA ? sA[0] : 1.f;
  float fB = sB ? sB[0] : 1.f;
  int pi = tid & 63;
  int cog = tid >> 6;
  float acc0[8] = {0.f, 0.f, 0.f, 0.f, 0.f, 0.f, 0.f, 0.f};
  float acc1[8] = {0.f, 0.f, 0.f, 0.f, 0.f, 0.f, 0.f, 0.f};
  for (int ci0 = 0; ci0 < CIN; ci0 += 16) {
#pragma unroll
    for (int t = 0; t < 8; ++t) {
      int idx = tid + t * 256;
      int ci = idx >> 7, pp = idx & 127;
      int c = ci0 + ci;
      int p = p0 + pp;
      float v;
      if (mode == 1) {
        v = (c < C1) ? fA * inA[(((size_t)(b * C1 + c)) << 12) + p]
                     : fB * inB[(((size_t)(b * (CIN - C1) + (c - C1))) << 12) + p];
      } else if (mode == 4) {
        if (c < 64) {
          float yv = inA[(((size_t)(b * 128 + coff + c)) << 12) + p];
          float arg = bn_stats[coff + c] * yv + bn_stats[128 + coff + c];
          float sg = 1.f / (1.f + expf(-arg));
          v = fB * inB[(((size_t)(b * 64 + c)) << 12) + p] * sg;
        } else {
          v = inB[(((size_t)(b * 64 + (c - 64))) << 12) + p];
        }
      } else {
        v = inA[(((size_t)(b * CIN + c)) << 12) + p];
        if (mode == 2) {
          v = (v - bn_stats[c]) * bn_stats[CIN + c] * bn_g[c] + bn_b[c];
          v = fmaxf(v, 0.f);
        } else if (mode == 3) {
          v += extra[(b << 12) + p];
        }
      }
      s_in[ci][pp] = v;
    }
#pragma unroll
    for (int t = 0; t < 2; ++t) {
      int idx = tid + t * 256;
      int ci = idx >> 5, co = idx & 31;
      float wv = 0.f;
      if (co0 + co < COUT) wv = wgt[(size_t)(co0 + co) * CIN + ci0 + ci];
      s_w[ci][co] = wv;
    }
    __syncthreads();
#pragma unroll
    for (int ci = 0; ci < 16; ++ci) {
      float2 v01 = *(const float2*)&s_in[ci][pi * 2];
      const float4* wp = (const float4*)&s_w[ci][cog * 8];
#pragma unroll
      for (int q = 0; q < 2; ++q) {
        float4 wv = wp[q];
        float wj[4] = {wv.x, wv.y, wv.z, wv.w};
#pragma unroll
        for (int r = 0; r < 4; ++r) {
          acc0[q * 4 + r] += v01.x * wj[r];
          acc1[q * 4 + r] += v01.y * wj[r];
        }
      }
    }
    __syncthreads();
  }
  if (out_mode >= 2) {
#pragma unroll
    for (int j = 0; j < 8; ++j) {
      int co = co0 + cog * 8 + j;
      float bs = bias[co];
      float r[2] = {acc0[j] + bs, acc1[j] + bs};
#pragma unroll
      for (int e = 0; e < 2; ++e) {
        float v = r[e];
        if (out_mode == 3) v = v < 0.f ? 0.1f * v : v;
        int px = pi * 2 + e;
        int w = px & 63;
        int slot = ((cog ^ ((w >> 1) & 3)) << 3) + j;
        int o = px * 32 + slot;
        unsigned short hsh = f2bf(v);
        sOH[o] = (short)hsh;
        sOL[o] = (short)f2bf(v - bf2f(hsh));
      }
    }
    __syncthreads();
    int cb = co0 >> 5;
    size_t base = (size_t)(b * (COUT >> 5) + cb) * 131072 + (size_t)p0 * 32;
    for (int k = tid; k < 512; k += 256) {
      *(float4*)(o_hi + base + (size_t)k * 8) = *(float4*)&sOH[k * 8];
      *(float4*)(o_lo + base + (size_t)k * 8) = *(float4*)&sOL[k * 8];
    }
  } else {
#pragma unroll
    for (int j = 0; j < 8; ++j) {
      int co = co0 + cog * 8 + j;
      if (co < COUT) {
        float bs = bias[co];
        float r0 = acc0[j] + bs;
        float r1 = acc1[j] + bs;
        if (out_mode == 1) {
          r0 = r0 < 0.f ? 0.1f * r0 : r0;
          r1 = r1 < 0.f ? 0.1f * r1 : r1;
        }
        float2 rr = make_float2(r0, r1);
        *(float2*)&out[(((size_t)(b * COUT + co)) << 12) + p0 + pi * 2] = rr;
      }
    }
  }
}

// ---------------- pack NCHW fp32 -> channels-last hi/lo bf16 ---------------
__global__ void __launch_bounds__(256) pack_k(
    const float* __restrict__ in, const float* __restrict__ scale_ptr,
    unsigned short* __restrict__ o_hi, unsigned short* __restrict__ o_lo) {
  __shared__ float lds[32][130];
  int bx = blockIdx.x;
  int pc = bx & 31, cb = (bx >> 5) & 1, b = bx >> 6;
  int p0 = pc * 128;
  float sc = scale_ptr ? scale_ptr[0] : 1.f;
  int tid = threadIdx.x;
  for (int i = tid; i < 4096; i += 256) {
    int c = i >> 7, px = i & 127;
    lds[c][px] = in[((size_t)(b * 64 + cb * 32 + c) << 12) + p0 + px] * sc;
  }
  __syncthreads();
  size_t base = (size_t)(b * 2 + cb) * 131072 + (size_t)p0 * 32;
  for (int k = tid; k < 512; k += 256) {
    int p = k >> 2, gsw = k & 3;
    int w = p & 63;
    int g = gsw ^ ((w >> 1) & 3);
    bf16x8 hi, lo;
#pragma unroll
    for (int j = 0; j < 8; ++j) {
      float v = lds[g * 8 + j][p];
      unsigned short h = f2bf(v);
      hi[j] = (short)h;
      lo[j] = (short)f2bf(v - bf2f(h));
    }
    *(bf16x8*)(o_hi + base + (size_t)k * 8) = hi;
    *(bf16x8*)(o_lo + base + (size_t)k * 8) = lo;
  }
}

// ---------------- e2 weight prep -------------------------------------------
__global__ void __launch_bounds__(256) prep_w_k(const float* __restrict__ w,
                                                unsigned short* __restrict__ Wt) {
  int bx = blockIdx.x;  // (cbco*16 + cbci)*25 + tap
  int cbco = bx / 400;
  int r = bx - cbco * 400;
  int cbci = r / 25, tap = r - cbci * 25;
  unsigned short* dst = Wt + (size_t)bx * 4096;
  for (int d = threadIdx.x; d < 4096; d += 256) {
    int co_l = d >> 5, s = d & 31;
    int g = (s >> 3) ^ ((co_l >> 1) & 3);
    int cil = (g << 3) + (s & 7);
    dst[d] = f2bf(w[((size_t)(cbco * 128 + co_l) * 512 + cbci * 32 + cil) * 25 + tap]);
  }
}

// ---------------- cr weight prep: [cb16][co128][ci32] ----------------------
__global__ void __launch_bounds__(256) prep_wcr_k(const float* __restrict__ w,
                                                  unsigned short* __restrict__ Wt) {
  int cb = blockIdx.x;  // 0..15
  unsigned short* dst = Wt + (size_t)cb * 4096;
  for (int d = threadIdx.x; d < 4096; d += 256) {
    int co = d >> 5, s = d & 31;
    int g = (s >> 3) ^ ((co >> 1) & 3);
    int cil = (g << 3) + (s & 7);
    dst[d] = f2bf(w[(size_t)co * 512 + cb * 32 + cil]);
  }
}

// ---------------- small-conv weight prep -----------------------------------
__global__ void __launch_bounds__(256) prep_ws_k(const float* __restrict__ w,
                                                 unsigned short* __restrict__ Wt,
                                                 int CIN, int KK) {
  int bx = blockIdx.x;
  int cbci = bx / KK, tap = bx - cbci * KK;
  unsigned short* dst = Wt + (size_t)bx * 2048;
  for (int d = threadIdx.x; d < 2048; d += 256) {
    int co = d >> 5, s = d & 31;
    int g = (s >> 3) ^ ((co >> 1) & 3);
    int cil = (g << 3) + (s & 7);
    dst[d] = f2bf(w[(size_t)(co * CIN + cbci * 32 + cil) * KK + tap]);
  }
}

// ---------------- e2: MFMA implicit GEMM, counted-vmcnt B prefetch ---------
// LDS: A hi[26112] lo[26112] (6 rows x 68 x 64B), B 3 x 8192. Epilogue:
// packed bf16 hi/lo channels-last + fused per-channel sum/sq atomics.
__global__ void __launch_bounds__(256, 2) e2_mfma_k(
    const unsigned short* __restrict__ y4h, const unsigned short* __restrict__ y4l,
    const unsigned short* __restrict__ Wt, const float* __restrict__ bias,
    unsigned short* __restrict__ E2h, unsigned short* __restrict__ E2l,
    float* __restrict__ sum5, float* __restrict__ sq5) {
  __shared__ __align__(16) char smem[76800];
  const int tid = threadIdx.x;
  const int lane = tid & 63;
  const int wid = tid >> 6;
  int logical = ((blockIdx.x & 7) << 7) + (blockIdx.x >> 3);  // XCD chunking
  int cbco = logical >> 8;
  int rem = logical & 255;
  int rowpair = rem >> 3;
  int b = rem & 7;
  int h0 = rowpair << 1;
  const int wm = wid >> 1, wn = wid & 1;
  const int l15 = lane & 15, lg = lane >> 4;

  int colterm[4][5];
#pragma unroll
  for (int mi = 0; mi < 4; ++mi)
#pragma unroll
    for (int kw = 0; kw < 5; ++kw) {
      int col = mi * 16 + l15 + kw;  // entry = w_in + 2
      colterm[mi][kw] = col * 64 + ((lg ^ (((col + 62) >> 1) & 3)) << 4);
    }
  int bterm[4];
#pragma unroll
  for (int ni = 0; ni < 4; ++ni) {
    int c = wn * 64 + ni * 16 + l15;
    bterm[ni] = c * 64 + ((lg ^ ((c >> 1) & 3)) << 4);
  }

  if (tid < 192) {  // zero halo columns 0,1,66,67 (both parts)
    int g = tid & 3, e = tid >> 2;
    int part = e / 24, r = e - part * 24;
    int s = r >> 2, cp = r & 3;
    int col = (cp < 2) ? cp : (64 + cp);
    *(float4*)(smem + part * 26112 + s * 4352 + col * 64 + g * 16) =
        make_float4(0.f, 0.f, 0.f, 0.f);
  }

  f32x4 acc[4][4];
#pragma unroll
  for (int i = 0; i < 4; ++i)
#pragma unroll
    for (int j = 0; j < 4; ++j) acc[i][j] = (f32x4)(0.f);

  const int part = wid >> 1;
  const int s0 = (wid & 1) * 3;
  const unsigned short* srcA = part ? y4l : y4h;

#pragma unroll 1
  for (int cb = 0; cb < 16; ++cb) {
    __syncthreads();  // prior-cb reads of A/B done before restage
#pragma unroll
    for (int si = 0; si < 3; ++si) {
      int s = s0 + si;
      int irow = h0 - 2 + s;
      char* ldsrow = smem + part * 26112 + s * 4352 + 128;
      if ((unsigned)irow < 64u) {
        const unsigned short* src =
            srcA + (((size_t)(b * 16 + cb) * 64 + irow) << 11);
#pragma unroll
        for (int c = 0; c < 4; ++c)
          gload16(src + (c << 9) + (lane << 3), ldsrow + (c << 10));
      } else {
#pragma unroll
        for (int c = 0; c < 4; ++c)
          *(float4*)(ldsrow + (c << 10) + (lane << 4)) =
              make_float4(0.f, 0.f, 0.f, 0.f);
      }
    }
    // stage B taps 0,1 into bufs 0,1
#pragma unroll
    for (int t0 = 0; t0 < 2; ++t0) {
      const unsigned short* src =
          Wt + ((size_t)((cbco * 16 + cb) * 25 + t0) << 12);
#pragma unroll
      for (int k = 0; k < 2; ++k) {
        int c2 = wid * 2 + k;
        gload16(src + (c2 << 9) + (lane << 3),
                smem + 52224 + t0 * 8192 + (c2 << 10));
      }
    }
    __syncthreads();  // full drain once per cb

#pragma unroll 1
    for (int kh = 0; kh < 5; ++kh) {
      int abase = (wm + kh) * 4352;
#pragma unroll
      for (int kw = 0; kw < 5; ++kw) {
        int tap = kh * 5 + kw;
        if (tap < 23) {  // issue tap+2 into buf (tap+2)%3
          int nb = (tap + 2) % 3;
          const unsigned short* src =
              Wt + ((size_t)((cbco * 16 + cb) * 25 + tap + 2) << 12);
#pragma unroll
          for (int k = 0; k < 2; ++k) {
            int c2 = wid * 2 + k;
            gload16(src + (c2 << 9) + (lane << 3),
                    smem + 52224 + nb * 8192 + (c2 << 10));
          }
        }
        char* bbase = smem + 52224 + (tap % 3) * 8192;
        bf16x8 bfr[4];
#pragma unroll
        for (int ni = 0; ni < 4; ++ni)
          bfr[ni] = *(bf16x8*)(bbase + bterm[ni]);
#pragma unroll
        for (int mi = 0; mi < 4; ++mi) {
          bf16x8 ah = *(bf16x8*)(smem + abase + colterm[mi][kw]);
          bf16x8 al = *(bf16x8*)(smem + 26112 + abase + colterm[mi][kw]);
#pragma unroll
          for (int ni = 0; ni < 4; ++ni) {
            acc[mi][ni] = __builtin_amdgcn_mfma_f32_16x16x32_bf16(
                ah, bfr[ni], acc[mi][ni], 0, 0, 0);
            acc[mi][ni] = __builtin_amdgcn_mfma_f32_16x16x32_bf16(
                al, bfr[ni], acc[mi][ni], 0, 0, 0);
          }
        }
        // counted-vmcnt barrier: tap+1's loads complete, tap+2 stays in flight
        if (tap < 23) {
          asm volatile("s_waitcnt vmcnt(2)\n\ts_barrier" ::: "memory");
        } else if (tap == 23) {
          asm volatile("s_waitcnt vmcnt(0)\n\ts_barrier" ::: "memory");
        }
      }
    }
  }
  __syncthreads();

  // ---- epilogue: pack bf16 hi/lo channels-last + stats atomics ----
  short* H = (short*)smem;            // [4 cb_l][128 px][32 slot]
  short* L = (short*)(smem + 32768);
#pragma unroll
  for (int ni = 0; ni < 4; ++ni) {
    int co_l = wn * 64 + ni * 16 + l15;
    int cb_l = co_l >> 5, ch = co_l & 31;
    float bs = bias[cbco * 128 + co_l];
    float ps = 0.f, pq = 0.f;
#pragma unroll
    for (int mi = 0; mi < 4; ++mi) {
#pragma unroll
      for (int j = 0; j < 4; ++j) {
        int w = mi * 16 + lg * 4 + j;
        float v = acc[mi][ni][j] + bs;
        ps += v;
        pq += v * v;
        int slot = (((ch >> 3) ^ ((w >> 1) & 3)) << 3) + (ch & 7);
        int o = (cb_l * 128 + wm * 64 + w) * 32 + slot;
        unsigned short hsh = f2bf(v);
        H[o] = (short)hsh;
        L[o] = (short)f2bf(v - bf2f(hsh));
      }
    }
    ps += __shfl_xor(ps, 16, 64); ps += __shfl_xor(ps, 32, 64);
    pq += __shfl_xor(pq, 16, 64); pq += __shfl_xor(pq, 32, 64);
    if (lg == 0) {
      atomicAdd(&sum5[cbco * 128 + co_l], ps);
      atomicAdd(&sq5[cbco * 128 + co_l], pq);
    }
  }
  __syncthreads();
  for (int k = tid; k < 2048; k += 256) {
    int cb_l = k >> 9, r = k & 511;
    size_t gb = ((size_t)(b * 16 + cbco * 4 + cb_l) * 4096 + h0 * 64) * 32 +
                (size_t)r * 8;
    *(float4*)(E2h + gb) = *(float4*)(H + cb_l * 4096 + r * 8);
    *(float4*)(E2l + gb) = *(float4*)(L + cb_l * 4096 + r * 8);
  }
}

// ---------------- cr: MFMA GEMM K=512, BN+ReLU fused on input --------------
// Input E2h/E2l packed; y7 fp32 NCHW out + bnr sum/sq atomics.
__global__ void __launch_bounds__(256, 2) cr_mfma_k(
    const unsigned short* __restrict__ E2h, const unsigned short* __restrict__ E2l,
    const unsigned short* __restrict__ Wcr, const float* __restrict__ ab2,
    const float* __restrict__ bias, float* __restrict__ y7,
    float* __restrict__ sum3, float* __restrict__ sq3) {
  __shared__ __align__(16) char smem[20480];  // Ah 4K | Al 4K | B 8K | par 4K
  float* sa = (float*)(smem + 16384);
  float* sb = sa + 512;
  const int tid = threadIdx.x;
  const int lane = tid & 63;
  const int wid = tid >> 6;
  const int b = blockIdx.y;
  const int p0 = blockIdx.x << 6;
  const int wm = wid >> 1, wn = wid & 1;
  const int l15 = lane & 15, lg = lane >> 4;

  for (int i = tid; i < 512; i += 256) {
    sa[i] = ab2[i];
    sb[i] = ab2[512 + i];
  }

  int aterm[2];
#pragma unroll
  for (int mi = 0; mi < 2; ++mi) {
    int px = wm * 32 + mi * 16 + l15;
    aterm[mi] = px * 64 + ((lg ^ ((px >> 1) & 3)) << 4);
  }
  int bterm[4];
#pragma unroll
  for (int ni = 0; ni < 4; ++ni) {
    int c = wn * 64 + ni * 16 + l15;
    bterm[ni] = c * 64 + ((lg ^ ((c >> 1) & 3)) << 4);
  }

  f32x4 acc[2][4];
#pragma unroll
  for (int i = 0; i < 2; ++i)
#pragma unroll
    for (int j = 0; j < 4; ++j) acc[i][j] = (f32x4)(0.f);

  const int spx = tid >> 2, sgs = tid & 3;
  const int sg = sgs ^ ((spx >> 1) & 3);
  __syncthreads();  // params visible

#pragma unroll 1
  for (int cb = 0; cb < 16; ++cb) {
    // stage A: load granule, reconstruct, BN+ReLU, re-split, ds_write
    {
      size_t src = ((size_t)(b * 16 + cb) * 4096 + p0 + spx) * 32 + sgs * 8;
      bf16x8 h8 = *(const bf16x8*)(E2h + src);
      bf16x8 l8 = *(const bf16x8*)(E2l + src);
      bf16x8 oh, ol;
      int cib = cb * 32 + sg * 8;
#pragma unroll
      for (int j = 0; j < 8; ++j) {
        float x = bf2f((unsigned short)h8[j]) + bf2f((unsigned short)l8[j]);
        float v = fmaxf(sa[cib + j] * x + sb[cib + j], 0.f);
        unsigned short hh2 = f2bf(v);
        oh[j] = (short)hh2;
        ol[j] = (short)f2bf(v - bf2f(hh2));
      }
      *(bf16x8*)(smem + spx * 64 + sgs * 16) = oh;
      *(bf16x8*)(smem + 4096 + spx * 64 + sgs * 16) = ol;
    }
    // stage B: 8KB weights via gload16
    {
      const unsigned short* srcB = Wcr + (size_t)cb * 4096;
#pragma unroll
      for (int k = 0; k < 2; ++k) {
        int c2 = wid * 2 + k;
        gload16(srcB + (c2 << 9) + (lane << 3), smem + 8192 + (c2 << 10));
      }
    }
    __syncthreads();
    bf16x8 bfr[4];
#pragma unroll
    for (int ni = 0; ni < 4; ++ni)
      bfr[ni] = *(bf16x8*)(smem + 8192 + bterm[ni]);
#pragma unroll
    for (int mi = 0; mi < 2; ++mi) {
      bf16x8 ah = *(bf16x8*)(smem + aterm[mi]);
      bf16x8 al = *(bf16x8*)(smem + 4096 + aterm[mi]);
#pragma unroll
      for (int ni = 0; ni < 4; ++ni) {
        acc[mi][ni] = __builtin_amdgcn_mfma_f32_16x16x32_bf16(
            ah, bfr[ni], acc[mi][ni], 0, 0, 0);
        acc[mi][ni] = __builtin_amdgcn_mfma_f32_16x16x32_bf16(
            al, bfr[ni], acc[mi][ni], 0, 0, 0);
      }
    }
    __syncthreads();
  }

  // epilogue: y7 fp32 NCHW + bnr stats
#pragma unroll
  for (int ni = 0; ni < 4; ++ni) {
    int co = wn * 64 + ni * 16 + l15;
    float bs = bias[co];
    float ps = 0.f, pq = 0.f;
#pragma unroll
    for (int mi = 0; mi < 2; ++mi) {
      f32x4 v = acc[mi][ni];
      v += (f32x4)(bs);
#pragma unroll
      for (int j = 0; j < 4; ++j) { ps += v[j]; pq += v[j] * v[j]; }
      int px = p0 + wm * 32 + mi * 16 + lg * 4;
      *(f32x4*)(y7 + (((size_t)(b * 128 + co)) << 12) + px) = v;
    }
    ps += __shfl_xor(ps, 16, 64); ps += __shfl_xor(ps, 32, 64);
    pq += __shfl_xor(pq, 16, 64); pq += __shfl_xor(pq, 32, 64);
    if (lg == 0) {
      atomicAdd(&sum3[co], ps);
      atomicAdd(&sq3[co], pq);
    }
  }
}

// ---------------- small KxK conv via MFMA (CIN=COUT=64, split-A) -----------
template <int K, int DIL, int OUTMODE>
__global__ void __launch_bounds__(256, 2) convmf_k(
    const unsigned short* __restrict__ inh, const unsigned short* __restrict__ inl,
    const unsigned short* __restrict__ Wsm, const float* __restrict__ bias,
    float* __restrict__ out_f, unsigned short* __restrict__ o_hi,
    unsigned short* __restrict__ o_lo) {
  constexpr int PAD = (K - 1) / 2 * DIL;
  constexpr int ROWS = 2 + 2 * PAD;
  constexpr int CW = 64 + 2 * PAD;
  constexpr int RB = CW * 64;
  constexpr int ABYTES = ROWS * RB;
  constexpr int KK = K * K;
  __shared__ __align__(16) char smem[2 * ABYTES + 8192];
  const int tid = threadIdx.x;
  const int lane = tid & 63;
  const int wid = tid >> 6;
  const int b = blockIdx.x >> 5;
  const int h0 = (blockIdx.x & 31) << 1;
  const int wm = wid >> 1, wn = wid & 1;
  const int l15 = lane & 15, lg = lane >> 4;

  int colterm[4][K];
#pragma unroll
  for (int mi = 0; mi < 4; ++mi)
#pragma unroll
    for (int kw = 0; kw < K; ++kw) {
      int e = mi * 16 + l15 + kw * DIL;
      colterm[mi][kw] = e * 64 + ((lg ^ (((e - PAD + 64) >> 1) & 3)) << 4);
    }
  int bterm[2];
#pragma unroll
  for (int ni = 0; ni < 2; ++ni) {
    int c = wn * 32 + ni * 16 + l15;
    bterm[ni] = c * 64 + ((lg ^ ((c >> 1) & 3)) << 4);
  }

  for (int i = tid; i < 2 * ROWS * 2 * PAD * 4; i += 256) {
    int c4 = i & 3;
    int r1 = i >> 2;
    int e = r1 % (2 * PAD);
    int r2 = r1 / (2 * PAD);
    int r = r2 % ROWS;
    int part = r2 / ROWS;
    int col = (e < PAD) ? e : (e + 64);
    *(float4*)(smem + part * ABYTES + r * RB + col * 64 + c4 * 16) =
        make_float4(0.f, 0.f, 0.f, 0.f);
  }

  f32x4 acc[4][2];
#pragma unroll
  for (int i = 0; i < 4; ++i)
#pragma unroll
    for (int j = 0; j < 2; ++j) acc[i][j] = (f32x4)(0.f);

  const int part = wid >> 1;
  const int s0 = (wid & 1) * (ROWS / 2);
  const unsigned short* srcA = part ? inl : inh;

#pragma unroll 1
  for (int cb = 0; cb < 2; ++cb) {
#pragma unroll
    for (int si = 0; si < ROWS / 2; ++si) {
      int s = s0 + si;
      int irow = h0 - PAD + s;
      char* ldsrow = smem + part * ABYTES + s * RB + PAD * 64;
      if ((unsigned)irow < 64u) {
        const unsigned short* src =
            srcA + (((size_t)(b * 2 + cb) << 12) + (irow << 6)) * 32;
#pragma unroll
        for (int c = 0; c < 4; ++c)
          gload16(src + (c << 9) + (lane << 3), ldsrow + (c << 10));
      } else {
#pragma unroll
        for (int c = 0; c < 4; ++c)
          *(float4*)(ldsrow + (c << 10) + (lane << 4)) =
              make_float4(0.f, 0.f, 0.f, 0.f);
      }
    }
    {
      const unsigned short* srcB = Wsm + (size_t)(cb * KK) * 2048;
      gload16(srcB + (tid << 3), smem + 2 * ABYTES + (tid << 4));
    }
    __syncthreads();

#pragma unroll 1
    for (int kh = 0; kh < K; ++kh) {
      int abase = (wm + kh * DIL) * RB;
#pragma unroll
      for (int kw = 0; kw < K; ++kw) {
        int tap = kh * K + kw;
        if (tap + 1 < KK) {
          const unsigned short* srcB = Wsm + (size_t)(cb * KK + tap + 1) * 2048;
          gload16(srcB + (tid << 3),
                  smem + 2 * ABYTES + (((tap + 1) & 1) << 12) + (tid << 4));
        }
        char* bbase = smem + 2 * ABYTES + ((tap & 1) << 12);
        bf16x8 bfr[2];
#pragma unroll
        for (int ni = 0; ni < 2; ++ni)
          bfr[ni] = *(bf16x8*)(bbase + bterm[ni]);
#pragma unroll
        for (int mi = 0; mi < 4; ++mi) {
          bf16x8 ah = *(bf16x8*)(smem + abase + colterm[mi][kw]);
          bf16x8 al = *(bf16x8*)(smem + ABYTES + abase + colterm[mi][kw]);
#pragma unroll
          for (int ni = 0; ni < 2; ++ni) {
            acc[mi][ni] = __builtin_amdgcn_mfma_f32_16x16x32_bf16(
                ah, bfr[ni], acc[mi][ni], 0, 0, 0);
            acc[mi][ni] = __builtin_amdgcn_mfma_f32_16x16x32_bf16(
                al, bfr[ni], acc[mi][ni], 0, 0, 0);
          }
        }
        __syncthreads();
      }
    }
  }

  if (OUTMODE == 0) {
    short* soH = (short*)smem;
    short* soL = (short*)(smem + ABYTES);
#pragma unroll
    for (int mi = 0; mi < 4; ++mi)
#pragma unroll
      for (int ni = 0; ni < 2; ++ni) {
        int co = wn * 32 + ni * 16 + l15;
        float bs = bias[co];
        int ch = co & 31;
#pragma unroll
        for (int j = 0; j < 4; ++j) {
          int w = mi * 16 + lg * 4 + j;
          float v = acc[mi][ni][j] + bs;
          int slot = (((ch >> 3) ^ ((w >> 1) & 3)) << 3) + (ch & 7);
          int o = ((wm * 2 + wn) * 64 + w) * 32 + slot;
          unsigned short hsh = f2bf(v);
          soH[o] = (short)hsh;
          soL[o] = (short)f2bf(v - bf2f(hsh));
        }
      }
    __syncthreads();
    for (int k = tid; k < 1024; k += 256) {
      int grp = k >> 8;
      int row = grp >> 1, cbo = grp & 1;
      size_t dstb = (size_t)(b * 2 + cbo) * 131072 +
                    (size_t)((h0 + row) << 6) * 32 + (size_t)(k & 255) * 8;
      *(float4*)(o_hi + dstb) = *(float4*)(soH + k * 8);
      *(float4*)(o_lo + dstb) = *(float4*)(soL + k * 8);
    }
  } else {
    int row = h0 + wm;
#pragma unroll
    for (int ni = 0; ni < 2; ++ni) {
      int co = wn * 32 + ni * 16 + l15;
      float bs = bias[co];
#pragma unroll
      for (int mi = 0; mi < 4; ++mi) {
        int col = mi * 16 + lg * 4;
        f32x4 v = acc[mi][ni];
        v += (f32x4)(bs);
        if (OUTMODE == 2) {
#pragma unroll
          for (int j = 0; j < 4; ++j) v[j] = tanhf(v[j]);
        }
        *(f32x4*)(out_f + ((size_t)(b * 64 + co) * 64 + row) * 64 + col) = v;
      }
    }
  }
}

// ---------------- generic KxK direct conv fp32 (e1 only) -------------------
template <int K, int DIL, int CI_T, int OUTMODE>
__global__ void __launch_bounds__(256) convK_k(
    const float* __restrict__ in, const float* __restrict__ wgt,
    const float* __restrict__ bias, float* __restrict__ out, int CIN, int COUT,
    const float* __restrict__ scale_ptr) {
  constexpr int IH = 32 + (K - 1) * DIL;
  constexpr int IW = 32 + (K - 1) * DIL;
  constexpr int PAD = (K - 1) / 2 * DIL;
  constexpr int KK = K * K;
  __shared__ __align__(16) float s_in[CI_T][IH][IW];
  __shared__ __align__(16) float s_w[CI_T * KK * 16];
  int tid = threadIdx.x;
  int tx = tid & 15, ty = tid >> 4;
  int w0 = blockIdx.x * 32, h0 = blockIdx.y * 32;
  int ncog = COUT >> 4;
  int cog = blockIdx.z % ncog;
  int b = blockIdx.z / ncog;
  int co0 = cog << 4;
  float scale = scale_ptr ? scale_ptr[0] : 1.f;
  float a00[16] = {}, a01[16] = {}, a10[16] = {}, a11[16] = {};
  for (int ci0 = 0; ci0 < CIN; ci0 += CI_T) {
    for (int idx = tid; idx < CI_T * IH * IW; idx += 256) {
      int ci = idx / (IH * IW);
      int r = idx - ci * (IH * IW);
      int iy = r / IW;
      int ix = r - iy * IW;
      int gh = h0 - PAD + iy, gw = w0 - PAD + ix;
      float v = 0.f;
      if ((unsigned)gh < 64u && (unsigned)gw < 64u)
        v = in[((((size_t)(b * CIN + ci0 + ci)) << 6) + (size_t)gh << 6) + gw] * scale;
      s_in[ci][iy][ix] = v;
    }
    for (int idx = tid; idx < CI_T * KK * 16; idx += 256) {
      int co = idx & 15;
      int t = (idx >> 4) % KK;
      int ci = (idx >> 4) / KK;
      s_w[(ci * KK + t) * 16 + co] =
          wgt[((size_t)(co0 + co) * CIN + ci0 + ci) * KK + t];
    }
    __syncthreads();
    for (int ci = 0; ci < CI_T; ++ci) {
#pragma unroll
      for (int t = 0; t < KK; ++t) {
        int kh = t / K, kw = t - (t / K) * K;
        int iy = ty * 2 + kh * DIL, ix = tx * 2 + kw * DIL;
        float v00 = s_in[ci][iy][ix];
        float v01 = s_in[ci][iy][ix + 1];
        float v10 = s_in[ci][iy + 1][ix];
        float v11 = s_in[ci][iy + 1][ix + 1];
        const float4* wp = (const float4*)&s_w[(ci * KK + t) * 16];
#pragma unroll
        for (int q = 0; q < 4; ++q) {
          float4 wv = wp[q];
          float wj[4] = {wv.x, wv.y, wv.z, wv.w};
#pragma unroll
          for (int r = 0; r < 4; ++r) {
            a00[q * 4 + r] += v00 * wj[r];
            a01[q * 4 + r] += v01 * wj[r];
            a10[q * 4 + r] += v10 * wj[r];
            a11[q * 4 + r] += v11 * wj[r];
          }
        }
      }
    }
    __syncthreads();
  }
  int oh = h0 + ty * 2, ow = w0 + tx * 2;
#pragma unroll
  for (int j = 0; j < 16; ++j) {
    int co = co0 + j;
    float bs = bias[co];
    float r00 = a00[j] + bs, r01 = a01[j] + bs;
    float r10 = a10[j] + bs, r11 = a11[j] + bs;
    if (OUTMODE == 1) {
      r00 = tanhf(r00); r01 = tanhf(r01);
      r10 = tanhf(r10); r11 = tanhf(r11);
    }
    size_t ob = ((((size_t)(b * COUT + co)) << 6) + (size_t)oh) << 6;
    *(float2*)&out[ob + ow] = make_float2(r00, r01);
    *(float2*)&out[ob + 64 + ow] = make_float2(r10, r11);
  }
}

// ---------------- Haar IDWT ------------------------------------------------
__global__ void __launch_bounds__(256) idwt_k(
    const float* __restrict__ ca, const float* __restrict__ ch,
    const float* __restrict__ cv, const float* __restrict__ cd,
    float* __restrict__ out) {
  int i = blockIdx.x * 256 + threadIdx.x;
  float A = ca[i], Hd = ch[i], V = cv[i], D = cd[i];
  float y00 = (A + Hd + V + D) * 0.5f;
  float y01 = (A + Hd - V - D) * 0.5f;
  float y10 = (A - Hd + V - D) * 0.5f;
  float y11 = (A - Hd - V + D) * 0.5f;
  int w = i & 63;
  int h = (i >> 6) & 63;
  int bc = i >> 12;
  size_t ob = (((size_t)bc * 128) + 2 * h) * 128 + 2 * w;
  *(float2*)&out[ob] = make_float2(y00, y01);
  *(float2*)&out[ob + 128] = make_float2(y10, y11);
}

// ---------------------------------------------------------------------------
extern "C" void kernel_launch(void* const* d_in, const int* in_sizes, int n_in,
                              void* d_out, int out_size, void* d_ws,
                              size_t ws_size, hipStream_t stream) {
  const float* ll_freq = (const float*)d_in[0];
  const float* hl_freq = (const float*)d_in[1];
  const float* lh_freq = (const float*)d_in[2];
  const float* hh_freq = (const float*)d_in[3];
  const float* w_ll = (const float*)d_in[4];
  const float* w_hl = (const float*)d_in[5];
  const float* w_lh = (const float*)d_in[6];
  const float* w_hh = (const float*)d_in[7];
  const float* cc_w = (const float*)d_in[8];
  const float* cc_b = (const float*)d_in[9];
  const float* bnc_g = (const float*)d_in[10];
  const float* bnc_b = (const float*)d_in[11];
  const float* e1_w = (const float*)d_in[12];
  const float* e1_b = (const float*)d_in[13];
  const float* fe_w = (const float*)d_in[14];
  const float* fe_b = (const float*)d_in[15];
  const float* e2_w = (const float*)d_in[16];
  const float* e2_b = (const float*)d_in[17];
  const float* bne_g = (const float*)d_in[18];
  const float* bne_b = (const float*)d_in[19];
  const float* cr_w = (const float*)d_in[20];
  const float* cr_b = (const float*)d_in[21];
  const float* bnr_g = (const float*)d_in[22];
  const float* bnr_b = (const float*)d_in[23];
  const float* adj_w = (const float*)d_in[24];
  const float* adj_b = (const float*)d_in[25];
  const float* cll_w = (const float*)d_in[26];
  const float* cll_b = (const float*)d_in[27];
  const float* chh_w = (const float*)d_in[28];
  const float* chh_b = (const float*)d_in[29];
  const float* c1_w = (const float*)d_in[30];
  const float* c1_b = (const float*)d_in[31];
  const float* c3_w = (const float*)d_in[32];
  const float* c3_b = (const float*)d_in[33];
  const float* c5_w = (const float*)d_in[34];
  const float* c5_b = (const float*)d_in[35];

  const size_t MB = 1ull << 20;
  char* ws = (char*)d_ws;
  unsigned short* y4h = (unsigned short*)(ws);            // 32MB
  unsigned short* y4l = (unsigned short*)(ws + 32 * MB);  // 32MB
  float* regA = (float*)(ws);
  unsigned short* E2h = (unsigned short*)(ws + 64 * MB);  // 32MB
  unsigned short* E2l = (unsigned short*)(ws + 96 * MB);  // 32MB
  float* y7   = (float*)(ws + 128 * MB);                  // 16MB
  float* y1   = (float*)(ws + 144 * MB);                  // 2MB
  float* y2   = (float*)(ws + 146 * MB);                  // 2MB
  unsigned short* Wt = (unsigned short*)(ws + 148 * MB);  // 13.1MB
  char* base162 = ws + 162 * MB;
  float* hh_m = (float*)(base162);                        // 128KB
  float* st1  = (float*)(base162 + 128 * 1024);           // 32 f
  float* SM   = (float*)(base162 + 132 * 1024);           // 1280 f
  float* AB2  = (float*)(base162 + 140 * 1024);           // 1024 f
  float* AB3  = (float*)(base162 + 146 * 1024);           // 256 f
  unsigned short* Wc1  = (unsigned short*)(base162 + 256 * 1024);
  unsigned short* Wc3  = (unsigned short*)(base162 + 512 * 1024);
  unsigned short* Wc5  = (unsigned short*)(base162 + 768 * 1024);
  unsigned short* Wcll = (unsigned short*)(base162 + 1280 * 1024);
  unsigned short* Wcr  = (unsigned short*)(base162 + 1536 * 1024);  // 128KB
  float* s512 = SM;            // [512]
  float* q512 = SM + 512;      // [512]
  float* s128 = SM + 1024;     // [128]
  float* q128 = SM + 1152;     // [128]

  const size_t F2M = 2097152;
  float* ll_a  = regA + 0 * F2M;
  float* ll_l2 = regA + 1 * F2M;
  float* hl_l2 = regA + 2 * F2M;
  float* lh_l2 = regA + 3 * F2M;
  unsigned short* Ph = (unsigned short*)(ws + 48 * MB);
  unsigned short* Pl = (unsigned short*)(ws + 52 * MB);
  unsigned short* Qh = (unsigned short*)(ws + 56 * MB);
  unsigned short* Ql = (unsigned short*)(ws + 60 * MB);
  float* S = (float*)(ws + 64 * MB);   // boxsum scratch (pre-e2, in regB)
  float* hh_l2 = (float*)(ws + 64 * MB);  // post-cr reuse

  dim3 blk(256);

  zero_k<<<dim3(1), blk, 0, stream>>>(SM);

  // weight preps
  prep_w_k<<<dim3(1600), blk, 0, stream>>>(e2_w, Wt);
  prep_wcr_k<<<dim3(16), blk, 0, stream>>>(cr_w, Wcr);
  prep_ws_k<<<dim3(18), blk, 0, stream>>>(c1_w, Wc1, 64, 9);
  prep_ws_k<<<dim3(50), blk, 0, stream>>>(c3_w, Wc3, 64, 25);
  prep_ws_k<<<dim3(98), blk, 0, stream>>>(c5_w, Wc5, 64, 49);
  prep_ws_k<<<dim3(50), blk, 0, stream>>>(cll_w, Wcll, 64, 25);

  // median branch
  boxsum_k<<<dim3(512), blk, 0, stream>>>(hh_freq, w_hh, S);
  med_k<<<dim3(512), blk, 0, stream>>>(S, hh_m);

  // cc 1x1 concat(w_hl*hl, w_lh*lh) 128->16
  conv1x1_k<<<dim3(32, 1, 8), blk, 0, stream>>>(
      hl_freq, lh_freq, 64, w_hl, w_lh, nullptr, nullptr, nullptr, nullptr, 1,
      cc_w, cc_b, y1, 128, 16, 0, nullptr, nullptr, 0);

  // e1 3x3 16->16
  convK_k<3, 1, 8, 0><<<dim3(2, 2, 8), blk, 0, stream>>>(y1, e1_w, e1_b, y2, 16,
                                                         16, nullptr);
  stats_k<<<dim3(16), blk, 0, stream>>>(y2, st1, 16, 8);

  // fe 1x1 16->512 (relu(bn)) -> bf16 hi/lo packed
  conv1x1_k<<<dim3(32, 16, 8), blk, 0, stream>>>(
      y2, nullptr, 0, nullptr, nullptr, st1, bnc_g, bnc_b, nullptr, 2, fe_w,
      fe_b, nullptr, 16, 512, 2, y4h, y4l, 0);

  // e2 5x5 512->512 MFMA (packed out + bne sums)
  e2_mfma_k<<<dim3(1024), blk, 0, stream>>>(y4h, y4l, Wt, e2_b, E2h, E2l, s512,
                                            q512);
  finalize_k<<<dim3(1), dim3(512), 0, stream>>>(s512, q512, bne_g, bne_b,
                                                1.f / 32768.f, 512, AB2);

  // cr 1x1 512->128 MFMA (BN+ReLU fused in; y7 + bnr sums)
  cr_mfma_k<<<dim3(64, 8), blk, 0, stream>>>(E2h, E2l, Wcr, AB2, cr_b, y7, s128,
                                             q128);
  finalize_k<<<dim3(1), dim3(128), 0, stream>>>(s128, q128, bnr_g, bnr_b,
                                                1.f / 32768.f, 128, AB3);

  // LL branch: pack(w_ll*ll) -> c1 -> c3 -> c5
  pack_k<<<dim3(512), blk, 0, stream>>>(ll_freq, w_ll, Ph, Pl);
  convmf_k<3, 1, 0><<<dim3(256), blk, 0, stream>>>(Ph, Pl, Wc1, c1_b, nullptr,
                                                   Qh, Ql);
  convmf_k<5, 1, 0><<<dim3(256), blk, 0, stream>>>(Qh, Ql, Wc3, c3_b, nullptr,
                                                   Ph, Pl);
  convmf_k<7, 1, 1><<<dim3(256), blk, 0, stream>>>(Ph, Pl, Wc5, c5_b, ll_a,
                                                   nullptr, nullptr);

  // adj convs: ll plain concat, hl/lh with fused sigmoid gate
  conv1x1_k<<<dim3(32, 2, 8), blk, 0, stream>>>(
      ll_a, ll_freq, 64, nullptr, w_ll, nullptr, nullptr, nullptr, nullptr, 1,
      adj_w, adj_b, ll_l2, 128, 64, 0, nullptr, nullptr, 0);
  conv1x1_k<<<dim3(32, 2, 8), blk, 0, stream>>>(
      y7, hl_freq, 64, nullptr, w_hl, AB3, nullptr, nullptr, nullptr, 4, adj_w,
      adj_b, hl_l2, 128, 64, 0, nullptr, nullptr, 0);
  conv1x1_k<<<dim3(32, 2, 8), blk, 0, stream>>>(
      y7, lh_freq, 64, nullptr, w_lh, AB3, nullptr, nullptr, nullptr, 4, adj_w,
      adj_b, lh_l2, 128, 64, 0, nullptr, nullptr, 64);

  // hh_a = leaky_relu(chh(hh_freq + hh_m)) -> packed
  conv1x1_k<<<dim3(32, 2, 8), blk, 0, stream>>>(
      hh_freq, nullptr, 0, nullptr, nullptr, nullptr, nullptr, nullptr, hh_m, 3,
      chh_w, chh_b, nullptr, 64, 64, 3, Qh, Ql, 0);

  // hh_l2 = tanh(cll 5x5 dil2)
  convmf_k<5, 2, 2><<<dim3(256), blk, 0, stream>>>(Qh, Ql, Wcll, cll_b, hh_l2,
                                                   nullptr, nullptr);

  // IDWT
  idwt_k<<<dim3(8192), blk, 0, stream>>>(ll_l2, hl_l2, lh_l2, hh_l2,
                                         (float*)d_out);
}

// Round 7
// 989.560 us; speedup vs baseline: 8.5238x; 1.4627x over previous
//
#include <hip/hip_runtime.h>
#include <math.h>

// ---------------------------------------------------------------------------
// FeatureProcessor forward. B=8, C=64, H=W=64, RED=16, EXP=512.
// e2: bf16 MFMA implicit GEMM, A = bf16-hi ONLY (error ~1e-3 at output,
// threshold 0.149). Small convs keep split-A hi+lo. adj 1x1s -> MFMA with
// fused sigmoid gate (R6 bug: M-tile half-covered; fixed: acc[4][2]).
//
// Workspace:
//   [0,32M) y4h (fe out). post-e2 reuse: ll_a[0,8) ll_l2[8,16)
//           hl_l2[16,24) lh_l2[24,32)
//   [32,64M): Ph@48 Pl@52 Qh@56 Ql@60 (post-e2)
//   [64,96M) E2h (e2 out packed bf16-hi). pre-e2: boxsum S[64,72);
//            post-cr: hh_l2[64,72)
//   [128,144M) y7 ; [144,146M) y1 ; [146,148M) y2
//   [148,~161M) Wt e2 weights
//   [162M..): hh_m, st1, SM, AB2, AB3, Wc1/3/5, Wcll, Wcr, Wadj
// ---------------------------------------------------------------------------

#define HWP 4096

typedef __attribute__((ext_vector_type(8))) short bf16x8;
typedef __attribute__((ext_vector_type(4))) float f32x4;

__device__ __forceinline__ unsigned short f2bf(float x) {
  unsigned int u = __float_as_uint(x);
  unsigned int r = (u + 0x7fffu + ((u >> 16) & 1u)) >> 16;
  return (unsigned short)r;
}
__device__ __forceinline__ float bf2f(unsigned short h) {
  return __uint_as_float(((unsigned int)h) << 16);
}

__device__ __forceinline__ void gload16(const void* g, void* l) {
  __builtin_amdgcn_global_load_lds(
      (const __attribute__((address_space(1))) unsigned int*)g,
      (__attribute__((address_space(3))) unsigned int*)l, 16, 0, 0);
}

// ---------------- finalize: sums -> BN affine ------------------------------
__global__ void finalize_k(const float* __restrict__ s,
                           const float* __restrict__ q,
                           const float* __restrict__ gamma,
                           const float* __restrict__ beta, float invN, int C,
                           float* __restrict__ ab) {
  int c = threadIdx.x;
  if (c < C) {
    float mean = s[c] * invN;
    float var = q[c] * invN - mean * mean;
    float a = gamma[c] * rsqrtf(fmaxf(var, 0.f) + 1e-5f);
    ab[c] = a;
    ab[C + c] = beta[c] - mean * a;
  }
}

// ---------------- box-sum 5x5 reflect (per b,c) ----------------------------
__global__ void __launch_bounds__(256) boxsum_k(
    const float* __restrict__ hh, const float* __restrict__ w_hh,
    float* __restrict__ S) {
  __shared__ float img[64][65];
  __shared__ float rs[64][65];
  int bc = blockIdx.x;
  const float* src = hh + ((size_t)bc << 12);
  float wv = w_hh[0];
  int tid = threadIdx.x;
  for (int i = tid; i < 4096; i += 256) img[i >> 6][i & 63] = src[i] * wv;
  __syncthreads();
  for (int i = tid; i < 4096; i += 256) {
    int h = i >> 6, w = i & 63;
    float s = 0.f;
#pragma unroll
    for (int d = -2; d <= 2; ++d) {
      int ww = w + d;
      ww = ww < 0 ? -ww : (ww > 63 ? 126 - ww : ww);
      s += img[h][ww];
    }
    rs[h][w] = s;
  }
  __syncthreads();
  float* dst = S + ((size_t)bc << 12);
  for (int i = tid; i < 4096; i += 256) {
    int h = i >> 6, w = i & 63;
    float s = 0.f;
#pragma unroll
    for (int d = -2; d <= 2; ++d) {
      int h2 = h + d;
      h2 = h2 < 0 ? -h2 : (h2 > 63 ? 126 - h2 : h2);
      s += rs[h2][w];
    }
    dst[i] = s;
  }
}

// ---------------- median over 64 channels ----------------------------------
__global__ void __launch_bounds__(256) med_k(const float* __restrict__ S,
                                             float* __restrict__ hh_m) {
  __shared__ float ldsS[64][65];
  int bx = blockIdx.x;
  int b = bx >> 6, h = bx & 63;
  int tid = threadIdx.x;
  for (int i = tid; i < 4096; i += 256) {
    int c = i >> 6, w = i & 63;
    ldsS[c][w] = S[((size_t)(b * 64 + c) << 12) + (h << 6) + w];
  }
  __syncthreads();
  int lane = tid & 63, wv = tid >> 6;
  for (int i = 0; i < 16; ++i) {
    int w = wv * 16 + i;
    float s = ldsS[lane][w];
    for (int k = 2; k <= 64; k <<= 1)
      for (int j = k >> 1; j > 0; j >>= 1) {
        float o = __shfl_xor(s, j, 64);
        bool up = (lane & k) == 0;
        bool low = (lane & j) == 0;
        s = (low == up) ? fminf(s, o) : fmaxf(s, o);
      }
    float v31 = __shfl(s, 31, 64);
    float v32 = __shfl(s, 32, 64);
    if (lane == 0) hh_m[(b << 12) + (h << 6) + w] = 0.5f * (v31 + v32);
  }
}

// ---------------- per-channel mean/invstd (bnc only) -----------------------
__global__ void __launch_bounds__(256) stats_k(
    const float* __restrict__ x, float* __restrict__ stats, int C, int B) {
  int c = blockIdx.x;
  int tid = threadIdx.x;
  int N = B * HWP;
  float s = 0.f, q = 0.f;
  for (int i = tid; i < N; i += 256) {
    int b = i >> 12, p = i & 4095;
    float v = x[(((size_t)(b * C + c)) << 12) + p];
    s += v;
    q += v * v;
  }
  __shared__ float rs[256], rq[256];
  rs[tid] = s; rq[tid] = q;
  __syncthreads();
  for (int st = 128; st > 0; st >>= 1) {
    if (tid < st) { rs[tid] += rs[tid + st]; rq[tid] += rq[tid + st]; }
    __syncthreads();
  }
  if (tid == 0) {
    float mean = rs[0] / (float)N;
    float var = rq[0] / (float)N - mean * mean;
    stats[c] = mean;
    stats[C + c] = rsqrtf(fmaxf(var, 0.f) + 1e-5f);
  }
}

// ---------------- 1x1 conv (pointwise GEMM) with fused input modes ---------
__global__ void __launch_bounds__(256) conv1x1_k(
    const float* __restrict__ inA, const float* __restrict__ inB, int C1,
    const float* __restrict__ sA, const float* __restrict__ sB,
    const float* __restrict__ bn_stats, const float* __restrict__ bn_g,
    const float* __restrict__ bn_b, const float* __restrict__ extra, int mode,
    const float* __restrict__ wgt, const float* __restrict__ bias,
    float* __restrict__ out, int CIN, int COUT, int out_mode,
    unsigned short* __restrict__ o_hi, unsigned short* __restrict__ o_lo) {
  __shared__ __align__(16) float s_in[16][128];
  __shared__ __align__(16) float s_w[16][32];
  __shared__ __align__(16) short sOH[4096];
  __shared__ __align__(16) short sOL[4096];
  int tid = threadIdx.x;
  int p0 = blockIdx.x * 128;
  int co0 = blockIdx.y * 32;
  int b = blockIdx.z;
  float fA = sA ? sA[0] : 1.f;
  float fB = sB ? sB[0] : 1.f;
  int pi = tid & 63;
  int cog = tid >> 6;
  float acc0[8] = {0.f, 0.f, 0.f, 0.f, 0.f, 0.f, 0.f, 0.f};
  float acc1[8] = {0.f, 0.f, 0.f, 0.f, 0.f, 0.f, 0.f, 0.f};
  for (int ci0 = 0; ci0 < CIN; ci0 += 16) {
#pragma unroll
    for (int t = 0; t < 8; ++t) {
      int idx = tid + t * 256;
      int ci = idx >> 7, pp = idx & 127;
      int c = ci0 + ci;
      int p = p0 + pp;
      float v;
      if (mode == 1) {
        v = (c < C1) ? fA * inA[(((size_t)(b * C1 + c)) << 12) + p]
                     : fB * inB[(((size_t)(b * (CIN - C1) + (c - C1))) << 12) + p];
      } else {
        v = inA[(((size_t)(b * CIN + c)) << 12) + p];
        if (mode == 2) {
          v = (v - bn_stats[c]) * bn_stats[CIN + c] * bn_g[c] + bn_b[c];
          v = fmaxf(v, 0.f);
        } else if (mode == 3) {
          v += extra[(b << 12) + p];
        }
      }
      s_in[ci][pp] = v;
    }
#pragma unroll
    for (int t = 0; t < 2; ++t) {
      int idx = tid + t * 256;
      int ci = idx >> 5, co = idx & 31;
      float wv = 0.f;
      if (co0 + co < COUT) wv = wgt[(size_t)(co0 + co) * CIN + ci0 + ci];
      s_w[ci][co] = wv;
    }
    __syncthreads();
#pragma unroll
    for (int ci = 0; ci < 16; ++ci) {
      float2 v01 = *(const float2*)&s_in[ci][pi * 2];
      const float4* wp = (const float4*)&s_w[ci][cog * 8];
#pragma unroll
      for (int q = 0; q < 2; ++q) {
        float4 wv = wp[q];
        float wj[4] = {wv.x, wv.y, wv.z, wv.w};
#pragma unroll
        for (int r = 0; r < 4; ++r) {
          acc0[q * 4 + r] += v01.x * wj[r];
          acc1[q * 4 + r] += v01.y * wj[r];
        }
      }
    }
    __syncthreads();
  }
  if (out_mode >= 2) {
#pragma unroll
    for (int j = 0; j < 8; ++j) {
      int co = co0 + cog * 8 + j;
      float bs = bias[co];
      float r[2] = {acc0[j] + bs, acc1[j] + bs};
#pragma unroll
      for (int e = 0; e < 2; ++e) {
        float v = r[e];
        if (out_mode == 3) v = v < 0.f ? 0.1f * v : v;
        int px = pi * 2 + e;
        int w = px & 63;
        int slot = ((cog ^ ((w >> 1) & 3)) << 3) + j;
        int o = px * 32 + slot;
        unsigned short hsh = f2bf(v);
        sOH[o] = (short)hsh;
        if (o_lo) sOL[o] = (short)f2bf(v - bf2f(hsh));
      }
    }
    __syncthreads();
    int cb = co0 >> 5;
    size_t base = (size_t)(b * (COUT >> 5) + cb) * 131072 + (size_t)p0 * 32;
    for (int k = tid; k < 512; k += 256) {
      *(float4*)(o_hi + base + (size_t)k * 8) = *(float4*)&sOH[k * 8];
      if (o_lo)
        *(float4*)(o_lo + base + (size_t)k * 8) = *(float4*)&sOL[k * 8];
    }
  } else {
#pragma unroll
    for (int j = 0; j < 8; ++j) {
      int co = co0 + cog * 8 + j;
      if (co < COUT) {
        float bs = bias[co];
        float r0 = acc0[j] + bs;
        float r1 = acc1[j] + bs;
        if (out_mode == 1) {
          r0 = r0 < 0.f ? 0.1f * r0 : r0;
          r1 = r1 < 0.f ? 0.1f * r1 : r1;
        }
        float2 rr = make_float2(r0, r1);
        *(float2*)&out[(((size_t)(b * COUT + co)) << 12) + p0 + pi * 2] = rr;
      }
    }
  }
}

// ---------------- pack NCHW fp32 -> channels-last hi/lo bf16 ---------------
__global__ void __launch_bounds__(256) pack_k(
    const float* __restrict__ in, const float* __restrict__ scale_ptr,
    unsigned short* __restrict__ o_hi, unsigned short* __restrict__ o_lo) {
  __shared__ float lds[32][130];
  int bx = blockIdx.x;
  int pc = bx & 31, cb = (bx >> 5) & 1, b = bx >> 6;
  int p0 = pc * 128;
  float sc = scale_ptr ? scale_ptr[0] : 1.f;
  int tid = threadIdx.x;
  for (int i = tid; i < 4096; i += 256) {
    int c = i >> 7, px = i & 127;
    lds[c][px] = in[((size_t)(b * 64 + cb * 32 + c) << 12) + p0 + px] * sc;
  }
  __syncthreads();
  size_t base = (size_t)(b * 2 + cb) * 131072 + (size_t)p0 * 32;
  for (int k = tid; k < 512; k += 256) {
    int p = k >> 2, gsw = k & 3;
    int w = p & 63;
    int g = gsw ^ ((w >> 1) & 3);
    bf16x8 hi, lo;
#pragma unroll
    for (int j = 0; j < 8; ++j) {
      float v = lds[g * 8 + j][p];
      unsigned short h = f2bf(v);
      hi[j] = (short)h;
      lo[j] = (short)f2bf(v - bf2f(h));
    }
    *(bf16x8*)(o_hi + base + (size_t)k * 8) = hi;
    *(bf16x8*)(o_lo + base + (size_t)k * 8) = lo;
  }
}

// ---------------- small-conv weight transform (shared body) ----------------
__device__ __forceinline__ void ws_body(const float* __restrict__ w,
                                        unsigned short* __restrict__ Wt,
                                        int bx, int CIN, int KK) {
  int cbci = bx / KK, tap = bx - cbci * KK;
  unsigned short* dst = Wt + (size_t)bx * 2048;
  for (int d = threadIdx.x; d < 2048; d += 256) {
    int co = d >> 5, s = d & 31;
    int g = (s >> 3) ^ ((co >> 1) & 3);
    int cil = (g << 3) + (s & 7);
    dst[d] = f2bf(w[(size_t)(co * CIN + cbci * 32 + cil) * KK + tap]);
  }
}

// ---------------- fat prep: all weight transforms + stats zero -------------
__global__ void __launch_bounds__(256) prep_all_k(
    const float* __restrict__ e2w, const float* __restrict__ crw,
    const float* __restrict__ c1w, const float* __restrict__ c3w,
    const float* __restrict__ c5w, const float* __restrict__ cllw,
    const float* __restrict__ adjw, unsigned short* __restrict__ Wt,
    unsigned short* __restrict__ Wcr, unsigned short* __restrict__ Wc1,
    unsigned short* __restrict__ Wc3, unsigned short* __restrict__ Wc5,
    unsigned short* __restrict__ Wcll, unsigned short* __restrict__ Wadj,
    float* __restrict__ SM) {
  __shared__ short lw[32][800];
  int bx = blockIdx.x, tid = threadIdx.x;
  if (bx < 256) {
    // e2 weights, LDS-transposed: coalesced read AND write
    int cbco = bx >> 6, cbci = (bx >> 2) & 15, cog = bx & 3;
    const float* src =
        e2w + ((size_t)(cbco * 128 + cog * 32) * 512 + cbci * 32) * 25;
    for (int i = tid; i < 25600; i += 256) {
      int co_l = i / 800, r = i - co_l * 800;  // r = ci_l*25 + tap
      lw[co_l][r] = (short)f2bf(src[(size_t)co_l * 12800 + r]);
    }
    __syncthreads();
    unsigned short* dstb =
        Wt + (((size_t)((cbco * 16 + cbci) * 25)) << 12) + cog * 1024;
    for (int k = tid; k < 6400; k += 256) {
      int tap = k >> 8, d4 = (k & 255) << 2;
      short4 o;
      short* op = (short*)&o;
#pragma unroll
      for (int u = 0; u < 4; ++u) {
        int d = d4 + u;
        int col = d >> 5, s = d & 31;
        int g = (s >> 3) ^ ((col >> 1) & 3);
        int cil = (g << 3) + (s & 7);
        op[u] = lw[col][cil * 25 + tap];
      }
      *(short4*)(dstb + (size_t)tap * 4096 + d4) = o;
    }
  } else if (bx < 272) {
    int cb = bx - 256;
    unsigned short* dst = Wcr + (size_t)cb * 4096;
    for (int d = tid; d < 4096; d += 256) {
      int co = d >> 5, s = d & 31;
      int g = (s >> 3) ^ ((co >> 1) & 3);
      int cil = (g << 3) + (s & 7);
      dst[d] = f2bf(crw[(size_t)co * 512 + cb * 32 + cil]);
    }
  } else if (bx < 290) {
    ws_body(c1w, Wc1, bx - 272, 64, 9);
  } else if (bx < 340) {
    ws_body(c3w, Wc3, bx - 290, 64, 25);
  } else if (bx < 438) {
    ws_body(c5w, Wc5, bx - 340, 64, 49);
  } else if (bx < 488) {
    ws_body(cllw, Wcll, bx - 438, 64, 25);
  } else if (bx < 492) {
    ws_body(adjw, Wadj, bx - 488, 128, 1);
  } else {
    for (int i = tid; i < 1280; i += 256) SM[i] = 0.f;
  }
}

// ---------------- e2: MFMA implicit GEMM, A = bf16-hi only -----------------
// LDS: A 26112 (6 rows x 68 x 64B) | B dbuf 2x8192 @26624. Total 43008 ->
// 3 blocks/CU. Epilogue: pack bf16-hi channels-last + bne sum/sq atomics.
__global__ void __launch_bounds__(256, 3) e2_mfma_k(
    const unsigned short* __restrict__ y4h, const unsigned short* __restrict__ Wt,
    const float* __restrict__ bias, unsigned short* __restrict__ E2h,
    float* __restrict__ sum5, float* __restrict__ sq5) {
  __shared__ __align__(16) char smem[43008];
  const int tid = threadIdx.x;
  const int lane = tid & 63;
  const int wid = tid >> 6;
  int logical = ((blockIdx.x & 7) << 7) + (blockIdx.x >> 3);  // XCD chunking
  int cbco = logical >> 8;
  int rem = logical & 255;
  int rowpair = rem >> 3;
  int b = rem & 7;
  int h0 = rowpair << 1;
  const int wm = wid >> 1, wn = wid & 1;
  const int l15 = lane & 15, lg = lane >> 4;

  int colterm[4][5];
#pragma unroll
  for (int mi = 0; mi < 4; ++mi)
#pragma unroll
    for (int kw = 0; kw < 5; ++kw) {
      int col = mi * 16 + l15 + kw;  // entry = w_in + 2
      colterm[mi][kw] = col * 64 + ((lg ^ (((col + 62) >> 1) & 3)) << 4);
    }
  int bterm[4];
#pragma unroll
  for (int ni = 0; ni < 4; ++ni) {
    int c = wn * 64 + ni * 16 + l15;
    bterm[ni] = c * 64 + ((lg ^ ((c >> 1) & 3)) << 4);
  }

  if (tid < 96) {  // zero halo columns 0,1,66,67
    int g = tid & 3, e = tid >> 2;
    int s = e >> 2, cp = e & 3;
    int col = (cp < 2) ? cp : (64 + cp);
    *(float4*)(smem + s * 4352 + col * 64 + g * 16) =
        make_float4(0.f, 0.f, 0.f, 0.f);
  }

  f32x4 acc[4][4];
#pragma unroll
  for (int i = 0; i < 4; ++i)
#pragma unroll
    for (int j = 0; j < 4; ++j) acc[i][j] = (f32x4)(0.f);

#pragma unroll 1
  for (int cb = 0; cb < 16; ++cb) {
    // ---- stage A (6 rows x 64 cols x 32ci, hi only; all 4 waves) ----
#pragma unroll
    for (int s = 0; s < 6; ++s) {
      int irow = h0 - 2 + s;
      char* ldsrow = smem + s * 4352 + 128;
      if ((unsigned)irow < 64u) {
        const unsigned short* src =
            y4h + (((size_t)(b * 16 + cb) * 64 + irow) << 11);
        gload16(src + (wid << 9) + (lane << 3), ldsrow + (wid << 10));
      } else {
        *(float4*)(ldsrow + (wid << 10) + (lane << 4)) =
            make_float4(0.f, 0.f, 0.f, 0.f);
      }
    }
    // ---- stage B tap 0 into buf 0 ----
    {
      const unsigned short* src = Wt + ((size_t)((cbco * 16 + cb) * 25) << 12);
#pragma unroll
      for (int k = 0; k < 2; ++k) {
        int c2 = wid * 2 + k;
        gload16(src + (c2 << 9) + (lane << 3), smem + 26624 + (c2 << 10));
      }
    }
    __syncthreads();

#pragma unroll 1
    for (int kh = 0; kh < 5; ++kh) {
      int abase = (wm + kh) * 4352;
#pragma unroll
      for (int kw = 0; kw < 5; ++kw) {
        int tap = kh * 5 + kw;
        if (tap < 24) {  // prefetch next tap's B
          const unsigned short* src =
              Wt + ((size_t)((cbco * 16 + cb) * 25 + tap + 1) << 12);
          int buf = (tap + 1) & 1;
#pragma unroll
          for (int k = 0; k < 2; ++k) {
            int c2 = wid * 2 + k;
            gload16(src + (c2 << 9) + (lane << 3),
                    smem + 26624 + (buf << 13) + (c2 << 10));
          }
        }
        char* bbase = smem + 26624 + ((tap & 1) << 13);
        bf16x8 bfr[4];
#pragma unroll
        for (int ni = 0; ni < 4; ++ni)
          bfr[ni] = *(bf16x8*)(bbase + bterm[ni]);
#pragma unroll
        for (int mi = 0; mi < 4; ++mi) {
          bf16x8 ah = *(bf16x8*)(smem + abase + colterm[mi][kw]);
#pragma unroll
          for (int ni = 0; ni < 4; ++ni) {
            acc[mi][ni] = __builtin_amdgcn_mfma_f32_16x16x32_bf16(
                ah, bfr[ni], acc[mi][ni], 0, 0, 0);
          }
        }
        __syncthreads();
      }
    }
  }

  // ---- epilogue: pack bf16-hi channels-last + stats atomics ----
  short* H = (short*)smem;  // [4 cb_l][128 px][32 slot] = 32KB
#pragma unroll
  for (int ni = 0; ni < 4; ++ni) {
    int co_l = wn * 64 + ni * 16 + l15;
    int cb_l = co_l >> 5, ch = co_l & 31;
    float bs = bias[cbco * 128 + co_l];
    float ps = 0.f, pq = 0.f;
#pragma unroll
    for (int mi = 0; mi < 4; ++mi) {
#pragma unroll
      for (int j = 0; j < 4; ++j) {
        int w = mi * 16 + lg * 4 + j;
        float v = acc[mi][ni][j] + bs;
        ps += v;
        pq += v * v;
        int slot = (((ch >> 3) ^ ((w >> 1) & 3)) << 3) + (ch & 7);
        H[(cb_l * 128 + wm * 64 + w) * 32 + slot] = (short)f2bf(v);
      }
    }
    ps += __shfl_xor(ps, 16, 64); ps += __shfl_xor(ps, 32, 64);
    pq += __shfl_xor(pq, 16, 64); pq += __shfl_xor(pq, 32, 64);
    if (lg == 0) {
      atomicAdd(&sum5[cbco * 128 + co_l], ps);
      atomicAdd(&sq5[cbco * 128 + co_l], pq);
    }
  }
  __syncthreads();
  for (int k = tid; k < 2048; k += 256) {
    int cb_l = k >> 9, r = k & 511;
    size_t gb = ((size_t)(b * 16 + cbco * 4 + cb_l) * 4096 + h0 * 64) * 32 +
                (size_t)r * 8;
    *(float4*)(E2h + gb) = *(float4*)(H + cb_l * 4096 + r * 8);
  }
}

// ---------------- cr: MFMA GEMM K=512, BN+ReLU fused on input --------------
__global__ void __launch_bounds__(256, 2) cr_mfma_k(
    const unsigned short* __restrict__ E2h, const unsigned short* __restrict__ Wcr,
    const float* __restrict__ ab2, const float* __restrict__ bias,
    float* __restrict__ y7, float* __restrict__ sum3, float* __restrict__ sq3) {
  __shared__ __align__(16) char smem[20480];  // Ah 4K | Al 4K | B 8K | par 4K
  float* sa = (float*)(smem + 16384);
  float* sb = sa + 512;
  const int tid = threadIdx.x;
  const int lane = tid & 63;
  const int wid = tid >> 6;
  const int b = blockIdx.y;
  const int p0 = blockIdx.x << 6;
  const int wm = wid >> 1, wn = wid & 1;
  const int l15 = lane & 15, lg = lane >> 4;

  for (int i = tid; i < 512; i += 256) {
    sa[i] = ab2[i];
    sb[i] = ab2[512 + i];
  }

  int aterm[2];
#pragma unroll
  for (int mi = 0; mi < 2; ++mi) {
    int px = wm * 32 + mi * 16 + l15;
    aterm[mi] = px * 64 + ((lg ^ ((px >> 1) & 3)) << 4);
  }
  int bterm[4];
#pragma unroll
  for (int ni = 0; ni < 4; ++ni) {
    int c = wn * 64 + ni * 16 + l15;
    bterm[ni] = c * 64 + ((lg ^ ((c >> 1) & 3)) << 4);
  }

  f32x4 acc[2][4];
#pragma unroll
  for (int i = 0; i < 2; ++i)
#pragma unroll
    for (int j = 0; j < 4; ++j) acc[i][j] = (f32x4)(0.f);

  const int spx = tid >> 2, sgs = tid & 3;
  const int sg = sgs ^ ((spx >> 1) & 3);
  __syncthreads();

#pragma unroll 1
  for (int cb = 0; cb < 16; ++cb) {
    {
      size_t src = ((size_t)(b * 16 + cb) * 4096 + p0 + spx) * 32 + sgs * 8;
      bf16x8 h8 = *(const bf16x8*)(E2h + src);
      bf16x8 oh, ol;
      int cib = cb * 32 + sg * 8;
#pragma unroll
      for (int j = 0; j < 8; ++j) {
        float x = bf2f((unsigned short)h8[j]);
        float v = fmaxf(sa[cib + j] * x + sb[cib + j], 0.f);
        unsigned short hh2 = f2bf(v);
        oh[j] = (short)hh2;
        ol[j] = (short)f2bf(v - bf2f(hh2));
      }
      *(bf16x8*)(smem + spx * 64 + sgs * 16) = oh;
      *(bf16x8*)(smem + 4096 + spx * 64 + sgs * 16) = ol;
    }
    {
      const unsigned short* srcB = Wcr + (size_t)cb * 4096;
#pragma unroll
      for (int k = 0; k < 2; ++k) {
        int c2 = wid * 2 + k;
        gload16(srcB + (c2 << 9) + (lane << 3), smem + 8192 + (c2 << 10));
      }
    }
    __syncthreads();
    bf16x8 bfr[4];
#pragma unroll
    for (int ni = 0; ni < 4; ++ni)
      bfr[ni] = *(bf16x8*)(smem + 8192 + bterm[ni]);
#pragma unroll
    for (int mi = 0; mi < 2; ++mi) {
      bf16x8 ah = *(bf16x8*)(smem + aterm[mi]);
      bf16x8 al = *(bf16x8*)(smem + 4096 + aterm[mi]);
#pragma unroll
      for (int ni = 0; ni < 4; ++ni) {
        acc[mi][ni] = __builtin_amdgcn_mfma_f32_16x16x32_bf16(
            ah, bfr[ni], acc[mi][ni], 0, 0, 0);
        acc[mi][ni] = __builtin_amdgcn_mfma_f32_16x16x32_bf16(
            al, bfr[ni], acc[mi][ni], 0, 0, 0);
      }
    }
    __syncthreads();
  }

#pragma unroll
  for (int ni = 0; ni < 4; ++ni) {
    int co = wn * 64 + ni * 16 + l15;
    float bs = bias[co];
    float ps = 0.f, pq = 0.f;
#pragma unroll
    for (int mi = 0; mi < 2; ++mi) {
      f32x4 v = acc[mi][ni];
      v += (f32x4)(bs);
#pragma unroll
      for (int j = 0; j < 4; ++j) { ps += v[j]; pq += v[j] * v[j]; }
      int px = p0 + wm * 32 + mi * 16 + lg * 4;
      *(f32x4*)(y7 + (((size_t)(b * 128 + co)) << 12) + px) = v;
    }
    ps += __shfl_xor(ps, 16, 64); ps += __shfl_xor(ps, 32, 64);
    pq += __shfl_xor(pq, 16, 64); pq += __shfl_xor(pq, 32, 64);
    if (lg == 0) {
      atomicAdd(&sum3[co], ps);
      atomicAdd(&sq3[co], pq);
    }
  }
}

// ---------------- adj 1x1 (128->64) MFMA with fused sigmoid gate -----------
// var 0: concat(ll_a, w_ll*ll_freq) ; var 1/2: concat(gate(freq), freq)
// R7 FIX: M-tile is 128 px = 2 M-waves x 4 mi subtiles (was 2 -> half the
// pixels never written).
__global__ void __launch_bounds__(256) adj_mfma_k(
    const float* __restrict__ ll_a, const float* __restrict__ ll_freq,
    const float* __restrict__ hl_freq, const float* __restrict__ lh_freq,
    const float* __restrict__ y7, const float* __restrict__ ab3,
    const float* __restrict__ w_ll, const float* __restrict__ w_hl,
    const float* __restrict__ w_lh, const unsigned short* __restrict__ Wadj,
    const float* __restrict__ bias, float* __restrict__ ll_l2,
    float* __restrict__ hl_l2, float* __restrict__ lh_l2) {
  __shared__ __align__(16) char smem[20480];  // Ah 8K | Al 8K | B 4K
  const int tid = threadIdx.x;
  const int lane = tid & 63;
  const int wid = tid >> 6;
  const int p0 = (int)blockIdx.x << 7;
  const int var = blockIdx.y;
  const int b = blockIdx.z;
  const int wm = wid >> 1, wn = wid & 1;
  const int l15 = lane & 15, lg = lane >> 4;

  int aterm[4];
#pragma unroll
  for (int mi = 0; mi < 4; ++mi) {
    int px = wm * 64 + mi * 16 + l15;
    aterm[mi] = px * 64 + ((lg ^ ((px >> 1) & 3)) << 4);
  }
  int bterm[2];
#pragma unroll
  for (int ni = 0; ni < 2; ++ni) {
    int c = wn * 32 + ni * 16 + l15;
    bterm[ni] = c * 64 + ((lg ^ ((c >> 1) & 3)) << 4);
  }

  f32x4 acc[4][2];
#pragma unroll
  for (int i = 0; i < 4; ++i)
#pragma unroll
    for (int j = 0; j < 2; ++j) acc[i][j] = (f32x4)(0.f);

  const float* fr = (var == 1) ? hl_freq : lh_freq;
  float scl = (var == 0) ? w_ll[0] : ((var == 1) ? w_hl[0] : w_lh[0]);

#pragma unroll 1
  for (int cb = 0; cb < 4; ++cb) {
    // stage A: 128 px x 32 ci, gate/concat fused, hi/lo split
#pragma unroll 1
    for (int pass = 0; pass < 16; ++pass) {
      int ci = pass * 2 + (tid >> 7);
      int px = tid & 127;
      int c = cb * 32 + ci;
      int p = p0 + px;
      float v;
      if (var == 0) {
        v = (c < 64) ? ll_a[(((size_t)(b * 64 + c)) << 12) + p]
                     : scl * ll_freq[(((size_t)(b * 64 + c - 64)) << 12) + p];
      } else {
        if (c < 64) {
          int yc = (var == 1) ? c : (64 + c);
          float arg = ab3[yc] * y7[(((size_t)(b * 128 + yc)) << 12) + p] +
                      ab3[128 + yc];
          float sg = 1.f / (1.f + expf(-arg));
          v = scl * fr[(((size_t)(b * 64 + c)) << 12) + p] * sg;
        } else {
          v = fr[(((size_t)(b * 64 + c - 64)) << 12) + p];
        }
      }
      unsigned short h = f2bf(v);
      int gs = (ci >> 3) ^ ((px >> 1) & 3);
      int off = px * 64 + gs * 16 + (ci & 7) * 2;
      *(short*)(smem + off) = (short)h;
      *(short*)(smem + 8192 + off) = (short)f2bf(v - bf2f(h));
    }
    // stage B: 4KB weights
    gload16(Wadj + (size_t)cb * 2048 + (tid << 3), smem + 16384 + (tid << 4));
    __syncthreads();
    bf16x8 bfr[2];
#pragma unroll
    for (int ni = 0; ni < 2; ++ni)
      bfr[ni] = *(bf16x8*)(smem + 16384 + bterm[ni]);
#pragma unroll
    for (int mi = 0; mi < 4; ++mi) {
      bf16x8 ah = *(bf16x8*)(smem + aterm[mi]);
      bf16x8 al = *(bf16x8*)(smem + 8192 + aterm[mi]);
#pragma unroll
      for (int ni = 0; ni < 2; ++ni) {
        acc[mi][ni] = __builtin_amdgcn_mfma_f32_16x16x32_bf16(
            ah, bfr[ni], acc[mi][ni], 0, 0, 0);
        acc[mi][ni] = __builtin_amdgcn_mfma_f32_16x16x32_bf16(
            al, bfr[ni], acc[mi][ni], 0, 0, 0);
      }
    }
    __syncthreads();
  }

  float* out = (var == 0) ? ll_l2 : ((var == 1) ? hl_l2 : lh_l2);
#pragma unroll
  for (int ni = 0; ni < 2; ++ni) {
    int co = wn * 32 + ni * 16 + l15;
    float bs = bias[co];
#pragma unroll
    for (int mi = 0; mi < 4; ++mi) {
      f32x4 v = acc[mi][ni];
      v += (f32x4)(bs);
      int px = p0 + wm * 64 + mi * 16 + lg * 4;
      *(f32x4*)(out + (((size_t)(b * 64 + co)) << 12) + px) = v;
    }
  }
}

// ---------------- small KxK conv via MFMA (CIN=COUT=64, split-A) -----------
template <int K, int DIL, int OUTMODE>
__global__ void __launch_bounds__(256, 2) convmf_k(
    const unsigned short* __restrict__ inh, const unsigned short* __restrict__ inl,
    const unsigned short* __restrict__ Wsm, const float* __restrict__ bias,
    float* __restrict__ out_f, unsigned short* __restrict__ o_hi,
    unsigned short* __restrict__ o_lo) {
  constexpr int PAD = (K - 1) / 2 * DIL;
  constexpr int ROWS = 2 + 2 * PAD;
  constexpr int CW = 64 + 2 * PAD;
  constexpr int RB = CW * 64;
  constexpr int ABYTES = ROWS * RB;
  constexpr int KK = K * K;
  __shared__ __align__(16) char smem[2 * ABYTES + 8192];
  const int tid = threadIdx.x;
  const int lane = tid & 63;
  const int wid = tid >> 6;
  const int b = blockIdx.x >> 5;
  const int h0 = (blockIdx.x & 31) << 1;
  const int wm = wid >> 1, wn = wid & 1;
  const int l15 = lane & 15, lg = lane >> 4;

  int colterm[4][K];
#pragma unroll
  for (int mi = 0; mi < 4; ++mi)
#pragma unroll
    for (int kw = 0; kw < K; ++kw) {
      int e = mi * 16 + l15 + kw * DIL;
      colterm[mi][kw] = e * 64 + ((lg ^ (((e - PAD + 64) >> 1) & 3)) << 4);
    }
  int bterm[2];
#pragma unroll
  for (int ni = 0; ni < 2; ++ni) {
    int c = wn * 32 + ni * 16 + l15;
    bterm[ni] = c * 64 + ((lg ^ ((c >> 1) & 3)) << 4);
  }

  for (int i = tid; i < 2 * ROWS * 2 * PAD * 4; i += 256) {
    int c4 = i & 3;
    int r1 = i >> 2;
    int e = r1 % (2 * PAD);
    int r2 = r1 / (2 * PAD);
    int r = r2 % ROWS;
    int part = r2 / ROWS;
    int col = (e < PAD) ? e : (e + 64);
    *(float4*)(smem + part * ABYTES + r * RB + col * 64 + c4 * 16) =
        make_float4(0.f, 0.f, 0.f, 0.f);
  }

  f32x4 acc[4][2];
#pragma unroll
  for (int i = 0; i < 4; ++i)
#pragma unroll
    for (int j = 0; j < 2; ++j) acc[i][j] = (f32x4)(0.f);

  const int part = wid >> 1;
  const int s0 = (wid & 1) * (ROWS / 2);
  const unsigned short* srcA = part ? inl : inh;

#pragma unroll 1
  for (int cb = 0; cb < 2; ++cb) {
#pragma unroll
    for (int si = 0; si < ROWS / 2; ++si) {
      int s = s0 + si;
      int irow = h0 - PAD + s;
      char* ldsrow = smem + part * ABYTES + s * RB + PAD * 64;
      if ((unsigned)irow < 64u) {
        const unsigned short* src =
            srcA + (((size_t)(b * 2 + cb) << 12) + (irow << 6)) * 32;
#pragma unroll
        for (int c = 0; c < 4; ++c)
          gload16(src + (c << 9) + (lane << 3), ldsrow + (c << 10));
      } else {
#pragma unroll
        for (int c = 0; c < 4; ++c)
          *(float4*)(ldsrow + (c << 10) + (lane << 4)) =
              make_float4(0.f, 0.f, 0.f, 0.f);
      }
    }
    {
      const unsigned short* srcB = Wsm + (size_t)(cb * KK) * 2048;
      gload16(srcB + (tid << 3), smem + 2 * ABYTES + (tid << 4));
    }
    __syncthreads();

#pragma unroll 1
    for (int kh = 0; kh < K; ++kh) {
      int abase = (wm + kh * DIL) * RB;
#pragma unroll
      for (int kw = 0; kw < K; ++kw) {
        int tap = kh * K + kw;
        if (tap + 1 < KK) {
          const unsigned short* srcB = Wsm + (size_t)(cb * KK + tap + 1) * 2048;
          gload16(srcB + (tid << 3),
                  smem + 2 * ABYTES + (((tap + 1) & 1) << 12) + (tid << 4));
        }
        char* bbase = smem + 2 * ABYTES + ((tap & 1) << 12);
        bf16x8 bfr[2];
#pragma unroll
        for (int ni = 0; ni < 2; ++ni)
          bfr[ni] = *(bf16x8*)(bbase + bterm[ni]);
#pragma unroll
        for (int mi = 0; mi < 4; ++mi) {
          bf16x8 ah = *(bf16x8*)(smem + abase + colterm[mi][kw]);
          bf16x8 al = *(bf16x8*)(smem + ABYTES + abase + colterm[mi][kw]);
#pragma unroll
          for (int ni = 0; ni < 2; ++ni) {
            acc[mi][ni] = __builtin_amdgcn_mfma_f32_16x16x32_bf16(
                ah, bfr[ni], acc[mi][ni], 0, 0, 0);
            acc[mi][ni] = __builtin_amdgcn_mfma_f32_16x16x32_bf16(
                al, bfr[ni], acc[mi][ni], 0, 0, 0);
          }
        }
        __syncthreads();
      }
    }
  }

  if (OUTMODE == 0) {
    short* soH = (short*)smem;
    short* soL = (short*)(smem + ABYTES);
#pragma unroll
    for (int mi = 0; mi < 4; ++mi)
#pragma unroll
      for (int ni = 0; ni < 2; ++ni) {
        int co = wn * 32 + ni * 16 + l15;
        float bs = bias[co];
        int ch = co & 31;
#pragma unroll
        for (int j = 0; j < 4; ++j) {
          int w = mi * 16 + lg * 4 + j;
          float v = acc[mi][ni][j] + bs;
          int slot = (((ch >> 3) ^ ((w >> 1) & 3)) << 3) + (ch & 7);
          int o = ((wm * 2 + wn) * 64 + w) * 32 + slot;
          unsigned short hsh = f2bf(v);
          soH[o] = (short)hsh;
          soL[o] = (short)f2bf(v - bf2f(hsh));
        }
      }
    __syncthreads();
    for (int k = tid; k < 1024; k += 256) {
      int grp = k >> 8;
      int row = grp >> 1, cbo = grp & 1;
      size_t dstb = (size_t)(b * 2 + cbo) * 131072 +
                    (size_t)((h0 + row) << 6) * 32 + (size_t)(k & 255) * 8;
      *(float4*)(o_hi + dstb) = *(float4*)(soH + k * 8);
      *(float4*)(o_lo + dstb) = *(float4*)(soL + k * 8);
    }
  } else {
    int row = h0 + wm;
#pragma unroll
    for (int ni = 0; ni < 2; ++ni) {
      int co = wn * 32 + ni * 16 + l15;
      float bs = bias[co];
#pragma unroll
      for (int mi = 0; mi < 4; ++mi) {
        int col = mi * 16 + lg * 4;
        f32x4 v = acc[mi][ni];
        v += (f32x4)(bs);
        if (OUTMODE == 2) {
#pragma unroll
          for (int j = 0; j < 4; ++j) v[j] = tanhf(v[j]);
        }
        *(f32x4*)(out_f + ((size_t)(b * 64 + co) * 64 + row) * 64 + col) = v;
      }
    }
  }
}

// ---------------- generic KxK direct conv fp32 (e1 only) -------------------
template <int K, int DIL, int CI_T, int OUTMODE>
__global__ void __launch_bounds__(256) convK_k(
    const float* __restrict__ in, const float* __restrict__ wgt,
    const float* __restrict__ bias, float* __restrict__ out, int CIN, int COUT,
    const float* __restrict__ scale_ptr) {
  constexpr int IH = 32 + (K - 1) * DIL;
  constexpr int IW = 32 + (K - 1) * DIL;
  constexpr int PAD = (K - 1) / 2 * DIL;
  constexpr int KK = K * K;
  __shared__ __align__(16) float s_in[CI_T][IH][IW];
  __shared__ __align__(16) float s_w[CI_T * KK * 16];
  int tid = threadIdx.x;
  int tx = tid & 15, ty = tid >> 4;
  int w0 = blockIdx.x * 32, h0 = blockIdx.y * 32;
  int ncog = COUT >> 4;
  int cog = blockIdx.z % ncog;
  int b = blockIdx.z / ncog;
  int co0 = cog << 4;
  float scale = scale_ptr ? scale_ptr[0] : 1.f;
  float a00[16] = {}, a01[16] = {}, a10[16] = {}, a11[16] = {};
  for (int ci0 = 0; ci0 < CIN; ci0 += CI_T) {
    for (int idx = tid; idx < CI_T * IH * IW; idx += 256) {
      int ci = idx / (IH * IW);
      int r = idx - ci * (IH * IW);
      int iy = r / IW;
      int ix = r - iy * IW;
      int gh = h0 - PAD + iy, gw = w0 - PAD + ix;
      float v = 0.f;
      if ((unsigned)gh < 64u && (unsigned)gw < 64u)
        v = in[((((size_t)(b * CIN + ci0 + ci)) << 6) + (size_t)gh << 6) + gw] * scale;
      s_in[ci][iy][ix] = v;
    }
    for (int idx = tid; idx < CI_T * KK * 16; idx += 256) {
      int co = idx & 15;
      int t = (idx >> 4) % KK;
      int ci = (idx >> 4) / KK;
      s_w[(ci * KK + t) * 16 + co] =
          wgt[((size_t)(co0 + co) * CIN + ci0 + ci) * KK + t];
    }
    __syncthreads();
    for (int ci = 0; ci < CI_T; ++ci) {
#pragma unroll
      for (int t = 0; t < KK; ++t) {
        int kh = t / K, kw = t - (t / K) * K;
        int iy = ty * 2 + kh * DIL, ix = tx * 2 + kw * DIL;
        float v00 = s_in[ci][iy][ix];
        float v01 = s_in[ci][iy][ix + 1];
        float v10 = s_in[ci][iy + 1][ix];
        float v11 = s_in[ci][iy + 1][ix + 1];
        const float4* wp = (const float4*)&s_w[(ci * KK + t) * 16];
#pragma unroll
        for (int q = 0; q < 4; ++q) {
          float4 wv = wp[q];
          float wj[4] = {wv.x, wv.y, wv.z, wv.w};
#pragma unroll
          for (int r = 0; r < 4; ++r) {
            a00[q * 4 + r] += v00 * wj[r];
            a01[q * 4 + r] += v01 * wj[r];
            a10[q * 4 + r] += v10 * wj[r];
            a11[q * 4 + r] += v11 * wj[r];
          }
        }
      }
    }
    __syncthreads();
  }
  int oh = h0 + ty * 2, ow = w0 + tx * 2;
#pragma unroll
  for (int j = 0; j < 16; ++j) {
    int co = co0 + j;
    float bs = bias[co];
    float r00 = a00[j] + bs, r01 = a01[j] + bs;
    float r10 = a10[j] + bs, r11 = a11[j] + bs;
    if (OUTMODE == 1) {
      r00 = tanhf(r00); r01 = tanhf(r01);
      r10 = tanhf(r10); r11 = tanhf(r11);
    }
    size_t ob = ((((size_t)(b * COUT + co)) << 6) + (size_t)oh) << 6;
    *(float2*)&out[ob + ow] = make_float2(r00, r01);
    *(float2*)&out[ob + 64 + ow] = make_float2(r10, r11);
  }
}

// ---------------- Haar IDWT ------------------------------------------------
__global__ void __launch_bounds__(256) idwt_k(
    const float* __restrict__ ca, const float* __restrict__ ch,
    const float* __restrict__ cv, const float* __restrict__ cd,
    float* __restrict__ out) {
  int i = blockIdx.x * 256 + threadIdx.x;
  float A = ca[i], Hd = ch[i], V = cv[i], D = cd[i];
  float y00 = (A + Hd + V + D) * 0.5f;
  float y01 = (A + Hd - V - D) * 0.5f;
  float y10 = (A - Hd + V - D) * 0.5f;
  float y11 = (A - Hd - V + D) * 0.5f;
  int w = i & 63;
  int h = (i >> 6) & 63;
  int bc = i >> 12;
  size_t ob = (((size_t)bc * 128) + 2 * h) * 128 + 2 * w;
  *(float2*)&out[ob] = make_float2(y00, y01);
  *(float2*)&out[ob + 128] = make_float2(y10, y11);
}

// ---------------------------------------------------------------------------
extern "C" void kernel_launch(void* const* d_in, const int* in_sizes, int n_in,
                              void* d_out, int out_size, void* d_ws,
                              size_t ws_size, hipStream_t stream) {
  const float* ll_freq = (const float*)d_in[0];
  const float* hl_freq = (const float*)d_in[1];
  const float* lh_freq = (const float*)d_in[2];
  const float* hh_freq = (const float*)d_in[3];
  const float* w_ll = (const float*)d_in[4];
  const float* w_hl = (const float*)d_in[5];
  const float* w_lh = (const float*)d_in[6];
  const float* w_hh = (const float*)d_in[7];
  const float* cc_w = (const float*)d_in[8];
  const float* cc_b = (const float*)d_in[9];
  const float* bnc_g = (const float*)d_in[10];
  const float* bnc_b = (const float*)d_in[11];
  const float* e1_w = (const float*)d_in[12];
  const float* e1_b = (const float*)d_in[13];
  const float* fe_w = (const float*)d_in[14];
  const float* fe_b = (const float*)d_in[15];
  const float* e2_w = (const float*)d_in[16];
  const float* e2_b = (const float*)d_in[17];
  const float* bne_g = (const float*)d_in[18];
  const float* bne_b = (const float*)d_in[19];
  const float* cr_w = (const float*)d_in[20];
  const float* cr_b = (const float*)d_in[21];
  const float* bnr_g = (const float*)d_in[22];
  const float* bnr_b = (const float*)d_in[23];
  const float* adj_w = (const float*)d_in[24];
  const float* adj_b = (const float*)d_in[25];
  const float* cll_w = (const float*)d_in[26];
  const float* cll_b = (const float*)d_in[27];
  const float* chh_w = (const float*)d_in[28];
  const float* chh_b = (const float*)d_in[29];
  const float* c1_w = (const float*)d_in[30];
  const float* c1_b = (const float*)d_in[31];
  const float* c3_w = (const float*)d_in[32];
  const float* c3_b = (const float*)d_in[33];
  const float* c5_w = (const float*)d_in[34];
  const float* c5_b = (const float*)d_in[35];

  const size_t MB = 1ull << 20;
  char* ws = (char*)d_ws;
  unsigned short* y4h = (unsigned short*)(ws);            // 32MB
  float* regA = (float*)(ws);
  unsigned short* E2h = (unsigned short*)(ws + 64 * MB);  // 32MB
  float* y7   = (float*)(ws + 128 * MB);                  // 16MB
  float* y1   = (float*)(ws + 144 * MB);                  // 2MB
  float* y2   = (float*)(ws + 146 * MB);                  // 2MB
  unsigned short* Wt = (unsigned short*)(ws + 148 * MB);  // 13.1MB
  char* base162 = ws + 162 * MB;
  float* hh_m = (float*)(base162);                        // 128KB
  float* st1  = (float*)(base162 + 128 * 1024);           // 32 f
  float* SM   = (float*)(base162 + 132 * 1024);           // 1280 f
  float* AB2  = (float*)(base162 + 140 * 1024);           // 1024 f
  float* AB3  = (float*)(base162 + 146 * 1024);           // 256 f
  unsigned short* Wc1  = (unsigned short*)(base162 + 256 * 1024);
  unsigned short* Wc3  = (unsigned short*)(base162 + 512 * 1024);
  unsigned short* Wc5  = (unsigned short*)(base162 + 768 * 1024);
  unsigned short* Wcll = (unsigned short*)(base162 + 1280 * 1024);
  unsigned short* Wcr  = (unsigned short*)(base162 + 1536 * 1024);  // 128KB
  unsigned short* Wadj = (unsigned short*)(base162 + 1664 * 1024);  // 16KB
  float* s512 = SM;
  float* q512 = SM + 512;
  float* s128 = SM + 1024;
  float* q128 = SM + 1152;

  const size_t F2M = 2097152;
  float* ll_a  = regA + 0 * F2M;
  float* ll_l2 = regA + 1 * F2M;
  float* hl_l2 = regA + 2 * F2M;
  float* lh_l2 = regA + 3 * F2M;
  unsigned short* Ph = (unsigned short*)(ws + 48 * MB);
  unsigned short* Pl = (unsigned short*)(ws + 52 * MB);
  unsigned short* Qh = (unsigned short*)(ws + 56 * MB);
  unsigned short* Ql = (unsigned short*)(ws + 60 * MB);
  float* S = (float*)(ws + 64 * MB);      // boxsum scratch (pre-e2)
  float* hh_l2 = (float*)(ws + 64 * MB);  // post-cr reuse

  dim3 blk(256);

  // all weight preps + stats zero, one launch
  prep_all_k<<<dim3(493), blk, 0, stream>>>(e2_w, cr_w, c1_w, c3_w, c5_w,
                                            cll_w, adj_w, Wt, Wcr, Wc1, Wc3,
                                            Wc5, Wcll, Wadj, SM);

  // median branch
  boxsum_k<<<dim3(512), blk, 0, stream>>>(hh_freq, w_hh, S);
  med_k<<<dim3(512), blk, 0, stream>>>(S, hh_m);

  // cc 1x1 concat(w_hl*hl, w_lh*lh) 128->16
  conv1x1_k<<<dim3(32, 1, 8), blk, 0, stream>>>(
      hl_freq, lh_freq, 64, w_hl, w_lh, nullptr, nullptr, nullptr, nullptr, 1,
      cc_w, cc_b, y1, 128, 16, 0, nullptr, nullptr);

  // e1 3x3 16->16
  convK_k<3, 1, 8, 0><<<dim3(2, 2, 8), blk, 0, stream>>>(y1, e1_w, e1_b, y2, 16,
                                                         16, nullptr);
  stats_k<<<dim3(16), blk, 0, stream>>>(y2, st1, 16, 8);

  // fe 1x1 16->512 (relu(bn)) -> bf16-hi packed only
  conv1x1_k<<<dim3(32, 16, 8), blk, 0, stream>>>(
      y2, nullptr, 0, nullptr, nullptr, st1, bnc_g, bnc_b, nullptr, 2, fe_w,
      fe_b, nullptr, 16, 512, 2, y4h, nullptr);

  // e2 5x5 512->512 MFMA, A = hi only (packed out + bne sums)
  e2_mfma_k<<<dim3(1024), blk, 0, stream>>>(y4h, Wt, e2_b, E2h, s512, q512);
  finalize_k<<<dim3(1), dim3(512), 0, stream>>>(s512, q512, bne_g, bne_b,
                                                1.f / 32768.f, 512, AB2);

  // cr 1x1 512->128 MFMA (BN+ReLU fused; y7 + bnr sums)
  cr_mfma_k<<<dim3(64, 8), blk, 0, stream>>>(E2h, Wcr, AB2, cr_b, y7, s128,
                                             q128);
  finalize_k<<<dim3(1), dim3(128), 0, stream>>>(s128, q128, bnr_g, bnr_b,
                                                1.f / 32768.f, 128, AB3);

  // LL branch: pack(w_ll*ll) -> c1 -> c3 -> c5
  pack_k<<<dim3(512), blk, 0, stream>>>(ll_freq, w_ll, Ph, Pl);
  convmf_k<3, 1, 0><<<dim3(256), blk, 0, stream>>>(Ph, Pl, Wc1, c1_b, nullptr,
                                                   Qh, Ql);
  convmf_k<5, 1, 0><<<dim3(256), blk, 0, stream>>>(Qh, Ql, Wc3, c3_b, nullptr,
                                                   Ph, Pl);
  convmf_k<7, 1, 1><<<dim3(256), blk, 0, stream>>>(Ph, Pl, Wc5, c5_b, ll_a,
                                                   nullptr, nullptr);

  // adj 1x1s (3 variants, gate fused) via MFMA
  adj_mfma_k<<<dim3(32, 3, 8), blk, 0, stream>>>(
      ll_a, ll_freq, hl_freq, lh_freq, y7, AB3, w_ll, w_hl, w_lh, Wadj, adj_b,
      ll_l2, hl_l2, lh_l2);

  // hh_a = leaky_relu(chh(hh_freq + hh_m)) -> packed hi+lo
  conv1x1_k<<<dim3(32, 2, 8), blk, 0, stream>>>(
      hh_freq, nullptr, 0, nullptr, nullptr, nullptr, nullptr, nullptr, hh_m, 3,
      chh_w, chh_b, nullptr, 64, 64, 3, Qh, Ql);

  // hh_l2 = tanh(cll 5x5 dil2)
  convmf_k<5, 2, 2><<<dim3(256), blk, 0, stream>>>(Qh, Ql, Wcll, cll_b, hh_l2,
                                                   nullptr, nullptr);

  // IDWT
  idwt_k<<<dim3(8192), blk, 0, stream>>>(ll_l2, hl_l2, lh_l2, hh_l2,
                                         (float*)d_out);
}

// Round 9
// 925.525 us; speedup vs baseline: 9.1135x; 1.0692x over previous
//
#include <hip/hip_runtime.h>
#include <math.h>

// ---------------------------------------------------------------------------
// FeatureProcessor forward. B=8, C=64, H=W=64, RED=16, EXP=512.
// e2: bf16 MFMA implicit GEMM, A=bf16-hi, wave tile 64px x 128co
// (12 LDS reads / 32 MFMA, -25% LDS/FLOP vs R7). convmf: B in registers,
// barrier-free tap loop. cr/adj/cll: hi-only A (err <=2e-3 at output).
// (R8 resubmission - container infra failure, kernel unchanged after audit.)
// ---------------------------------------------------------------------------

#define HWP 4096

typedef __attribute__((ext_vector_type(8))) short bf16x8;
typedef __attribute__((ext_vector_type(4))) float f32x4;

__device__ __forceinline__ unsigned short f2bf(float x) {
  unsigned int u = __float_as_uint(x);
  unsigned int r = (u + 0x7fffu + ((u >> 16) & 1u)) >> 16;
  return (unsigned short)r;
}
__device__ __forceinline__ float bf2f(unsigned short h) {
  return __uint_as_float(((unsigned int)h) << 16);
}

__device__ __forceinline__ void gload16(const void* g, void* l) {
  __builtin_amdgcn_global_load_lds(
      (const __attribute__((address_space(1))) unsigned int*)g,
      (__attribute__((address_space(3))) unsigned int*)l, 16, 0, 0);
}

// ---------------- finalize: sums -> BN affine ------------------------------
__global__ void finalize_k(const float* __restrict__ s,
                           const float* __restrict__ q,
                           const float* __restrict__ gamma,
                           const float* __restrict__ beta, float invN, int C,
                           float* __restrict__ ab) {
  int c = threadIdx.x;
  if (c < C) {
    float mean = s[c] * invN;
    float var = q[c] * invN - mean * mean;
    float a = gamma[c] * rsqrtf(fmaxf(var, 0.f) + 1e-5f);
    ab[c] = a;
    ab[C + c] = beta[c] - mean * a;
  }
}

// ---------------- box-sum 5x5 reflect (per b,c) ----------------------------
__global__ void __launch_bounds__(256) boxsum_k(
    const float* __restrict__ hh, const float* __restrict__ w_hh,
    float* __restrict__ S) {
  __shared__ float img[64][65];
  __shared__ float rs[64][65];
  int bc = blockIdx.x;
  const float* src = hh + ((size_t)bc << 12);
  float wv = w_hh[0];
  int tid = threadIdx.x;
  for (int i = tid; i < 4096; i += 256) img[i >> 6][i & 63] = src[i] * wv;
  __syncthreads();
  for (int i = tid; i < 4096; i += 256) {
    int h = i >> 6, w = i & 63;
    float s = 0.f;
#pragma unroll
    for (int d = -2; d <= 2; ++d) {
      int ww = w + d;
      ww = ww < 0 ? -ww : (ww > 63 ? 126 - ww : ww);
      s += img[h][ww];
    }
    rs[h][w] = s;
  }
  __syncthreads();
  float* dst = S + ((size_t)bc << 12);
  for (int i = tid; i < 4096; i += 256) {
    int h = i >> 6, w = i & 63;
    float s = 0.f;
#pragma unroll
    for (int d = -2; d <= 2; ++d) {
      int h2 = h + d;
      h2 = h2 < 0 ? -h2 : (h2 > 63 ? 126 - h2 : h2);
      s += rs[h2][w];
    }
    dst[i] = s;
  }
}

// ---------------- median over 64 channels ----------------------------------
__global__ void __launch_bounds__(256) med_k(const float* __restrict__ S,
                                             float* __restrict__ hh_m) {
  __shared__ float ldsS[64][65];
  int bx = blockIdx.x;
  int b = bx >> 6, h = bx & 63;
  int tid = threadIdx.x;
  for (int i = tid; i < 4096; i += 256) {
    int c = i >> 6, w = i & 63;
    ldsS[c][w] = S[((size_t)(b * 64 + c) << 12) + (h << 6) + w];
  }
  __syncthreads();
  int lane = tid & 63, wv = tid >> 6;
  for (int i = 0; i < 16; ++i) {
    int w = wv * 16 + i;
    float s = ldsS[lane][w];
    for (int k = 2; k <= 64; k <<= 1)
      for (int j = k >> 1; j > 0; j >>= 1) {
        float o = __shfl_xor(s, j, 64);
        bool up = (lane & k) == 0;
        bool low = (lane & j) == 0;
        s = (low == up) ? fminf(s, o) : fmaxf(s, o);
      }
    float v31 = __shfl(s, 31, 64);
    float v32 = __shfl(s, 32, 64);
    if (lane == 0) hh_m[(b << 12) + (h << 6) + w] = 0.5f * (v31 + v32);
  }
}

// ---------------- per-channel mean/invstd (bnc only) -----------------------
__global__ void __launch_bounds__(256) stats_k(
    const float* __restrict__ x, float* __restrict__ stats, int C, int B) {
  int c = blockIdx.x;
  int tid = threadIdx.x;
  int N = B * HWP;
  float s = 0.f, q = 0.f;
  for (int i = tid; i < N; i += 256) {
    int b = i >> 12, p = i & 4095;
    float v = x[(((size_t)(b * C + c)) << 12) + p];
    s += v;
    q += v * v;
  }
  __shared__ float rs[256], rq[256];
  rs[tid] = s; rq[tid] = q;
  __syncthreads();
  for (int st = 128; st > 0; st >>= 1) {
    if (tid < st) { rs[tid] += rs[tid + st]; rq[tid] += rq[tid + st]; }
    __syncthreads();
  }
  if (tid == 0) {
    float mean = rs[0] / (float)N;
    float var = rq[0] / (float)N - mean * mean;
    stats[c] = mean;
    stats[C + c] = rsqrtf(fmaxf(var, 0.f) + 1e-5f);
  }
}

// ---------------- 1x1 conv (pointwise GEMM) with fused input modes ---------
__global__ void __launch_bounds__(256) conv1x1_k(
    const float* __restrict__ inA, const float* __restrict__ inB, int C1,
    const float* __restrict__ sA, const float* __restrict__ sB,
    const float* __restrict__ bn_stats, const float* __restrict__ bn_g,
    const float* __restrict__ bn_b, const float* __restrict__ extra, int mode,
    const float* __restrict__ wgt, const float* __restrict__ bias,
    float* __restrict__ out, int CIN, int COUT, int out_mode,
    unsigned short* __restrict__ o_hi, unsigned short* __restrict__ o_lo) {
  __shared__ __align__(16) float s_in[16][128];
  __shared__ __align__(16) float s_w[16][32];
  __shared__ __align__(16) short sOH[4096];
  __shared__ __align__(16) short sOL[4096];
  int tid = threadIdx.x;
  int p0 = blockIdx.x * 128;
  int co0 = blockIdx.y * 32;
  int b = blockIdx.z;
  float fA = sA ? sA[0] : 1.f;
  float fB = sB ? sB[0] : 1.f;
  int pi = tid & 63;
  int cog = tid >> 6;
  float acc0[8] = {0.f, 0.f, 0.f, 0.f, 0.f, 0.f, 0.f, 0.f};
  float acc1[8] = {0.f, 0.f, 0.f, 0.f, 0.f, 0.f, 0.f, 0.f};
  for (int ci0 = 0; ci0 < CIN; ci0 += 16) {
#pragma unroll
    for (int t = 0; t < 8; ++t) {
      int idx = tid + t * 256;
      int ci = idx >> 7, pp = idx & 127;
      int c = ci0 + ci;
      int p = p0 + pp;
      float v;
      if (mode == 1) {
        v = (c < C1) ? fA * inA[(((size_t)(b * C1 + c)) << 12) + p]
                     : fB * inB[(((size_t)(b * (CIN - C1) + (c - C1))) << 12) + p];
      } else {
        v = inA[(((size_t)(b * CIN + c)) << 12) + p];
        if (mode == 2) {
          v = (v - bn_stats[c]) * bn_stats[CIN + c] * bn_g[c] + bn_b[c];
          v = fmaxf(v, 0.f);
        } else if (mode == 3) {
          v += extra[(b << 12) + p];
        }
      }
      s_in[ci][pp] = v;
    }
#pragma unroll
    for (int t = 0; t < 2; ++t) {
      int idx = tid + t * 256;
      int ci = idx >> 5, co = idx & 31;
      float wv = 0.f;
      if (co0 + co < COUT) wv = wgt[(size_t)(co0 + co) * CIN + ci0 + ci];
      s_w[ci][co] = wv;
    }
    __syncthreads();
#pragma unroll
    for (int ci = 0; ci < 16; ++ci) {
      float2 v01 = *(const float2*)&s_in[ci][pi * 2];
      const float4* wp = (const float4*)&s_w[ci][cog * 8];
#pragma unroll
      for (int q = 0; q < 2; ++q) {
        float4 wv = wp[q];
        float wj[4] = {wv.x, wv.y, wv.z, wv.w};
#pragma unroll
        for (int r = 0; r < 4; ++r) {
          acc0[q * 4 + r] += v01.x * wj[r];
          acc1[q * 4 + r] += v01.y * wj[r];
        }
      }
    }
    __syncthreads();
  }
  if (out_mode >= 2) {
#pragma unroll
    for (int j = 0; j < 8; ++j) {
      int co = co0 + cog * 8 + j;
      float bs = bias[co];
      float r[2] = {acc0[j] + bs, acc1[j] + bs};
#pragma unroll
      for (int e = 0; e < 2; ++e) {
        float v = r[e];
        if (out_mode == 3) v = v < 0.f ? 0.1f * v : v;
        int px = pi * 2 + e;
        int w = px & 63;
        int slot = ((cog ^ ((w >> 1) & 3)) << 3) + j;
        int o = px * 32 + slot;
        unsigned short hsh = f2bf(v);
        sOH[o] = (short)hsh;
        if (o_lo) sOL[o] = (short)f2bf(v - bf2f(hsh));
      }
    }
    __syncthreads();
    int cb = co0 >> 5;
    size_t base = (size_t)(b * (COUT >> 5) + cb) * 131072 + (size_t)p0 * 32;
    for (int k = tid; k < 512; k += 256) {
      *(float4*)(o_hi + base + (size_t)k * 8) = *(float4*)&sOH[k * 8];
      if (o_lo)
        *(float4*)(o_lo + base + (size_t)k * 8) = *(float4*)&sOL[k * 8];
    }
  } else {
#pragma unroll
    for (int j = 0; j < 8; ++j) {
      int co = co0 + cog * 8 + j;
      if (co < COUT) {
        float bs = bias[co];
        float r0 = acc0[j] + bs;
        float r1 = acc1[j] + bs;
        if (out_mode == 1) {
          r0 = r0 < 0.f ? 0.1f * r0 : r0;
          r1 = r1 < 0.f ? 0.1f * r1 : r1;
        }
        float2 rr = make_float2(r0, r1);
        *(float2*)&out[(((size_t)(b * COUT + co)) << 12) + p0 + pi * 2] = rr;
      }
    }
  }
}

// ---------------- pack NCHW fp32 -> channels-last hi/lo bf16 ---------------
__global__ void __launch_bounds__(256) pack_k(
    const float* __restrict__ in, const float* __restrict__ scale_ptr,
    unsigned short* __restrict__ o_hi, unsigned short* __restrict__ o_lo) {
  __shared__ float lds[32][130];
  int bx = blockIdx.x;
  int pc = bx & 31, cb = (bx >> 5) & 1, b = bx >> 6;
  int p0 = pc * 128;
  float sc = scale_ptr ? scale_ptr[0] : 1.f;
  int tid = threadIdx.x;
  for (int i = tid; i < 4096; i += 256) {
    int c = i >> 7, px = i & 127;
    lds[c][px] = in[((size_t)(b * 64 + cb * 32 + c) << 12) + p0 + px] * sc;
  }
  __syncthreads();
  size_t base = (size_t)(b * 2 + cb) * 131072 + (size_t)p0 * 32;
  for (int k = tid; k < 512; k += 256) {
    int p = k >> 2, gsw = k & 3;
    int w = p & 63;
    int g = gsw ^ ((w >> 1) & 3);
    bf16x8 hi, lo;
#pragma unroll
    for (int j = 0; j < 8; ++j) {
      float v = lds[g * 8 + j][p];
      unsigned short h = f2bf(v);
      hi[j] = (short)h;
      lo[j] = (short)f2bf(v - bf2f(h));
    }
    *(bf16x8*)(o_hi + base + (size_t)k * 8) = hi;
    *(bf16x8*)(o_lo + base + (size_t)k * 8) = lo;
  }
}

// ---------------- small-conv weight transform (shared body) ----------------
__device__ __forceinline__ void ws_body(const float* __restrict__ w,
                                        unsigned short* __restrict__ Wt,
                                        int bx, int CIN, int KK) {
  int cbci = bx / KK, tap = bx - cbci * KK;
  unsigned short* dst = Wt + (size_t)bx * 2048;
  for (int d = threadIdx.x; d < 2048; d += 256) {
    int co = d >> 5, s = d & 31;
    int g = (s >> 3) ^ ((co >> 1) & 3);
    int cil = (g << 3) + (s & 7);
    dst[d] = f2bf(w[(size_t)(co * CIN + cbci * 32 + cil) * KK + tap]);
  }
}

// ---------------- fat prep: all weight transforms + stats zero -------------
__global__ void __launch_bounds__(256) prep_all_k(
    const float* __restrict__ e2w, const float* __restrict__ crw,
    const float* __restrict__ c1w, const float* __restrict__ c3w,
    const float* __restrict__ c5w, const float* __restrict__ cllw,
    const float* __restrict__ adjw, unsigned short* __restrict__ Wt,
    unsigned short* __restrict__ Wcr, unsigned short* __restrict__ Wc1,
    unsigned short* __restrict__ Wc3, unsigned short* __restrict__ Wc5,
    unsigned short* __restrict__ Wcll, unsigned short* __restrict__ Wadj,
    float* __restrict__ SM) {
  __shared__ short lw[32][800];
  int bx = blockIdx.x, tid = threadIdx.x;
  if (bx < 256) {
    int cbco = bx >> 6, cbci = (bx >> 2) & 15, cog = bx & 3;
    const float* src =
        e2w + ((size_t)(cbco * 128 + cog * 32) * 512 + cbci * 32) * 25;
    for (int i = tid; i < 25600; i += 256) {
      int co_l = i / 800, r = i - co_l * 800;
      lw[co_l][r] = (short)f2bf(src[(size_t)co_l * 12800 + r]);
    }
    __syncthreads();
    unsigned short* dstb =
        Wt + (((size_t)((cbco * 16 + cbci) * 25)) << 12) + cog * 1024;
    for (int k = tid; k < 6400; k += 256) {
      int tap = k >> 8, d4 = (k & 255) << 2;
      short4 o;
      short* op = (short*)&o;
#pragma unroll
      for (int u = 0; u < 4; ++u) {
        int d = d4 + u;
        int col = d >> 5, s = d & 31;
        int g = (s >> 3) ^ ((col >> 1) & 3);
        int cil = (g << 3) + (s & 7);
        op[u] = lw[col][cil * 25 + tap];
      }
      *(short4*)(dstb + (size_t)tap * 4096 + d4) = o;
    }
  } else if (bx < 272) {
    int cb = bx - 256;
    unsigned short* dst = Wcr + (size_t)cb * 4096;
    for (int d = tid; d < 4096; d += 256) {
      int co = d >> 5, s = d & 31;
      int g = (s >> 3) ^ ((co >> 1) & 3);
      int cil = (g << 3) + (s & 7);
      dst[d] = f2bf(crw[(size_t)co * 512 + cb * 32 + cil]);
    }
  } else if (bx < 290) {
    ws_body(c1w, Wc1, bx - 272, 64, 9);
  } else if (bx < 340) {
    ws_body(c3w, Wc3, bx - 290, 64, 25);
  } else if (bx < 438) {
    ws_body(c5w, Wc5, bx - 340, 64, 49);
  } else if (bx < 488) {
    ws_body(cllw, Wcll, bx - 438, 64, 25);
  } else if (bx < 492) {
    ws_body(adjw, Wadj, bx - 488, 128, 1);
  } else {
    for (int i = tid; i < 1280; i += 256) SM[i] = 0.f;
  }
}

// ---------------- e2: MFMA implicit GEMM, wave tile 64px x 128co -----------
// Block: 4 rows x 128 co, 4 waves (wave = 1 row, all 128 co). A hi-only.
// LDS: A 8 rows x 4352 = 34816 | B dbuf 2x8192 @34816. Total 51200.
// 12 ds_read / 32 MFMA per tap per wave.
__global__ void __launch_bounds__(256, 2) e2_mfma_k(
    const unsigned short* __restrict__ y4h, const unsigned short* __restrict__ Wt,
    const float* __restrict__ bias, unsigned short* __restrict__ E2h,
    float* __restrict__ sum5, float* __restrict__ sq5) {
  __shared__ __align__(16) char smem[51200];
  const int tid = threadIdx.x;
  const int lane = tid & 63;
  const int wid = tid >> 6;  // wave owns output row h0+wid
  int logical = ((blockIdx.x & 7) << 6) + (blockIdx.x >> 3);  // XCD chunking
  int cbco = logical >> 7;
  int rem = logical & 127;
  int rowgroup = rem >> 3;
  int b = rem & 7;
  int h0 = rowgroup << 2;
  const int wm = wid;
  const int l15 = lane & 15, lg = lane >> 4;

  int colterm[4][5];
#pragma unroll
  for (int mi = 0; mi < 4; ++mi)
#pragma unroll
    for (int kw = 0; kw < 5; ++kw) {
      int col = mi * 16 + l15 + kw;  // entry = w_in + 2
      colterm[mi][kw] = col * 64 + ((lg ^ (((col + 62) >> 1) & 3)) << 4);
    }
  int bterm[8];
#pragma unroll
  for (int ni = 0; ni < 8; ++ni) {
    int c = ni * 16 + l15;
    bterm[ni] = c * 64 + ((lg ^ ((c >> 1) & 3)) << 4);
  }

  if (tid < 128) {  // zero halo columns 0,1,66,67 of 8 rows
    int g = tid & 3, e = tid >> 2;  // e = s*4 + cp
    int s = e >> 2, cp = e & 3;
    int col = (cp < 2) ? cp : (64 + cp);
    *(float4*)(smem + s * 4352 + col * 64 + g * 16) =
        make_float4(0.f, 0.f, 0.f, 0.f);
  }

  f32x4 acc[4][8];
#pragma unroll
  for (int i = 0; i < 4; ++i)
#pragma unroll
    for (int j = 0; j < 8; ++j) acc[i][j] = (f32x4)(0.f);

#pragma unroll 1
  for (int cb = 0; cb < 16; ++cb) {
    __syncthreads();  // prior-cb reads done before restage
    // ---- stage A: 8 rows, each wave stages rows wid, wid+4 (4KB each) ----
#pragma unroll
    for (int si = 0; si < 2; ++si) {
      int s = wid + si * 4;
      int irow = h0 - 2 + s;
      char* ldsrow = smem + s * 4352 + 128;
      if ((unsigned)irow < 64u) {
        const unsigned short* src =
            y4h + (((size_t)(b * 16 + cb) * 64 + irow) << 11);
#pragma unroll
        for (int c = 0; c < 4; ++c)
          gload16(src + (c << 9) + (lane << 3), ldsrow + (c << 10));
      } else {
#pragma unroll
        for (int c = 0; c < 4; ++c)
          *(float4*)(ldsrow + (c << 10) + (lane << 4)) =
              make_float4(0.f, 0.f, 0.f, 0.f);
      }
    }
    // ---- stage B tap 0 into buf 0 ----
    {
      const unsigned short* src = Wt + ((size_t)((cbco * 16 + cb) * 25) << 12);
#pragma unroll
      for (int k = 0; k < 2; ++k) {
        int c2 = wid * 2 + k;
        gload16(src + (c2 << 9) + (lane << 3), smem + 34816 + (c2 << 10));
      }
    }
    __syncthreads();

#pragma unroll 1
    for (int kh = 0; kh < 5; ++kh) {
      int abase = (wm + kh) * 4352;
#pragma unroll
      for (int kw = 0; kw < 5; ++kw) {
        int tap = kh * 5 + kw;
        if (tap < 24) {  // prefetch next tap's B
          const unsigned short* src =
              Wt + ((size_t)((cbco * 16 + cb) * 25 + tap + 1) << 12);
          int buf = (tap + 1) & 1;
#pragma unroll
          for (int k = 0; k < 2; ++k) {
            int c2 = wid * 2 + k;
            gload16(src + (c2 << 9) + (lane << 3),
                    smem + 34816 + (buf << 13) + (c2 << 10));
          }
        }
        char* bbase = smem + 34816 + ((tap & 1) << 13);
        bf16x8 bfr[8];
#pragma unroll
        for (int ni = 0; ni < 8; ++ni)
          bfr[ni] = *(bf16x8*)(bbase + bterm[ni]);
#pragma unroll
        for (int mi = 0; mi < 4; ++mi) {
          bf16x8 ah = *(bf16x8*)(smem + abase + colterm[mi][kw]);
#pragma unroll
          for (int ni = 0; ni < 8; ++ni) {
            acc[mi][ni] = __builtin_amdgcn_mfma_f32_16x16x32_bf16(
                ah, bfr[ni], acc[mi][ni], 0, 0, 0);
          }
        }
        __syncthreads();
      }
    }
  }

  // ---- stats (register-only) ----
#pragma unroll
  for (int ni = 0; ni < 8; ++ni) {
    int co_l = ni * 16 + l15;
    float bs = bias[cbco * 128 + co_l];
    float ps = 0.f, pq = 0.f;
#pragma unroll
    for (int mi = 0; mi < 4; ++mi)
#pragma unroll
      for (int j = 0; j < 4; ++j) {
        float v = acc[mi][ni][j] + bs;
        ps += v;
        pq += v * v;
      }
    ps += __shfl_xor(ps, 16, 64); ps += __shfl_xor(ps, 32, 64);
    pq += __shfl_xor(pq, 16, 64); pq += __shfl_xor(pq, 32, 64);
    if (lg == 0) {
      atomicAdd(&sum5[cbco * 128 + co_l], ps);
      atomicAdd(&sq5[cbco * 128 + co_l], pq);
    }
  }

  // ---- epilogue: 2 passes of 2 rows into H (32KB), then copy out ----
  short* H = (short*)smem;  // [4 cb_l][2 rows x 64 w][32 slot]
#pragma unroll 1
  for (int pass = 0; pass < 2; ++pass) {
    if ((wid >> 1) == pass) {
      int r_l = wid & 1;
#pragma unroll
      for (int ni = 0; ni < 8; ++ni) {
        int co_l = ni * 16 + l15;
        int cb_l = co_l >> 5, ch = co_l & 31;
        float bs = bias[cbco * 128 + co_l];
#pragma unroll
        for (int mi = 0; mi < 4; ++mi)
#pragma unroll
          for (int j = 0; j < 4; ++j) {
            int w = mi * 16 + lg * 4 + j;
            float v = acc[mi][ni][j] + bs;
            int slot = (((ch >> 3) ^ ((w >> 1) & 3)) << 3) + (ch & 7);
            H[(cb_l * 128 + r_l * 64 + w) * 32 + slot] = (short)f2bf(v);
          }
      }
    }
    __syncthreads();
    for (int k = tid; k < 2048; k += 256) {
      int cb_l = k >> 9, r = k & 511;
      size_t gb =
          ((size_t)(b * 16 + cbco * 4 + cb_l) * 4096 + (h0 + 2 * pass) * 64) *
              32 +
          (size_t)r * 8;
      *(float4*)(E2h + gb) = *(float4*)(H + cb_l * 4096 + r * 8);
    }
    __syncthreads();
  }
}

// ---------------- cr: MFMA GEMM K=512, BN+ReLU fused, hi-only --------------
__global__ void __launch_bounds__(256, 2) cr_mfma_k(
    const unsigned short* __restrict__ E2h, const unsigned short* __restrict__ Wcr,
    const float* __restrict__ ab2, const float* __restrict__ bias,
    float* __restrict__ y7, float* __restrict__ sum3, float* __restrict__ sq3) {
  __shared__ __align__(16) char smem[16384];  // Ah 4K | B 8K @4096 | par @12288
  float* sa = (float*)(smem + 12288);
  float* sb = sa + 512;
  const int tid = threadIdx.x;
  const int lane = tid & 63;
  const int wid = tid >> 6;
  const int b = blockIdx.y;
  const int p0 = blockIdx.x << 6;
  const int wm = wid >> 1, wn = wid & 1;
  const int l15 = lane & 15, lg = lane >> 4;

  for (int i = tid; i < 512; i += 256) {
    sa[i] = ab2[i];
    sb[i] = ab2[512 + i];
  }

  int aterm[2];
#pragma unroll
  for (int mi = 0; mi < 2; ++mi) {
    int px = wm * 32 + mi * 16 + l15;
    aterm[mi] = px * 64 + ((lg ^ ((px >> 1) & 3)) << 4);
  }
  int bterm[4];
#pragma unroll
  for (int ni = 0; ni < 4; ++ni) {
    int c = wn * 64 + ni * 16 + l15;
    bterm[ni] = c * 64 + ((lg ^ ((c >> 1) & 3)) << 4);
  }

  f32x4 acc[2][4];
#pragma unroll
  for (int i = 0; i < 2; ++i)
#pragma unroll
    for (int j = 0; j < 4; ++j) acc[i][j] = (f32x4)(0.f);

  const int spx = tid >> 2, sgs = tid & 3;
  const int sg = sgs ^ ((spx >> 1) & 3);
  __syncthreads();

#pragma unroll 1
  for (int cb = 0; cb < 16; ++cb) {
    {
      size_t src = ((size_t)(b * 16 + cb) * 4096 + p0 + spx) * 32 + sgs * 8;
      bf16x8 h8 = *(const bf16x8*)(E2h + src);
      bf16x8 oh;
      int cib = cb * 32 + sg * 8;
#pragma unroll
      for (int j = 0; j < 8; ++j) {
        float x = bf2f((unsigned short)h8[j]);
        float v = fmaxf(sa[cib + j] * x + sb[cib + j], 0.f);
        oh[j] = (short)f2bf(v);
      }
      *(bf16x8*)(smem + spx * 64 + sgs * 16) = oh;
    }
    {
      const unsigned short* srcB = Wcr + (size_t)cb * 4096;
#pragma unroll
      for (int k = 0; k < 2; ++k) {
        int c2 = wid * 2 + k;
        gload16(srcB + (c2 << 9) + (lane << 3), smem + 4096 + (c2 << 10));
      }
    }
    __syncthreads();
    bf16x8 bfr[4];
#pragma unroll
    for (int ni = 0; ni < 4; ++ni)
      bfr[ni] = *(bf16x8*)(smem + 4096 + bterm[ni]);
#pragma unroll
    for (int mi = 0; mi < 2; ++mi) {
      bf16x8 ah = *(bf16x8*)(smem + aterm[mi]);
#pragma unroll
      for (int ni = 0; ni < 4; ++ni) {
        acc[mi][ni] = __builtin_amdgcn_mfma_f32_16x16x32_bf16(
            ah, bfr[ni], acc[mi][ni], 0, 0, 0);
      }
    }
    __syncthreads();
  }

#pragma unroll
  for (int ni = 0; ni < 4; ++ni) {
    int co = wn * 64 + ni * 16 + l15;
    float bs = bias[co];
    float ps = 0.f, pq = 0.f;
#pragma unroll
    for (int mi = 0; mi < 2; ++mi) {
      f32x4 v = acc[mi][ni];
      v += (f32x4)(bs);
#pragma unroll
      for (int j = 0; j < 4; ++j) { ps += v[j]; pq += v[j] * v[j]; }
      int px = p0 + wm * 32 + mi * 16 + lg * 4;
      *(f32x4*)(y7 + (((size_t)(b * 128 + co)) << 12) + px) = v;
    }
    ps += __shfl_xor(ps, 16, 64); ps += __shfl_xor(ps, 32, 64);
    pq += __shfl_xor(pq, 16, 64); pq += __shfl_xor(pq, 32, 64);
    if (lg == 0) {
      atomicAdd(&sum3[co], ps);
      atomicAdd(&sq3[co], pq);
    }
  }
}

// ---------------- adj 1x1 (128->64) MFMA, gate fused, hi-only --------------
__global__ void __launch_bounds__(256) adj_mfma_k(
    const float* __restrict__ ll_a, const float* __restrict__ ll_freq,
    const float* __restrict__ hl_freq, const float* __restrict__ lh_freq,
    const float* __restrict__ y7, const float* __restrict__ ab3,
    const float* __restrict__ w_ll, const float* __restrict__ w_hl,
    const float* __restrict__ w_lh, const unsigned short* __restrict__ Wadj,
    const float* __restrict__ bias, float* __restrict__ ll_l2,
    float* __restrict__ hl_l2, float* __restrict__ lh_l2) {
  __shared__ __align__(16) char smem[12288];  // Ah 8K | B 4K @8192
  const int tid = threadIdx.x;
  const int lane = tid & 63;
  const int wid = tid >> 6;
  const int p0 = (int)blockIdx.x << 7;
  const int var = blockIdx.y;
  const int b = blockIdx.z;
  const int wm = wid >> 1, wn = wid & 1;
  const int l15 = lane & 15, lg = lane >> 4;

  int aterm[4];
#pragma unroll
  for (int mi = 0; mi < 4; ++mi) {
    int px = wm * 64 + mi * 16 + l15;
    aterm[mi] = px * 64 + ((lg ^ ((px >> 1) & 3)) << 4);
  }
  int bterm[2];
#pragma unroll
  for (int ni = 0; ni < 2; ++ni) {
    int c = wn * 32 + ni * 16 + l15;
    bterm[ni] = c * 64 + ((lg ^ ((c >> 1) & 3)) << 4);
  }

  f32x4 acc[4][2];
#pragma unroll
  for (int i = 0; i < 4; ++i)
#pragma unroll
    for (int j = 0; j < 2; ++j) acc[i][j] = (f32x4)(0.f);

  const float* fr = (var == 1) ? hl_freq : lh_freq;
  float scl = (var == 0) ? w_ll[0] : ((var == 1) ? w_hl[0] : w_lh[0]);

#pragma unroll 1
  for (int cb = 0; cb < 4; ++cb) {
#pragma unroll 1
    for (int pass = 0; pass < 16; ++pass) {
      int ci = pass * 2 + (tid >> 7);
      int px = tid & 127;
      int c = cb * 32 + ci;
      int p = p0 + px;
      float v;
      if (var == 0) {
        v = (c < 64) ? ll_a[(((size_t)(b * 64 + c)) << 12) + p]
                     : scl * ll_freq[(((size_t)(b * 64 + c - 64)) << 12) + p];
      } else {
        if (c < 64) {
          int yc = (var == 1) ? c : (64 + c);
          float arg = ab3[yc] * y7[(((size_t)(b * 128 + yc)) << 12) + p] +
                      ab3[128 + yc];
          float sg = 1.f / (1.f + expf(-arg));
          v = scl * fr[(((size_t)(b * 64 + c)) << 12) + p] * sg;
        } else {
          v = fr[(((size_t)(b * 64 + c - 64)) << 12) + p];
        }
      }
      int gs = (ci >> 3) ^ ((px >> 1) & 3);
      int off = px * 64 + gs * 16 + (ci & 7) * 2;
      *(short*)(smem + off) = (short)f2bf(v);
    }
    gload16(Wadj + (size_t)cb * 2048 + (tid << 3), smem + 8192 + (tid << 4));
    __syncthreads();
    bf16x8 bfr[2];
#pragma unroll
    for (int ni = 0; ni < 2; ++ni)
      bfr[ni] = *(bf16x8*)(smem + 8192 + bterm[ni]);
#pragma unroll
    for (int mi = 0; mi < 4; ++mi) {
      bf16x8 ah = *(bf16x8*)(smem + aterm[mi]);
#pragma unroll
      for (int ni = 0; ni < 2; ++ni) {
        acc[mi][ni] = __builtin_amdgcn_mfma_f32_16x16x32_bf16(
            ah, bfr[ni], acc[mi][ni], 0, 0, 0);
      }
    }
    __syncthreads();
  }

  float* out = (var == 0) ? ll_l2 : ((var == 1) ? hl_l2 : lh_l2);
#pragma unroll
  for (int ni = 0; ni < 2; ++ni) {
    int co = wn * 32 + ni * 16 + l15;
    float bs = bias[co];
#pragma unroll
    for (int mi = 0; mi < 4; ++mi) {
      f32x4 v = acc[mi][ni];
      v += (f32x4)(bs);
      int px = p0 + wm * 64 + mi * 16 + lg * 4;
      *(f32x4*)(out + (((size_t)(b * 64 + co)) << 12) + px) = v;
    }
  }
}

// ---------------- small KxK conv via MFMA, B in registers, no tap barriers -
// LO=1: split-A hi+lo; LO=0: hi-only (inl ignored).
// OUTMODE 0: packed hi/lo out; 1: fp32 NCHW; 2: tanh + fp32 NCHW.
template <int K, int DIL, int OUTMODE, int LO>
__global__ void __launch_bounds__(256, 2) convmf_k(
    const unsigned short* __restrict__ inh, const unsigned short* __restrict__ inl,
    const unsigned short* __restrict__ Wsm, const float* __restrict__ bias,
    float* __restrict__ out_f, unsigned short* __restrict__ o_hi,
    unsigned short* __restrict__ o_lo) {
  constexpr int PAD = (K - 1) / 2 * DIL;
  constexpr int ROWS = 2 + 2 * PAD;
  constexpr int CW = 64 + 2 * PAD;
  constexpr int RB = CW * 64;
  constexpr int ABYTES = ROWS * RB;
  constexpr int KK = K * K;
  constexpr int SBYTES = LO ? 2 * ABYTES : ABYTES;
  __shared__ __align__(16) char smem[SBYTES];
  const int tid = threadIdx.x;
  const int lane = tid & 63;
  const int wid = tid >> 6;
  const int b = blockIdx.x >> 5;
  const int h0 = (blockIdx.x & 31) << 1;
  const int wm = wid >> 1, wn = wid & 1;
  const int l15 = lane & 15, lg = lane >> 4;

  int colterm[4][K];
#pragma unroll
  for (int mi = 0; mi < 4; ++mi)
#pragma unroll
    for (int kw = 0; kw < K; ++kw) {
      int e = mi * 16 + l15 + kw * DIL;
      colterm[mi][kw] = e * 64 + ((lg ^ (((e - PAD + 64) >> 1) & 3)) << 4);
    }
  int bterm[2];
#pragma unroll
  for (int ni = 0; ni < 2; ++ni) {
    int c = wn * 32 + ni * 16 + l15;
    bterm[ni] = c * 64 + ((lg ^ ((c >> 1) & 3)) << 4);
  }

  // zero halo entries
  for (int i = tid; i < (LO ? 2 : 1) * ROWS * 2 * PAD * 4; i += 256) {
    int c4 = i & 3;
    int r1 = i >> 2;
    int e = r1 % (2 * PAD);
    int r2 = r1 / (2 * PAD);
    int r = r2 % ROWS;
    int part = r2 / ROWS;
    int col = (e < PAD) ? e : (e + 64);
    *(float4*)(smem + part * ABYTES + r * RB + col * 64 + c4 * 16) =
        make_float4(0.f, 0.f, 0.f, 0.f);
  }

  f32x4 acc[4][2];
#pragma unroll
  for (int i = 0; i < 4; ++i)
#pragma unroll
    for (int j = 0; j < 2; ++j) acc[i][j] = (f32x4)(0.f);

#pragma unroll 1
  for (int cb = 0; cb < 2; ++cb) {
    __syncthreads();  // prior-cb reads complete
    if (LO) {
      const int part = wid >> 1;
      const int s0 = (wid & 1) * (ROWS / 2);
      const unsigned short* srcA = part ? inl : inh;
#pragma unroll
      for (int si = 0; si < ROWS / 2; ++si) {
        int s = s0 + si;
        int irow = h0 - PAD + s;
        char* ldsrow = smem + part * ABYTES + s * RB + PAD * 64;
        if ((unsigned)irow < 64u) {
          const unsigned short* src =
              srcA + (((size_t)(b * 2 + cb) << 12) + (irow << 6)) * 32;
#pragma unroll
          for (int c = 0; c < 4; ++c)
            gload16(src + (c << 9) + (lane << 3), ldsrow + (c << 10));
        } else {
#pragma unroll
          for (int c = 0; c < 4; ++c)
            *(float4*)(ldsrow + (c << 10) + (lane << 4)) =
                make_float4(0.f, 0.f, 0.f, 0.f);
        }
      }
    } else {
      for (int s = wid; s < ROWS; s += 4) {
        int irow = h0 - PAD + s;
        char* ldsrow = smem + s * RB + PAD * 64;
        if ((unsigned)irow < 64u) {
          const unsigned short* src =
              inh + (((size_t)(b * 2 + cb) << 12) + (irow << 6)) * 32;
#pragma unroll
          for (int c = 0; c < 4; ++c)
            gload16(src + (c << 9) + (lane << 3), ldsrow + (c << 10));
        } else {
#pragma unroll
          for (int c = 0; c < 4; ++c)
            *(float4*)(ldsrow + (c << 10) + (lane << 4)) =
                make_float4(0.f, 0.f, 0.f, 0.f);
        }
      }
    }
    __syncthreads();

    // B in registers, 1-tap prefetch, barrier-free tap loop
    const char* WB0 = (const char*)Wsm + (size_t)(cb * KK) * 4096;
    bf16x8 bc0 = *(const bf16x8*)(WB0 + bterm[0]);
    bf16x8 bc1 = *(const bf16x8*)(WB0 + bterm[1]);
#pragma unroll 1
    for (int kh = 0; kh < K; ++kh) {
      int abase = (wm + kh * DIL) * RB;
#pragma unroll
      for (int kw = 0; kw < K; ++kw) {
        int tap = kh * K + kw;
        bf16x8 bn0 = bc0, bn1 = bc1;
        if (tap + 1 < KK) {
          const char* WB =
              (const char*)Wsm + (size_t)(cb * KK + tap + 1) * 4096;
          bn0 = *(const bf16x8*)(WB + bterm[0]);
          bn1 = *(const bf16x8*)(WB + bterm[1]);
        }
#pragma unroll
        for (int mi = 0; mi < 4; ++mi) {
          bf16x8 ah = *(bf16x8*)(smem + abase + colterm[mi][kw]);
          acc[mi][0] = __builtin_amdgcn_mfma_f32_16x16x32_bf16(ah, bc0,
                                                              acc[mi][0], 0, 0, 0);
          acc[mi][1] = __builtin_amdgcn_mfma_f32_16x16x32_bf16(ah, bc1,
                                                              acc[mi][1], 0, 0, 0);
          if (LO) {
            bf16x8 al = *(bf16x8*)(smem + ABYTES + abase + colterm[mi][kw]);
            acc[mi][0] = __builtin_amdgcn_mfma_f32_16x16x32_bf16(
                al, bc0, acc[mi][0], 0, 0, 0);
            acc[mi][1] = __builtin_amdgcn_mfma_f32_16x16x32_bf16(
                al, bc1, acc[mi][1], 0, 0, 0);
          }
        }
        bc0 = bn0;
        bc1 = bn1;
      }
    }
  }

  if (OUTMODE == 0) {
    __syncthreads();
    short* soH = (short*)smem;
    short* soL = (short*)(smem + ABYTES);
#pragma unroll
    for (int mi = 0; mi < 4; ++mi)
#pragma unroll
      for (int ni = 0; ni < 2; ++ni) {
        int co = wn * 32 + ni * 16 + l15;
        float bs = bias[co];
        int ch = co & 31;
#pragma unroll
        for (int j = 0; j < 4; ++j) {
          int w = mi * 16 + lg * 4 + j;
          float v = acc[mi][ni][j] + bs;
          int slot = (((ch >> 3) ^ ((w >> 1) & 3)) << 3) + (ch & 7);
          int o = ((wm * 2 + wn) * 64 + w) * 32 + slot;
          unsigned short hsh = f2bf(v);
          soH[o] = (short)hsh;
          soL[o] = (short)f2bf(v - bf2f(hsh));
        }
      }
    __syncthreads();
    for (int k = tid; k < 1024; k += 256) {
      int grp = k >> 8;
      int row = grp >> 1, cbo = grp & 1;
      size_t dstb = (size_t)(b * 2 + cbo) * 131072 +
                    (size_t)((h0 + row) << 6) * 32 + (size_t)(k & 255) * 8;
      *(float4*)(o_hi + dstb) = *(float4*)(soH + k * 8);
      *(float4*)(o_lo + dstb) = *(float4*)(soL + k * 8);
    }
  } else {
    int row = h0 + wm;
#pragma unroll
    for (int ni = 0; ni < 2; ++ni) {
      int co = wn * 32 + ni * 16 + l15;
      float bs = bias[co];
#pragma unroll
      for (int mi = 0; mi < 4; ++mi) {
        int col = mi * 16 + lg * 4;
        f32x4 v = acc[mi][ni];
        v += (f32x4)(bs);
        if (OUTMODE == 2) {
#pragma unroll
          for (int j = 0; j < 4; ++j) v[j] = tanhf(v[j]);
        }
        *(f32x4*)(out_f + ((size_t)(b * 64 + co) * 64 + row) * 64 + col) = v;
      }
    }
  }
}

// ---------------- generic KxK direct conv fp32 (e1 only) -------------------
template <int K, int DIL, int CI_T, int OUTMODE>
__global__ void __launch_bounds__(256) convK_k(
    const float* __restrict__ in, const float* __restrict__ wgt,
    const float* __restrict__ bias, float* __restrict__ out, int CIN, int COUT,
    const float* __restrict__ scale_ptr) {
  constexpr int IH = 32 + (K - 1) * DIL;
  constexpr int IW = 32 + (K - 1) * DIL;
  constexpr int PAD = (K - 1) / 2 * DIL;
  constexpr int KK = K * K;
  __shared__ __align__(16) float s_in[CI_T][IH][IW];
  __shared__ __align__(16) float s_w[CI_T * KK * 16];
  int tid = threadIdx.x;
  int tx = tid & 15, ty = tid >> 4;
  int w0 = blockIdx.x * 32, h0 = blockIdx.y * 32;
  int ncog = COUT >> 4;
  int cog = blockIdx.z % ncog;
  int b = blockIdx.z / ncog;
  int co0 = cog << 4;
  float scale = scale_ptr ? scale_ptr[0] : 1.f;
  float a00[16] = {}, a01[16] = {}, a10[16] = {}, a11[16] = {};
  for (int ci0 = 0; ci0 < CIN; ci0 += CI_T) {
    for (int idx = tid; idx < CI_T * IH * IW; idx += 256) {
      int ci = idx / (IH * IW);
      int r = idx - ci * (IH * IW);
      int iy = r / IW;
      int ix = r - iy * IW;
      int gh = h0 - PAD + iy, gw = w0 - PAD + ix;
      float v = 0.f;
      if ((unsigned)gh < 64u && (unsigned)gw < 64u)
        v = in[((((size_t)(b * CIN + ci0 + ci)) << 6) + (size_t)gh << 6) + gw] * scale;
      s_in[ci][iy][ix] = v;
    }
    for (int idx = tid; idx < CI_T * KK * 16; idx += 256) {
      int co = idx & 15;
      int t = (idx >> 4) % KK;
      int ci = (idx >> 4) / KK;
      s_w[(ci * KK + t) * 16 + co] =
          wgt[((size_t)(co0 + co) * CIN + ci0 + ci) * KK + t];
    }
    __syncthreads();
    for (int ci = 0; ci < CI_T; ++ci) {
#pragma unroll
      for (int t = 0; t < KK; ++t) {
        int kh = t / K, kw = t - (t / K) * K;
        int iy = ty * 2 + kh * DIL, ix = tx * 2 + kw * DIL;
        float v00 = s_in[ci][iy][ix];
        float v01 = s_in[ci][iy][ix + 1];
        float v10 = s_in[ci][iy + 1][ix];
        float v11 = s_in[ci][iy + 1][ix + 1];
        const float4* wp = (const float4*)&s_w[(ci * KK + t) * 16];
#pragma unroll
        for (int q = 0; q < 4; ++q) {
          float4 wv = wp[q];
          float wj[4] = {wv.x, wv.y, wv.z, wv.w};
#pragma unroll
          for (int r = 0; r < 4; ++r) {
            a00[q * 4 + r] += v00 * wj[r];
            a01[q * 4 + r] += v01 * wj[r];
            a10[q * 4 + r] += v10 * wj[r];
            a11[q * 4 + r] += v11 * wj[r];
          }
        }
      }
    }
    __syncthreads();
  }
  int oh = h0 + ty * 2, ow = w0 + tx * 2;
#pragma unroll
  for (int j = 0; j < 16; ++j) {
    int co = co0 + j;
    float bs = bias[co];
    float r00 = a00[j] + bs, r01 = a01[j] + bs;
    float r10 = a10[j] + bs, r11 = a11[j] + bs;
    if (OUTMODE == 1) {
      r00 = tanhf(r00); r01 = tanhf(r01);
      r10 = tanhf(r10); r11 = tanhf(r11);
    }
    size_t ob = ((((size_t)(b * COUT + co)) << 6) + (size_t)oh) << 6;
    *(float2*)&out[ob + ow] = make_float2(r00, r01);
    *(float2*)&out[ob + 64 + ow] = make_float2(r10, r11);
  }
}

// ---------------- Haar IDWT ------------------------------------------------
__global__ void __launch_bounds__(256) idwt_k(
    const float* __restrict__ ca, const float* __restrict__ ch,
    const float* __restrict__ cv, const float* __restrict__ cd,
    float* __restrict__ out) {
  int i = blockIdx.x * 256 + threadIdx.x;
  float A = ca[i], Hd = ch[i], V = cv[i], D = cd[i];
  float y00 = (A + Hd + V + D) * 0.5f;
  float y01 = (A + Hd - V - D) * 0.5f;
  float y10 = (A - Hd + V - D) * 0.5f;
  float y11 = (A - Hd - V + D) * 0.5f;
  int w = i & 63;
  int h = (i >> 6) & 63;
  int bc = i >> 12;
  size_t ob = (((size_t)bc * 128) + 2 * h) * 128 + 2 * w;
  *(float2*)&out[ob] = make_float2(y00, y01);
  *(float2*)&out[ob + 128] = make_float2(y10, y11);
}

// ---------------------------------------------------------------------------
extern "C" void kernel_launch(void* const* d_in, const int* in_sizes, int n_in,
                              void* d_out, int out_size, void* d_ws,
                              size_t ws_size, hipStream_t stream) {
  const float* ll_freq = (const float*)d_in[0];
  const float* hl_freq = (const float*)d_in[1];
  const float* lh_freq = (const float*)d_in[2];
  const float* hh_freq = (const float*)d_in[3];
  const float* w_ll = (const float*)d_in[4];
  const float* w_hl = (const float*)d_in[5];
  const float* w_lh = (const float*)d_in[6];
  const float* w_hh = (const float*)d_in[7];
  const float* cc_w = (const float*)d_in[8];
  const float* cc_b = (const float*)d_in[9];
  const float* bnc_g = (const float*)d_in[10];
  const float* bnc_b = (const float*)d_in[11];
  const float* e1_w = (const float*)d_in[12];
  const float* e1_b = (const float*)d_in[13];
  const float* fe_w = (const float*)d_in[14];
  const float* fe_b = (const float*)d_in[15];
  const float* e2_w = (const float*)d_in[16];
  const float* e2_b = (const float*)d_in[17];
  const float* bne_g = (const float*)d_in[18];
  const float* bne_b = (const float*)d_in[19];
  const float* cr_w = (const float*)d_in[20];
  const float* cr_b = (const float*)d_in[21];
  const float* bnr_g = (const float*)d_in[22];
  const float* bnr_b = (const float*)d_in[23];
  const float* adj_w = (const float*)d_in[24];
  const float* adj_b = (const float*)d_in[25];
  const float* cll_w = (const float*)d_in[26];
  const float* cll_b = (const float*)d_in[27];
  const float* chh_w = (const float*)d_in[28];
  const float* chh_b = (const float*)d_in[29];
  const float* c1_w = (const float*)d_in[30];
  const float* c1_b = (const float*)d_in[31];
  const float* c3_w = (const float*)d_in[32];
  const float* c3_b = (const float*)d_in[33];
  const float* c5_w = (const float*)d_in[34];
  const float* c5_b = (const float*)d_in[35];

  const size_t MB = 1ull << 20;
  char* ws = (char*)d_ws;
  unsigned short* y4h = (unsigned short*)(ws);            // 32MB
  float* regA = (float*)(ws);
  unsigned short* E2h = (unsigned short*)(ws + 64 * MB);  // 32MB
  float* y7   = (float*)(ws + 128 * MB);                  // 16MB
  float* y1   = (float*)(ws + 144 * MB);                  // 2MB
  float* y2   = (float*)(ws + 146 * MB);                  // 2MB
  unsigned short* Wt = (unsigned short*)(ws + 148 * MB);  // 13.1MB
  char* base162 = ws + 162 * MB;
  float* hh_m = (float*)(base162);                        // 128KB
  float* st1  = (float*)(base162 + 128 * 1024);           // 32 f
  float* SM   = (float*)(base162 + 132 * 1024);           // 1280 f
  float* AB2  = (float*)(base162 + 140 * 1024);           // 1024 f
  float* AB3  = (float*)(base162 + 146 * 1024);           // 256 f
  unsigned short* Wc1  = (unsigned short*)(base162 + 256 * 1024);
  unsigned short* Wc3  = (unsigned short*)(base162 + 512 * 1024);
  unsigned short* Wc5  = (unsigned short*)(base162 + 768 * 1024);
  unsigned short* Wcll = (unsigned short*)(base162 + 1280 * 1024);
  unsigned short* Wcr  = (unsigned short*)(base162 + 1536 * 1024);  // 128KB
  unsigned short* Wadj = (unsigned short*)(base162 + 1664 * 1024);  // 16KB
  float* s512 = SM;
  float* q512 = SM + 512;
  float* s128 = SM + 1024;
  float* q128 = SM + 1152;

  const size_t F2M = 2097152;
  float* ll_a  = regA + 0 * F2M;
  float* ll_l2 = regA + 1 * F2M;
  float* hl_l2 = regA + 2 * F2M;
  float* lh_l2 = regA + 3 * F2M;
  unsigned short* Ph = (unsigned short*)(ws + 48 * MB);
  unsigned short* Pl = (unsigned short*)(ws + 52 * MB);
  unsigned short* Qh = (unsigned short*)(ws + 56 * MB);
  unsigned short* Ql = (unsigned short*)(ws + 60 * MB);
  float* S = (float*)(ws + 64 * MB);      // boxsum scratch (pre-e2)
  float* hh_l2 = (float*)(ws + 64 * MB);  // post-cr reuse

  dim3 blk(256);

  prep_all_k<<<dim3(493), blk, 0, stream>>>(e2_w, cr_w, c1_w, c3_w, c5_w,
                                            cll_w, adj_w, Wt, Wcr, Wc1, Wc3,
                                            Wc5, Wcll, Wadj, SM);

  // median branch
  boxsum_k<<<dim3(512), blk, 0, stream>>>(hh_freq, w_hh, S);
  med_k<<<dim3(512), blk, 0, stream>>>(S, hh_m);

  // cc 1x1 concat(w_hl*hl, w_lh*lh) 128->16
  conv1x1_k<<<dim3(32, 1, 8), blk, 0, stream>>>(
      hl_freq, lh_freq, 64, w_hl, w_lh, nullptr, nullptr, nullptr, nullptr, 1,
      cc_w, cc_b, y1, 128, 16, 0, nullptr, nullptr);

  // e1 3x3 16->16
  convK_k<3, 1, 8, 0><<<dim3(2, 2, 8), blk, 0, stream>>>(y1, e1_w, e1_b, y2, 16,
                                                         16, nullptr);
  stats_k<<<dim3(16), blk, 0, stream>>>(y2, st1, 16, 8);

  // fe 1x1 16->512 (relu(bn)) -> bf16-hi packed only
  conv1x1_k<<<dim3(32, 16, 8), blk, 0, stream>>>(
      y2, nullptr, 0, nullptr, nullptr, st1, bnc_g, bnc_b, nullptr, 2, fe_w,
      fe_b, nullptr, 16, 512, 2, y4h, nullptr);

  // e2 5x5 512->512 MFMA (wave 64px x 128co, packed out + bne sums)
  e2_mfma_k<<<dim3(512), blk, 0, stream>>>(y4h, Wt, e2_b, E2h, s512, q512);
  finalize_k<<<dim3(1), dim3(512), 0, stream>>>(s512, q512, bne_g, bne_b,
                                                1.f / 32768.f, 512, AB2);

  // cr 1x1 512->128 MFMA (BN+ReLU fused, hi-only; y7 + bnr sums)
  cr_mfma_k<<<dim3(64, 8), blk, 0, stream>>>(E2h, Wcr, AB2, cr_b, y7, s128,
                                             q128);
  finalize_k<<<dim3(1), dim3(128), 0, stream>>>(s128, q128, bnr_g, bnr_b,
                                                1.f / 32768.f, 128, AB3);

  // LL branch: pack(w_ll*ll) -> c1 -> c3 -> c5 (split-A)
  pack_k<<<dim3(512), blk, 0, stream>>>(ll_freq, w_ll, Ph, Pl);
  convmf_k<3, 1, 0, 1><<<dim3(256), blk, 0, stream>>>(Ph, Pl, Wc1, c1_b,
                                                      nullptr, Qh, Ql);
  convmf_k<5, 1, 0, 1><<<dim3(256), blk, 0, stream>>>(Qh, Ql, Wc3, c3_b,
                                                      nullptr, Ph, Pl);
  convmf_k<7, 1, 1, 1><<<dim3(256), blk, 0, stream>>>(Ph, Pl, Wc5, c5_b, ll_a,
                                                      nullptr, nullptr);

  // adj 1x1s (3 variants, gate fused, hi-only) via MFMA
  adj_mfma_k<<<dim3(32, 3, 8), blk, 0, stream>>>(
      ll_a, ll_freq, hl_freq, lh_freq, y7, AB3, w_ll, w_hl, w_lh, Wadj, adj_b,
      ll_l2, hl_l2, lh_l2);

  // hh_a = leaky_relu(chh(hh_freq + hh_m)) -> packed hi only
  conv1x1_k<<<dim3(32, 2, 8), blk, 0, stream>>>(
      hh_freq, nullptr, 0, nullptr, nullptr, nullptr, nullptr, nullptr, hh_m, 3,
      chh_w, chh_b, nullptr, 64, 64, 3, Qh, nullptr);

  // hh_l2 = tanh(cll 5x5 dil2), hi-only
  convmf_k<5, 2, 2, 0><<<dim3(256), blk, 0, stream>>>(Qh, nullptr, Wcll, cll_b,
                                                      hh_l2, nullptr, nullptr);

  // IDWT
  idwt_k<<<dim3(8192), blk, 0, stream>>>(ll_l2, hl_l2, lh_l2, hh_l2,
                                         (float*)d_out);
}